// Round 6
// baseline (16823.465 us; speedup 1.0000x reference)
//
#include <hip/hip_runtime.h>
#include <math.h>

#define NT 512

__device__ __forceinline__ float sigf(float x){ return 1.0f/(1.0f+expf(-x)); }
__device__ __forceinline__ float rdlane(float v, int l){
  return __int_as_float(__builtin_amdgcn_readlane(__float_as_int(v), l));
}

__launch_bounds__(NT, 1)
__global__ void kf_fwd(const float* __restrict__ a_seq, const float* __restrict__ h_obs,
  const float* __restrict__ Amat, const float* __restrict__ Cmat, const float* __restrict__ Bmat,
  const float* __restrict__ u_seq, const float* __restrict__ mask, const float* __restrict__ P0,
  const float* __restrict__ matQ, const float* __restrict__ matR,
  const float* __restrict__ Wx, const float* __restrict__ Wh, const float* __restrict__ gbias,
  const float* __restrict__ outW, const float* __restrict__ outb, float* __restrict__ out)
{
  constexpr int T=256, B=128;
  constexpr int L6=36, L0=20;
  constexpr size_t BT=(size_t)B*T;
  const size_t off_zf=0;
  const size_t off_Pf=off_zf+BT*32;
  const size_t off_zl=off_Pf+BT*1024;
  const size_t off_tr=off_zl+BT*32;
  const size_t off_zp=off_tr+BT*1024;
  const size_t off_Pp=off_zp+BT*32;
  const size_t off_af=off_Pp+BT*1024;
  const size_t off_ap=off_af+BT*16;
  const size_t off_S =off_ap+BT*16;
  const size_t off_al=off_S +BT*256;
  const size_t off_ai=off_al+BT*8;
  const size_t off_R =off_ai+BT*8;
  const size_t off_Q =off_R +256;

  // LDS-resident small weights
  __shared__ __align__(16) float sA[8*32*L6];
  __shared__ __align__(16) float sC[8*16*L6];
  __shared__ __align__(16) float sCA[8*16*L6];   // CA_k = C_k @ A_k
  __shared__ __align__(16) float sBm[1024];
  __shared__ __align__(16) float souWT[512];     // [r][q] = outW[q*8+r]
  __shared__ __align__(16) float sgb[192];
  __shared__ __align__(16) float soutb[8];
  // work matrices
  __shared__ __align__(16) float P[32*L6], Ak[32*L6], AkT[32*L6], IKCm[32*L6], IKCT[32*L6];
  __shared__ __align__(16) float T1[32*L6], T3[32*L6], Qm[32*L6], sTril[32*L6];
  __shared__ __align__(16) float Ck[16*L6], CPm[16*L6], KgT[16*L6];
  __shared__ __align__(16) float CPT[32*L0], Kg[32*L0], KgR[32*L0];
  __shared__ __align__(16) float Sm[16*L0], Rm[16*L0], Sinv[16*L0];
  __shared__ __align__(16) float Linv[16*17];
  __shared__ __align__(16) float Bk[128];
  __shared__ __align__(16) float zj[256], aj[128];
  __shared__ __align__(16) float gxp[384], ghlv[192], xin[192];
  __shared__ __align__(16) float zc[32], znew[32], zloc[32], zpred[32], ghs[64];
  __shared__ __align__(16) float ak[16], uk[4], rk[16], ll[8], alpha8[8];
  __shared__ float mval;

  const int tid = threadIdx.x;
  const int b = blockIdx.x;

  // ---------- stage LDS ----------
  for (int e=tid; e<8192; e+=NT){ int k=e>>10, i=(e>>5)&31, j=e&31; sA[(k*32+i)*L6+j]=Amat[e]; }
  for (int e=tid; e<4096; e+=NT){ int k=e>>9, a=(e>>5)&15, i=e&31; sC[(k*16+a)*L6+i]=Cmat[e]; }
  for (int e=tid; e<1024; e+=NT) sBm[e]=Bmat[e];
  if (tid<512){ int r=tid>>6, q=tid&63; souWT[r*64+q]=outW[q*8+r]; }
  if (tid<192) sgb[tid]=gbias[tid];
  if (tid<8)   soutb[tid]=outb[tid];
  for (int e=tid; e<1024; e+=NT){
    int i=e>>5, j=e&31;
    float s=0.f;
    #pragma unroll
    for (int k=0;k<32;k++) s += matQ[i*32+k]*matQ[j*32+k];
    Qm[i*L6+j]=s+(i==j?0.001f:0.f);
    P[i*L6+j]=P0[e];
  }
  for (int e=tid; e<256; e+=NT){
    int i=e>>4, j=e&15;
    float s=0.f;
    #pragma unroll
    for (int k=0;k<16;k++) s += matR[i*16+k]*matR[j*16+k];
    Rm[i*L0+j]=s+(i==j?0.001f:0.f);
  }
  for (int e=tid; e<16*L6; e+=NT) Ck[e]=0.f;   // t=0: aprev = 0 (z_prev=0)
  if (tid<32) zc[tid]=0.f;
  if (tid<64) ghs[tid]=0.f;
  if (tid<16) xin[16+tid]=h_obs[b*16+tid];
  __syncthreads();

  // CA_k = C_k @ A_k (one-time) ; R/Q outputs
  for (int e=tid; e<4096; e+=NT){
    int k=e>>9, a=(e>>5)&15, j=e&31;
    float s=0.f;
    #pragma unroll
    for (int i=0;i<32;i++) s += sC[(k*16+a)*L6+i]*sA[(k*32+i)*L6+j];
    sCA[(k*16+a)*L6+j]=s;
  }
  if (b==0){
    for (int e=tid;e<256;e+=NT) out[off_R+e]=Rm[(e>>4)*L0+(e&15)];
    for (int e=tid;e<1024;e+=NT) out[off_Q+e]=Qm[(e>>5)*L6+(e&31)];
  }
  __syncthreads();

  for (int t=0;t<T;t++){
    const size_t bt=(size_t)b*T+t;

    // ==== A: aj=CA@zc | ghl (global Wh) | small loads/stores + lagged tril/a_pred ====
    if (tid<128){
      int k=tid>>4, a2=tid&15;
      const float* car=&sCA[(k*16+a2)*L6];
      float s0=0.f,s1=0.f,s2=0.f,s3=0.f;
      #pragma unroll
      for (int q=0;q<8;q++){
        float4 cv=*(const float4*)&car[q*4];
        float4 zv=*(const float4*)&zc[q*4];
        s0+=cv.x*zv.x; s1+=cv.y*zv.y; s2+=cv.z*zv.z; s3+=cv.w*zv.w;
      }
      float s=(s0+s1)+(s2+s3);
      aj[tid]=s; xin[64+tid]=s;
    } else if (tid<320){
      int c=tid-128;
      const float* wp=Wh+c;
      float s0=0.f,s1=0.f,s2=0.f,s3=0.f;
      #pragma unroll
      for (int q=0;q<16;q++){
        float4 gv=*(const float4*)&ghs[q*4];
        s0+=gv.x*wp[(q*4+0)*192]; s1+=gv.y*wp[(q*4+1)*192];
        s2+=gv.z*wp[(q*4+2)*192]; s3+=gv.w*wp[(q*4+3)*192];
      }
      ghlv[c]=(s0+s1)+(s2+s3);
    } else {
      int th=tid-320;
      if (th<16) ak[th]=a_seq[bt*16+th];
      else if (th<20) uk[th-16]=u_seq[bt*4+(th-16)];
      else if (th==20) mval=mask[bt];
      else if (th>=32 && th<48){
        int a2=th-32;
        float p0=0.f,p1=0.f,p2=0.f,p3=0.f;
        #pragma unroll
        for (int q=0;q<8;q++){
          float4 cv=*(const float4*)&Ck[a2*L6+q*4];
          float4 zv=*(const float4*)&zc[q*4];
          p0+=cv.x*zv.x; p1+=cv.y*zv.y; p2+=cv.z*zv.z; p3+=cv.w*zv.w;
        }
        xin[a2]=(p0+p1)+(p2+p3);
      }
      else if (th>=48 && th<80) xin[32+(th-48)]=zc[th-48];
      else if (th>=80 && th<144){
        if (t>0){
          for (int e4=th-80; e4<256; e4+=64){
            float4 v=*(const float4*)&sTril[(e4>>3)*L6+(e4&7)*4];
            *(float4*)&out[off_tr+(bt-1)*1024+e4*4]=v;
          }
        }
      }
      else if (th>=144 && th<160){
        if (t>0){
          int a2=th-144;
          float p0=0.f,p1=0.f,p2=0.f,p3=0.f;
          #pragma unroll
          for (int q=0;q<8;q++){
            float4 cv=*(const float4*)&Ck[a2*L6+q*4];
            float4 zv=*(const float4*)&zpred[q*4];
            p0+=cv.x*zv.x; p1+=cv.y*zv.y; p2+=cv.z*zv.z; p3+=cv.w*zv.w;
          }
          out[off_ap+(bt-1)*16+a2]=(p0+p1)+(p2+p3);
        }
      }
    }
    __syncthreads();

    // ==== B: gx full (global Wx, 96 rows per thread) | zj ====
    if (tid<384){
      int h=(tid>=192); int c=tid-h*192;
      const int xb=h*96;
      const float* wp=Wx+(size_t)(h*96)*192+c;
      float s0=0.f,s1=0.f,s2=0.f,s3=0.f;
      #pragma unroll
      for (int q=0;q<24;q++){
        float4 xv=*(const float4*)&xin[xb+q*4];
        s0+=xv.x*wp[(size_t)(q*4+0)*192]; s1+=xv.y*wp[(size_t)(q*4+1)*192];
        s2+=xv.z*wp[(size_t)(q*4+2)*192]; s3+=xv.w*wp[(size_t)(q*4+3)*192];
      }
      gxp[h*192+c]=(s0+s1)+(s2+s3);
    } else {
      int th=tid-384;   // 128 threads, 2 zj outputs each
      #pragma unroll
      for (int r=0;r<2;r++){
        int e=th+r*128; int k=e>>5, i2=e&31;
        const float* ar=&sA[(k*32+i2)*L6];
        float s0=0.f,s1=0.f,s2=0.f,s3=0.f;
        #pragma unroll
        for (int q=0;q<8;q++){
          float4 av=*(const float4*)&ar[q*4];
          float4 zv=*(const float4*)&zc[q*4];
          s0+=av.x*zv.x; s1+=av.y*zv.y; s2+=av.z*zv.z; s3+=av.w*zv.w;
        }
        zj[e]=(s0+s1)+(s2+s3);
      }
    }
    __syncthreads();

    // ==== C: wave0 gates->gh->logits->alpha | wave1: ll + alpha_imm ====
    if (tid<64){
      int j=tid;
      float gr=sgb[j]    +gxp[j]    +gxp[192+j]+ghlv[j];
      float gz=sgb[64+j] +gxp[64+j] +gxp[256+j]+ghlv[64+j];
      float r =sigf(gr);
      float zg=sigf(gz);
      float n =tanhf(sgb[128+j]+gxp[128+j]+gxp[320+j]+r*ghlv[128+j]);
      ghs[j]=(1.f-zg)*n+zg*ghs[j];
      if (tid<8){
        float s0=soutb[tid],s1=0.f,s2=0.f,s3=0.f;
        #pragma unroll
        for (int q=0;q<16;q++){
          float4 g=*(const float4*)&ghs[q*4];
          float4 w=*(const float4*)&souWT[tid*64+q*4];
          s0+=g.x*w.x; s1+=g.y*w.y; s2+=g.z*w.z; s3+=g.w*w.w;
        }
        float s=(s0+s1)+(s2+s3);
        float m8=s;
        m8=fmaxf(m8,__shfl_xor(m8,1));
        m8=fmaxf(m8,__shfl_xor(m8,2));
        m8=fmaxf(m8,__shfl_xor(m8,4));
        float e2=expf(s-m8);
        float ss=e2;
        ss+=__shfl_xor(ss,1); ss+=__shfl_xor(ss,2); ss+=__shfl_xor(ss,4);
        float av=e2/ss;
        alpha8[tid]=av;
        out[off_al+bt*8+tid]=av;
      }
    } else if (tid<72){
      int k=tid-64;
      float s=0.f;
      #pragma unroll
      for (int a=0;a<16;a++){ float d=ak[a]-aj[k*16+a]; s+=d*d; }
      ll[k]=-s;
      float m8=ll[0];
      #pragma unroll
      for (int j=1;j<8;j++) m8=fmaxf(m8,ll[j]);
      float ssum=0.f, ek=0.f;
      #pragma unroll
      for (int j=0;j<8;j++){ float e2=expf(ll[j]-m8); ssum+=e2; if(j==k) ek=e2; }
      out[off_ai+bt*8+k]=ek/ssum*mval;
    }
    __syncthreads();

    // ==== H: blends Ak(+AkT) | Ck | Bk | znew=blend(zj) ====
    if (tid<256){
      int i=tid>>3, j0=(tid&7)*4;
      float c0=0.f,c1=0.f,c2=0.f,c3=0.f;
      #pragma unroll
      for (int k=0;k<8;k++){
        float al=alpha8[k];
        float4 av=*(const float4*)&sA[(k*32+i)*L6+j0];
        c0+=al*av.x; c1+=al*av.y; c2+=al*av.z; c3+=al*av.w;
      }
      *(float4*)&Ak[i*L6+j0]=make_float4(c0,c1,c2,c3);
      AkT[(j0+0)*L6+i]=c0; AkT[(j0+1)*L6+i]=c1; AkT[(j0+2)*L6+i]=c2; AkT[(j0+3)*L6+i]=c3;
    } else if (tid<384){
      int th=tid-256; int a=th>>3, i0=(th&7)*4;
      float c0=0.f,c1=0.f,c2=0.f,c3=0.f;
      #pragma unroll
      for (int k=0;k<8;k++){
        float al=alpha8[k];
        float4 cv=*(const float4*)&sC[(k*16+a)*L6+i0];
        c0+=al*cv.x; c1+=al*cv.y; c2+=al*cv.z; c3+=al*cv.w;
      }
      *(float4*)&Ck[a*L6+i0]=make_float4(c0,c1,c2,c3);
    } else if (tid<448){
      int th=tid-384;   // 64 threads, 2 each
      #pragma unroll
      for (int r=0;r<2;r++){
        int e=th+r*64;
        float s=0.f;
        #pragma unroll
        for (int k=0;k<8;k++) s+=alpha8[k]*sBm[k*128+e];
        Bk[e]=s;
      }
    } else if (tid<480){
      int i=tid-448;
      float s=0.f;
      #pragma unroll
      for (int k=0;k<8;k++) s+=alpha8[k]*zj[k*32+i];
      znew[i]=s;
    }
    __syncthreads();

    // ==== I: CP = Ck@P (+CPT) | rk = ak - Ck@znew ====
    if (tid<128){
      int a=tid>>3, i0=(tid&7)*4;
      float c0=0.f,c1=0.f,c2=0.f,c3=0.f;
      #pragma unroll
      for (int q=0;q<8;q++){
        float4 ck=*(const float4*)&Ck[a*L6+q*4];
        float4 p0=*(const float4*)&P[(q*4+0)*L6+i0];
        float4 p1=*(const float4*)&P[(q*4+1)*L6+i0];
        float4 p2=*(const float4*)&P[(q*4+2)*L6+i0];
        float4 p3=*(const float4*)&P[(q*4+3)*L6+i0];
        c0+=ck.x*p0.x+ck.y*p1.x+ck.z*p2.x+ck.w*p3.x;
        c1+=ck.x*p0.y+ck.y*p1.y+ck.z*p2.y+ck.w*p3.y;
        c2+=ck.x*p0.z+ck.y*p1.z+ck.z*p2.z+ck.w*p3.z;
        c3+=ck.x*p0.w+ck.y*p1.w+ck.z*p2.w+ck.w*p3.w;
      }
      *(float4*)&CPm[a*L6+i0]=make_float4(c0,c1,c2,c3);
      CPT[(i0+0)*L0+a]=c0; CPT[(i0+1)*L0+a]=c1; CPT[(i0+2)*L0+a]=c2; CPT[(i0+3)*L0+a]=c3;
    } else if (tid<144){
      int a=tid-128;
      float p0=0.f,p1=0.f,p2=0.f,p3=0.f;
      #pragma unroll
      for (int q=0;q<8;q++){
        float4 cv=*(const float4*)&Ck[a*L6+q*4];
        float4 zv=*(const float4*)&znew[q*4];
        p0+=cv.x*zv.x; p1+=cv.y*zv.y; p2+=cv.z*zv.z; p3+=cv.w*zv.w;
      }
      rk[a]=ak[a]-((p0+p1)+(p2+p3));
    }
    __syncthreads();

    // ==== JK (wave0): S -> chol16 -> Linv -> Sinv  (readlane, no divisions) ====
    if (tid<64){
      int lane=tid;
      {
        int a=lane>>2, c0i=(lane&3)*4;
        float r0=0.f,r1=0.f,r2=0.f,r3=0.f;
        #pragma unroll
        for (int q=0;q<8;q++){
          float4 cp=*(const float4*)&CPm[a*L6+q*4];
          float4 v0=*(const float4*)&Ck[(c0i+0)*L6+q*4];
          float4 v1=*(const float4*)&Ck[(c0i+1)*L6+q*4];
          float4 v2=*(const float4*)&Ck[(c0i+2)*L6+q*4];
          float4 v3=*(const float4*)&Ck[(c0i+3)*L6+q*4];
          r0+=cp.x*v0.x+cp.y*v0.y+cp.z*v0.z+cp.w*v0.w;
          r1+=cp.x*v1.x+cp.y*v1.y+cp.z*v1.z+cp.w*v1.w;
          r2+=cp.x*v2.x+cp.y*v2.y+cp.z*v2.z+cp.w*v2.w;
          r3+=cp.x*v3.x+cp.y*v3.y+cp.z*v3.z+cp.w*v3.w;
        }
        float4 rm=*(const float4*)&Rm[a*L0+c0i];
        r0+=rm.x+((a==c0i+0)?1e-4f:0.f);
        r1+=rm.y+((a==c0i+1)?1e-4f:0.f);
        r2+=rm.z+((a==c0i+2)?1e-4f:0.f);
        r3+=rm.w+((a==c0i+3)?1e-4f:0.f);
        *(float4*)&Sm[a*L0+c0i]=make_float4(r0,r1,r2,r3);
      }
      int row=lane<16?lane:15;
      float Sr[16], Lr[16], invd[16];
      #pragma unroll
      for (int q=0;q<4;q++){
        float4 v=*(const float4*)&Sm[row*L0+q*4];
        Sr[q*4+0]=v.x; Sr[q*4+1]=v.y; Sr[q*4+2]=v.z; Sr[q*4+3]=v.w;
      }
      #pragma unroll
      for (int c=0;c<16;c++){
        float v=Sr[c];
        #pragma unroll
        for (int k=0;k<c;k++) v-=Lr[k]*rdlane(Lr[k],c);
        float d=rdlane(v,c);
        float inv=rsqrtf(d);
        invd[c]=inv;
        Lr[c]=(lane==c)?d*inv:v*inv;
      }
      float Li[16];
      #pragma unroll
      for (int r=0;r<16;r++){
        float tv=(lane==r)?1.f:0.f;
        #pragma unroll
        for (int k=0;k<r;k++) tv-=rdlane(Lr[k],r)*Li[k];
        Li[r]=tv*invd[r];
      }
      if (lane<16){
        #pragma unroll
        for (int r=0;r<16;r++) Linv[r*17+lane]=Li[r];
      }
      #pragma unroll
      for (int q=0;q<4;q++){
        int e=lane+64*q; int a2=e>>4, b2=e&15;
        float s=0.f;
        #pragma unroll
        for (int k=0;k<16;k++) s+=Linv[k*17+a2]*Linv[k*17+b2];
        Sinv[a2*L0+b2]=s;
      }
    }
    __syncthreads();

    // ==== M: Kg = CPT@Sinv * mval (+KgT) | S store ====
    if (tid<128){
      int i=tid>>2, a0=(tid&3)*4;
      float c0=0.f,c1=0.f,c2=0.f,c3=0.f;
      #pragma unroll
      for (int q=0;q<4;q++){
        float4 cp=*(const float4*)&CPT[i*L0+q*4];
        float4 s0=*(const float4*)&Sinv[(q*4+0)*L0+a0];
        float4 s1=*(const float4*)&Sinv[(q*4+1)*L0+a0];
        float4 s2=*(const float4*)&Sinv[(q*4+2)*L0+a0];
        float4 s3=*(const float4*)&Sinv[(q*4+3)*L0+a0];
        c0+=cp.x*s0.x+cp.y*s1.x+cp.z*s2.x+cp.w*s3.x;
        c1+=cp.x*s0.y+cp.y*s1.y+cp.z*s2.y+cp.w*s3.y;
        c2+=cp.x*s0.z+cp.y*s1.z+cp.z*s2.z+cp.w*s3.z;
        c3+=cp.x*s0.w+cp.y*s1.w+cp.z*s2.w+cp.w*s3.w;
      }
      float m=mval;
      c0*=m; c1*=m; c2*=m; c3*=m;
      *(float4*)&Kg[i*L0+a0]=make_float4(c0,c1,c2,c3);
      KgT[(a0+0)*L6+i]=c0; KgT[(a0+1)*L6+i]=c1; KgT[(a0+2)*L6+i]=c2; KgT[(a0+3)*L6+i]=c3;
    } else if (tid<192){
      int th=tid-128;
      float4 v=*(const float4*)&Sm[(th>>2)*L0+(th&3)*4];
      *(float4*)&out[off_S+bt*256+th*4]=v;
    }
    __syncthreads();

    // ==== N: IKC (+IKCT) | KgR | zloc ====
    if (tid<256){
      int i=tid>>3, j0=(tid&7)*4;
      float c0=(i==j0+0)?1.f:0.f;
      float c1=(i==j0+1)?1.f:0.f;
      float c2=(i==j0+2)?1.f:0.f;
      float c3=(i==j0+3)?1.f:0.f;
      #pragma unroll
      for (int q=0;q<4;q++){
        float4 kg=*(const float4*)&Kg[i*L0+q*4];
        float4 v0=*(const float4*)&Ck[(q*4+0)*L6+j0];
        float4 v1=*(const float4*)&Ck[(q*4+1)*L6+j0];
        float4 v2=*(const float4*)&Ck[(q*4+2)*L6+j0];
        float4 v3=*(const float4*)&Ck[(q*4+3)*L6+j0];
        c0-=kg.x*v0.x+kg.y*v1.x+kg.z*v2.x+kg.w*v3.x;
        c1-=kg.x*v0.y+kg.y*v1.y+kg.z*v2.y+kg.w*v3.y;
        c2-=kg.x*v0.z+kg.y*v1.z+kg.z*v2.z+kg.w*v3.z;
        c3-=kg.x*v0.w+kg.y*v1.w+kg.z*v2.w+kg.w*v3.w;
      }
      *(float4*)&IKCm[i*L6+j0]=make_float4(c0,c1,c2,c3);
      IKCT[(j0+0)*L6+i]=c0; IKCT[(j0+1)*L6+i]=c1; IKCT[(j0+2)*L6+i]=c2; IKCT[(j0+3)*L6+i]=c3;
    } else if (tid<384){
      int th=tid-256; int i=th>>2, a0=(th&3)*4;
      float c0=0.f,c1=0.f,c2=0.f,c3=0.f;
      #pragma unroll
      for (int q=0;q<4;q++){
        float4 kg=*(const float4*)&Kg[i*L0+q*4];
        float4 v0=*(const float4*)&Rm[(q*4+0)*L0+a0];
        float4 v1=*(const float4*)&Rm[(q*4+1)*L0+a0];
        float4 v2=*(const float4*)&Rm[(q*4+2)*L0+a0];
        float4 v3=*(const float4*)&Rm[(q*4+3)*L0+a0];
        c0+=kg.x*v0.x+kg.y*v1.x+kg.z*v2.x+kg.w*v3.x;
        c1+=kg.x*v0.y+kg.y*v1.y+kg.z*v2.y+kg.w*v3.y;
        c2+=kg.x*v0.z+kg.y*v1.z+kg.z*v2.z+kg.w*v3.z;
        c3+=kg.x*v0.w+kg.y*v1.w+kg.z*v2.w+kg.w*v3.w;
      }
      *(float4*)&KgR[i*L0+a0]=make_float4(c0,c1,c2,c3);
    } else if (tid<416){
      int i=tid-384;
      float s=znew[i];
      #pragma unroll
      for (int a=0;a<16;a++) s+=Kg[i*L0+a]*rk[a];
      zloc[i]=s;
    }
    __syncthreads();

    // ==== OP: T1=IKC@P ; T3=T1@IKCT+KgR@KgT+.001I | zf/zl/zp/af | zc carry ====
    if (tid<128){
      int i0=(tid>>3)*2, j0=(tid&7)*4;
      float a00=0.f,a01=0.f,a02=0.f,a03=0.f,a10=0.f,a11=0.f,a12=0.f,a13=0.f;
      #pragma unroll
      for (int q=0;q<8;q++){
        float4 wa=*(const float4*)&IKCm[i0*L6+q*4];
        float4 wb=*(const float4*)&IKCm[(i0+1)*L6+q*4];
        float4 p0=*(const float4*)&P[(q*4+0)*L6+j0];
        float4 p1=*(const float4*)&P[(q*4+1)*L6+j0];
        float4 p2=*(const float4*)&P[(q*4+2)*L6+j0];
        float4 p3=*(const float4*)&P[(q*4+3)*L6+j0];
        a00+=wa.x*p0.x+wa.y*p1.x+wa.z*p2.x+wa.w*p3.x;
        a01+=wa.x*p0.y+wa.y*p1.y+wa.z*p2.y+wa.w*p3.y;
        a02+=wa.x*p0.z+wa.y*p1.z+wa.z*p2.z+wa.w*p3.z;
        a03+=wa.x*p0.w+wa.y*p1.w+wa.z*p2.w+wa.w*p3.w;
        a10+=wb.x*p0.x+wb.y*p1.x+wb.z*p2.x+wb.w*p3.x;
        a11+=wb.x*p0.y+wb.y*p1.y+wb.z*p2.y+wb.w*p3.y;
        a12+=wb.x*p0.z+wb.y*p1.z+wb.z*p2.z+wb.w*p3.z;
        a13+=wb.x*p0.w+wb.y*p1.w+wb.z*p2.w+wb.w*p3.w;
      }
      *(float4*)&T1[i0*L6+j0]=make_float4(a00,a01,a02,a03);
      *(float4*)&T1[(i0+1)*L6+j0]=make_float4(a10,a11,a12,a13);
      a00=0.f;a01=0.f;a02=0.f;a03=0.f;a10=0.f;a11=0.f;a12=0.f;a13=0.f;
      #pragma unroll
      for (int q=0;q<8;q++){
        float4 wa=*(const float4*)&T1[i0*L6+q*4];
        float4 wb=*(const float4*)&T1[(i0+1)*L6+q*4];
        float4 v0=*(const float4*)&IKCT[(q*4+0)*L6+j0];
        float4 v1=*(const float4*)&IKCT[(q*4+1)*L6+j0];
        float4 v2=*(const float4*)&IKCT[(q*4+2)*L6+j0];
        float4 v3=*(const float4*)&IKCT[(q*4+3)*L6+j0];
        a00+=wa.x*v0.x+wa.y*v1.x+wa.z*v2.x+wa.w*v3.x;
        a01+=wa.x*v0.y+wa.y*v1.y+wa.z*v2.y+wa.w*v3.y;
        a02+=wa.x*v0.z+wa.y*v1.z+wa.z*v2.z+wa.w*v3.z;
        a03+=wa.x*v0.w+wa.y*v1.w+wa.z*v2.w+wa.w*v3.w;
        a10+=wb.x*v0.x+wb.y*v1.x+wb.z*v2.x+wb.w*v3.x;
        a11+=wb.x*v0.y+wb.y*v1.y+wb.z*v2.y+wb.w*v3.y;
        a12+=wb.x*v0.z+wb.y*v1.z+wb.z*v2.z+wb.w*v3.z;
        a13+=wb.x*v0.w+wb.y*v1.w+wb.z*v2.w+wb.w*v3.w;
      }
      #pragma unroll
      for (int q=0;q<4;q++){
        float4 ka=*(const float4*)&KgR[i0*L0+q*4];
        float4 kb=*(const float4*)&KgR[(i0+1)*L0+q*4];
        float4 v0=*(const float4*)&KgT[(q*4+0)*L6+j0];
        float4 v1=*(const float4*)&KgT[(q*4+1)*L6+j0];
        float4 v2=*(const float4*)&KgT[(q*4+2)*L6+j0];
        float4 v3=*(const float4*)&KgT[(q*4+3)*L6+j0];
        a00+=ka.x*v0.x+ka.y*v1.x+ka.z*v2.x+ka.w*v3.x;
        a01+=ka.x*v0.y+ka.y*v1.y+ka.z*v2.y+ka.w*v3.y;
        a02+=ka.x*v0.z+ka.y*v1.z+ka.z*v2.z+ka.w*v3.z;
        a03+=ka.x*v0.w+ka.y*v1.w+ka.z*v2.w+ka.w*v3.w;
        a10+=kb.x*v0.x+kb.y*v1.x+kb.z*v2.x+kb.w*v3.x;
        a11+=kb.x*v0.y+kb.y*v1.y+kb.z*v2.y+kb.w*v3.y;
        a12+=kb.x*v0.z+kb.y*v1.z+kb.z*v2.z+kb.w*v3.z;
        a13+=kb.x*v0.w+kb.y*v1.w+kb.z*v2.w+kb.w*v3.w;
      }
      float d0[4]={a00,a01,a02,a03}, d1[4]={a10,a11,a12,a13};
      #pragma unroll
      for (int q=0;q<4;q++){
        if (i0==j0+q)   d0[q]+=0.001f;
        if (i0+1==j0+q) d1[q]+=0.001f;
      }
      *(float4*)&T3[i0*L6+j0]=make_float4(d0[0],d0[1],d0[2],d0[3]);
      *(float4*)&T3[(i0+1)*L6+j0]=make_float4(d1[0],d1[1],d1[2],d1[3]);
    } else if (tid<160){
      int row=tid-128;
      float zl=zloc[row];
      out[off_zf+bt*32+row]=zl;
      out[off_zl+bt*32+row]=zl;
    } else if (tid<192){
      int i=tid-160;
      float s0=0.f,s1=0.f,s2=0.f,s3=0.f;
      #pragma unroll
      for (int q=0;q<8;q++){
        float4 av=*(const float4*)&Ak[i*L6+q*4];
        float4 zv=*(const float4*)&zloc[q*4];
        s0+=av.x*zv.x; s1+=av.y*zv.y; s2+=av.z*zv.z; s3+=av.w*zv.w;
      }
      float s=(s0+s1)+(s2+s3);
      s+=Bk[i*4+0]*uk[0]+Bk[i*4+1]*uk[1]+Bk[i*4+2]*uk[2]+Bk[i*4+3]*uk[3];
      zpred[i]=s;
      out[off_zp+bt*32+i]=s;
    } else if (tid<208){
      int a=tid-192;
      float s0=0.f,s1=0.f,s2=0.f,s3=0.f;
      #pragma unroll
      for (int q=0;q<8;q++){
        float4 cv=*(const float4*)&Ck[a*L6+q*4];
        float4 zv=*(const float4*)&zloc[q*4];
        s0+=cv.x*zv.x; s1+=cv.y*zv.y; s2+=cv.z*zv.z; s3+=cv.w*zv.w;
      }
      out[off_af+bt*16+a]=(s0+s1)+(s2+s3);
    } else if (tid<240){
      int i=tid-208;
      zc[i]=zloc[i];
    }
    __syncthreads();

    // ==== R: chol32 (wave0, readlane) | Pp=Ak@T3@AkT+Q -> P (waves1-2) | Pf store (wave3) ====
    {
      int wv=tid>>6, lane=tid&63;
      if (wv==0){
        int row=lane<32?lane:31;
        float Pr[32], Lr[32];
        #pragma unroll
        for (int q=0;q<8;q++){
          float4 v=*(const float4*)&T3[row*L6+q*4];
          Pr[q*4+0]=v.x; Pr[q*4+1]=v.y; Pr[q*4+2]=v.z; Pr[q*4+3]=v.w;
        }
        #pragma unroll
        for (int c=0;c<32;c++){
          float v=Pr[c];
          #pragma unroll
          for (int k=0;k<c;k++) v-=Lr[k]*rdlane(Lr[k],c);
          float d=rdlane(v,c);
          float inv=rsqrtf(d);
          Lr[c]=(lane==c)?d*inv:v*inv;
        }
        if (lane<32){
          #pragma unroll
          for (int q=0;q<8;q++){
            float t0=(q*4+0<=lane)?Lr[q*4+0]:0.f;
            float t1=(q*4+1<=lane)?Lr[q*4+1]:0.f;
            float t2=(q*4+2<=lane)?Lr[q*4+2]:0.f;
            float t3=(q*4+3<=lane)?Lr[q*4+3]:0.f;
            *(float4*)&sTril[lane*L6+q*4]=make_float4(t0,t1,t2,t3);
          }
        }
      } else if (wv<3){
        int th=tid-64;
        int i0=(th>>3)*2, j0=(th&7)*4;
        float a00=0.f,a01=0.f,a02=0.f,a03=0.f,a10=0.f,a11=0.f,a12=0.f,a13=0.f;
        #pragma unroll
        for (int q=0;q<8;q++){
          float4 wa=*(const float4*)&Ak[i0*L6+q*4];
          float4 wb=*(const float4*)&Ak[(i0+1)*L6+q*4];
          float4 p0=*(const float4*)&T3[(q*4+0)*L6+j0];
          float4 p1=*(const float4*)&T3[(q*4+1)*L6+j0];
          float4 p2=*(const float4*)&T3[(q*4+2)*L6+j0];
          float4 p3=*(const float4*)&T3[(q*4+3)*L6+j0];
          a00+=wa.x*p0.x+wa.y*p1.x+wa.z*p2.x+wa.w*p3.x;
          a01+=wa.x*p0.y+wa.y*p1.y+wa.z*p2.y+wa.w*p3.y;
          a02+=wa.x*p0.z+wa.y*p1.z+wa.z*p2.z+wa.w*p3.z;
          a03+=wa.x*p0.w+wa.y*p1.w+wa.z*p2.w+wa.w*p3.w;
          a10+=wb.x*p0.x+wb.y*p1.x+wb.z*p2.x+wb.w*p3.x;
          a11+=wb.x*p0.y+wb.y*p1.y+wb.z*p2.y+wb.w*p3.y;
          a12+=wb.x*p0.z+wb.y*p1.z+wb.z*p2.z+wb.w*p3.z;
          a13+=wb.x*p0.w+wb.y*p1.w+wb.z*p2.w+wb.w*p3.w;
        }
        *(float4*)&T1[i0*L6+j0]=make_float4(a00,a01,a02,a03);
        *(float4*)&T1[(i0+1)*L6+j0]=make_float4(a10,a11,a12,a13);
        float4 q0v=*(const float4*)&Qm[i0*L6+j0];
        float4 q1v=*(const float4*)&Qm[(i0+1)*L6+j0];
        float d0[4]={q0v.x,q0v.y,q0v.z,q0v.w}, d1[4]={q1v.x,q1v.y,q1v.z,q1v.w};
        #pragma unroll
        for (int q=0;q<4;q++){
          if (i0==j0+q)   d0[q]+=0.001f;
          if (i0+1==j0+q) d1[q]+=0.001f;
        }
        #pragma unroll
        for (int q=0;q<8;q++){
          float4 wa=*(const float4*)&T1[i0*L6+q*4];
          float4 wb=*(const float4*)&T1[(i0+1)*L6+q*4];
          float4 v0=*(const float4*)&AkT[(q*4+0)*L6+j0];
          float4 v1=*(const float4*)&AkT[(q*4+1)*L6+j0];
          float4 v2=*(const float4*)&AkT[(q*4+2)*L6+j0];
          float4 v3=*(const float4*)&AkT[(q*4+3)*L6+j0];
          d0[0]+=wa.x*v0.x+wa.y*v1.x+wa.z*v2.x+wa.w*v3.x;
          d0[1]+=wa.x*v0.y+wa.y*v1.y+wa.z*v2.y+wa.w*v3.y;
          d0[2]+=wa.x*v0.z+wa.y*v1.z+wa.z*v2.z+wa.w*v3.z;
          d0[3]+=wa.x*v0.w+wa.y*v1.w+wa.z*v2.w+wa.w*v3.w;
          d1[0]+=wb.x*v0.x+wb.y*v1.x+wb.z*v2.x+wb.w*v3.x;
          d1[1]+=wb.x*v0.y+wb.y*v1.y+wb.z*v2.y+wb.w*v3.y;
          d1[2]+=wb.x*v0.z+wb.y*v1.z+wb.z*v2.z+wb.w*v3.z;
          d1[3]+=wb.x*v0.w+wb.y*v1.w+wb.z*v2.w+wb.w*v3.w;
        }
        float4 p0=make_float4(d0[0],d0[1],d0[2],d0[3]);
        float4 p1=make_float4(d1[0],d1[1],d1[2],d1[3]);
        *(float4*)&P[i0*L6+j0]=p0;
        *(float4*)&P[(i0+1)*L6+j0]=p1;
        *(float4*)&out[off_Pp+bt*1024+i0*32+j0]=p0;
        *(float4*)&out[off_Pp+bt*1024+(i0+1)*32+j0]=p1;
      } else if (wv==3 && lane<32){
        int row=lane;
        #pragma unroll
        for (int q=0;q<8;q++){
          float4 v=*(const float4*)&T3[row*L6+q*4];
          *(float4*)&out[off_Pf+bt*1024+row*32+q*4]=v;
        }
      }
    }
    __syncthreads();
  }

  // epilogue: tril and a_pred for t = T-1
  {
    const size_t btL=(size_t)b*T+(T-1);
    for (int e4=tid; e4<256; e4+=NT){
      float4 v=*(const float4*)&sTril[(e4>>3)*L6+(e4&7)*4];
      *(float4*)&out[off_tr+btL*1024+e4*4]=v;
    }
    if (tid<16){
      float s0=0.f,s1=0.f,s2=0.f,s3=0.f;
      #pragma unroll
      for (int q=0;q<8;q++){
        float4 cv=*(const float4*)&Ck[tid*L6+q*4];
        float4 zv=*(const float4*)&zpred[q*4];
        s0+=cv.x*zv.x; s1+=cv.y*zv.y; s2+=cv.z*zv.z; s3+=cv.w*zv.w;
      }
      out[off_ap+btL*16+tid]=(s0+s1)+(s2+s3);
    }
  }
}

extern "C" void kernel_launch(void* const* d_in, const int* in_sizes, int n_in,
                              void* d_out, int out_size, void* d_ws, size_t ws_size,
                              hipStream_t stream) {
  kf_fwd<<<128, NT, 0, stream>>>(
    (const float*)d_in[0],  // a_seq
    (const float*)d_in[1],  // h_obs
    (const float*)d_in[2],  // A_matrices
    (const float*)d_in[3],  // C_matrices
    (const float*)d_in[4],  // B_matrices
    (const float*)d_in[5],  // u_seq
    (const float*)d_in[6],  // mask
    (const float*)d_in[7],  // P_0
    (const float*)d_in[8],  // mat_Q
    (const float*)d_in[9],  // mat_R
    (const float*)d_in[10], // gru_Wx
    (const float*)d_in[11], // gru_Wh
    (const float*)d_in[12], // gru_b
    (const float*)d_in[13], // out_W
    (const float*)d_in[14], // out_b
    (float*)d_out);
}

// Round 7
// 8196.428 us; speedup vs baseline: 2.0525x; 2.0525x over previous
//
#include <hip/hip_runtime.h>
#include <math.h>

#define NT 64

__device__ __forceinline__ float sigf(float x){ return 1.0f/(1.0f+expf(-x)); }
__device__ __forceinline__ float rdlane(float v, int l){
  return __int_as_float(__builtin_amdgcn_readlane(__float_as_int(v), l));
}
__device__ __forceinline__ float dot4(float4 a, float4 b){
  return a.x*b.x + a.y*b.y + a.z*b.z + a.w*b.w;
}

__launch_bounds__(NT, 1)
__global__ void kf_fwd(const float* __restrict__ a_seq, const float* __restrict__ h_obs,
  const float* __restrict__ Amat, const float* __restrict__ Cmat, const float* __restrict__ Bmat,
  const float* __restrict__ u_seq, const float* __restrict__ mask, const float* __restrict__ P0,
  const float* __restrict__ matQ, const float* __restrict__ matR,
  const float* __restrict__ Wx, const float* __restrict__ Wh, const float* __restrict__ gbias,
  const float* __restrict__ outW, const float* __restrict__ outb, float* __restrict__ out)
{
  constexpr int T=256, B=128;
  constexpr int L6=36, L0=20;
  constexpr size_t BT=(size_t)B*T;
  const size_t off_zf=0;
  const size_t off_Pf=off_zf+BT*32;
  const size_t off_zl=off_Pf+BT*1024;
  const size_t off_tr=off_zl+BT*32;
  const size_t off_zp=off_tr+BT*1024;
  const size_t off_Pp=off_zp+BT*32;
  const size_t off_af=off_Pp+BT*1024;
  const size_t off_ap=off_af+BT*16;
  const size_t off_S =off_ap+BT*16;
  const size_t off_al=off_S +BT*256;
  const size_t off_ai=off_al+BT*8;
  const size_t off_R =off_ai+BT*8;
  const size_t off_Q =off_R +256;

  __shared__ __align__(16) float sA[8*32*L6];
  __shared__ __align__(16) float sC[8*16*L6];
  __shared__ __align__(16) float sCA[8*16*L6];
  __shared__ __align__(16) float sBm[1024];
  __shared__ __align__(16) float souWT[512];     // [r][q] = outW[q*8+r]
  __shared__ __align__(16) float sgb[192];
  __shared__ __align__(16) float soutb8[8];
  __shared__ __align__(16) float P[32*L6], Ak[32*L6], AkT[32*L6], IKCm[32*L6], IKCT[32*L6];
  __shared__ __align__(16) float T1m[32*L6], T3m[32*L6], Qm[32*L6];
  __shared__ __align__(16) float Ck[16*L6], CPm[16*L6], KgT[16*L6];
  __shared__ __align__(16) float CPT[32*L0], Kg[32*L0], KgR[32*L0];
  __shared__ __align__(16) float Sm[16*L0], Rm[16*L0], Sinv[16*L0];
  __shared__ __align__(16) float Linv[16*17];
  __shared__ __align__(16) float Bk[128];
  __shared__ __align__(16) float zj[256], aj[128];
  __shared__ __align__(16) float gx[192], ghl[192], xin[192];
  __shared__ __align__(16) float zc[32], znew[32], zloc[32], zpred[32], ghs[64];
  __shared__ __align__(16) float ak[16], uk[4], rk[16], alpha8[8];
  __shared__ float mvs;

  const int lane = threadIdx.x;
  const int b = blockIdx.x;

  // ---------- init (single wave, stride 64; in-wave DS order, no barriers) ----------
  for (int e=lane; e<8192; e+=NT){ int k=e>>10, i=(e>>5)&31, j=e&31; sA[(k*32+i)*L6+j]=Amat[e]; }
  for (int e=lane; e<4096; e+=NT){ int k=e>>9, a=(e>>5)&15, i=e&31; sC[(k*16+a)*L6+i]=Cmat[e]; }
  for (int e=lane; e<1024; e+=NT) sBm[e]=Bmat[e];
  for (int e=lane; e<512; e+=NT){ int r=e>>6, q=e&63; souWT[r*64+q]=outW[q*8+r]; }
  for (int e=lane; e<192; e+=NT) sgb[e]=gbias[e];
  if (lane<8) soutb8[lane]=outb[lane];
  for (int e=lane; e<1024; e+=NT){
    int i=e>>5, j=e&31;
    float s=0.f;
    #pragma unroll 8
    for (int k=0;k<32;k++) s += matQ[i*32+k]*matQ[j*32+k];
    Qm[i*L6+j]=s+(i==j?0.001f:0.f);
    P[i*L6+j]=P0[e];
  }
  for (int e=lane; e<256; e+=NT){
    int i=e>>4, j=e&15;
    float s=0.f;
    #pragma unroll
    for (int k=0;k<16;k++) s += matR[i*16+k]*matR[j*16+k];
    Rm[i*L0+j]=s+(i==j?0.001f:0.f);
  }
  for (int e=lane; e<16*L6; e+=NT) Ck[e]=0.f;   // t=0: aprev = Ck@0 = 0
  if (lane<32) zc[lane]=0.f;
  ghs[lane]=0.f;
  if (lane<16) xin[16+lane]=h_obs[b*16+lane];   // constant slice of x_in
  // CA_k = C_k @ A_k  (reads sC,sA written above by this wave: in-order DS)
  for (int e=lane; e<4096; e+=NT){
    int k=e>>9, a=(e>>5)&15, j=e&31;
    float s=0.f;
    #pragma unroll 8
    for (int i=0;i<32;i++) s += sC[(k*16+a)*L6+i]*sA[(k*32+i)*L6+j];
    sCA[(k*16+a)*L6+j]=s;
  }
  if (b==0){
    for (int e=lane;e<256;e+=NT) out[off_R+e]=Rm[(e>>4)*L0+(e&15)];
    for (int e=lane;e<1024;e+=NT) out[off_Q+e]=Qm[(e>>5)*L6+(e&31)];
  }

  for (int t=0;t<T;t++){
    const size_t bt=(size_t)b*T+t;

    // ---- P0: per-step loads ----
    if (lane<16) ak[lane]=a_seq[bt*16+lane];
    if (lane>=16 && lane<20) uk[lane-16]=u_seq[bt*4+(lane-16)];
    if (lane==20) mvs=mask[bt];

    // preload zc (start-of-step value) into regs
    float4 zq[8];
    #pragma unroll
    for (int q=0;q<8;q++) zq[q]=*(const float4*)&zc[q*4];

    // ---- P1: aprev -> xin[0:16] (uses prev-step Ck) ; xin[32:64]=zc ----
    if (lane<16){
      float s=0.f;
      #pragma unroll
      for (int q=0;q<8;q++) s+=dot4(*(const float4*)&Ck[lane*L6+q*4], zq[q]);
      xin[lane]=s;
    }
    if (lane>=32) xin[lane]=zc[lane-32];

    // ---- P2: zj (4/lane) ; aj (2/lane) -> xin[64:192] ----
    #pragma unroll
    for (int r=0;r<4;r++){
      int e=lane+64*r; int k=e>>5, i=e&31;
      float s=0.f;
      #pragma unroll
      for (int q=0;q<8;q++) s+=dot4(*(const float4*)&sA[(k*32+i)*L6+q*4], zq[q]);
      zj[e]=s;
    }
    #pragma unroll
    for (int r=0;r<2;r++){
      int e=lane+64*r; int k=e>>4, a=e&15;
      float s=0.f;
      #pragma unroll
      for (int q=0;q<8;q++) s+=dot4(*(const float4*)&sCA[(k*16+a)*L6+q*4], zq[q]);
      aj[e]=s; xin[64+e]=s;
    }

    // ---- P3: ghl = ghs @ Wh  (48 lanes, f4 columns) ----
    if (lane<48){
      const int c0=lane*4;
      float4 acc=make_float4(0.f,0.f,0.f,0.f);
      #pragma unroll 2
      for (int q=0;q<16;q++){
        float4 gv=*(const float4*)&ghs[q*4];
        float4 w0=*(const float4*)(Wh+(size_t)(q*4+0)*192+c0);
        float4 w1=*(const float4*)(Wh+(size_t)(q*4+1)*192+c0);
        float4 w2=*(const float4*)(Wh+(size_t)(q*4+2)*192+c0);
        float4 w3=*(const float4*)(Wh+(size_t)(q*4+3)*192+c0);
        acc.x+=gv.x*w0.x+gv.y*w1.x+gv.z*w2.x+gv.w*w3.x;
        acc.y+=gv.x*w0.y+gv.y*w1.y+gv.z*w2.y+gv.w*w3.y;
        acc.z+=gv.x*w0.z+gv.y*w1.z+gv.z*w2.z+gv.w*w3.z;
        acc.w+=gv.x*w0.w+gv.y*w1.w+gv.z*w2.w+gv.w*w3.w;
      }
      *(float4*)&ghl[c0]=acc;
    }

    // ---- P4: gx = x_in @ Wx + b  (48 lanes, f4 columns) ----
    if (lane<48){
      const int c0=lane*4;
      float4 acc=*(const float4*)&sgb[c0];
      #pragma unroll 2
      for (int q=0;q<48;q++){
        float4 xv=*(const float4*)&xin[q*4];
        float4 w0=*(const float4*)(Wx+(size_t)(q*4+0)*192+c0);
        float4 w1=*(const float4*)(Wx+(size_t)(q*4+1)*192+c0);
        float4 w2=*(const float4*)(Wx+(size_t)(q*4+2)*192+c0);
        float4 w3=*(const float4*)(Wx+(size_t)(q*4+3)*192+c0);
        acc.x+=xv.x*w0.x+xv.y*w1.x+xv.z*w2.x+xv.w*w3.x;
        acc.y+=xv.x*w0.y+xv.y*w1.y+xv.z*w2.y+xv.w*w3.y;
        acc.z+=xv.x*w0.z+xv.y*w1.z+xv.z*w2.z+xv.w*w3.z;
        acc.w+=xv.x*w0.w+xv.y*w1.w+xv.z*w2.w+xv.w*w3.w;
      }
      *(float4*)&gx[c0]=acc;
    }

    // ---- P5: ll + alpha_imm (8 lanes, shfl softmax) ----
    if (lane<8){
      float s=0.f;
      #pragma unroll
      for (int q=0;q<4;q++){
        float4 av=*(const float4*)&ak[q*4];
        float4 jv=*(const float4*)&aj[lane*16+q*4];
        float dx=av.x-jv.x, dy=av.y-jv.y, dz=av.z-jv.z, dw=av.w-jv.w;
        s+=dx*dx+dy*dy+dz*dz+dw*dw;
      }
      float llv=-s;
      float m8=llv;
      m8=fmaxf(m8,__shfl_xor(m8,1)); m8=fmaxf(m8,__shfl_xor(m8,2)); m8=fmaxf(m8,__shfl_xor(m8,4));
      float e2=expf(llv-m8);
      float ss=e2;
      ss+=__shfl_xor(ss,1); ss+=__shfl_xor(ss,2); ss+=__shfl_xor(ss,4);
      out[off_ai+bt*8+lane]=e2/ss*mvs;
    }

    // ---- P6: GRU gates (all 64 lanes; gx includes bias) ----
    {
      float r =sigf(gx[lane]+ghl[lane]);
      float zg=sigf(gx[64+lane]+ghl[64+lane]);
      float n =tanhf(gx[128+lane]+r*ghl[128+lane]);
      float h=ghs[lane];
      ghs[lane]=(1.f-zg)*n+zg*h;
    }

    // ---- P7: logits + alpha softmax (8 lanes) ----
    if (lane<8){
      float s=soutb8[lane];
      #pragma unroll
      for (int q=0;q<16;q++){
        float4 g=*(const float4*)&ghs[q*4];
        float4 w=*(const float4*)&souWT[lane*64+q*4];
        s+=dot4(g,w);
      }
      float m8=s;
      m8=fmaxf(m8,__shfl_xor(m8,1)); m8=fmaxf(m8,__shfl_xor(m8,2)); m8=fmaxf(m8,__shfl_xor(m8,4));
      float e2=expf(s-m8);
      float ss=e2;
      ss+=__shfl_xor(ss,1); ss+=__shfl_xor(ss,2); ss+=__shfl_xor(ss,4);
      float av=e2/ss;
      alpha8[lane]=av;
      out[off_al+bt*8+lane]=av;
    }

    // ---- P8: blends Ak(+AkT), Ck, Bk, znew ----
    float alr[8];
    {
      float4 a0=*(const float4*)&alpha8[0], a1=*(const float4*)&alpha8[4];
      alr[0]=a0.x; alr[1]=a0.y; alr[2]=a0.z; alr[3]=a0.w;
      alr[4]=a1.x; alr[5]=a1.y; alr[6]=a1.z; alr[7]=a1.w;
    }
    #pragma unroll
    for (int r=0;r<4;r++){
      int e=lane+64*r; int i=e>>3, qd=e&7;
      float4 acc=make_float4(0.f,0.f,0.f,0.f);
      #pragma unroll
      for (int k=0;k<8;k++){
        float4 av=*(const float4*)&sA[(k*32+i)*L6+qd*4];
        acc.x+=alr[k]*av.x; acc.y+=alr[k]*av.y; acc.z+=alr[k]*av.z; acc.w+=alr[k]*av.w;
      }
      *(float4*)&Ak[i*L6+qd*4]=acc;
      AkT[(qd*4+0)*L6+i]=acc.x; AkT[(qd*4+1)*L6+i]=acc.y;
      AkT[(qd*4+2)*L6+i]=acc.z; AkT[(qd*4+3)*L6+i]=acc.w;
    }
    #pragma unroll
    for (int r=0;r<2;r++){
      int e=lane+64*r; int a=e>>3, qd=e&7;
      float4 acc=make_float4(0.f,0.f,0.f,0.f);
      #pragma unroll
      for (int k=0;k<8;k++){
        float4 cv=*(const float4*)&sC[(k*16+a)*L6+qd*4];
        acc.x+=alr[k]*cv.x; acc.y+=alr[k]*cv.y; acc.z+=alr[k]*cv.z; acc.w+=alr[k]*cv.w;
      }
      *(float4*)&Ck[a*L6+qd*4]=acc;
    }
    #pragma unroll
    for (int r=0;r<2;r++){
      int e=lane+64*r;
      float s=0.f;
      #pragma unroll
      for (int k=0;k<8;k++) s+=alr[k]*sBm[k*128+e];
      Bk[e]=s;
    }
    if (lane<32){
      float s=0.f;
      #pragma unroll
      for (int k=0;k<8;k++) s+=alr[k]*zj[k*32+lane];
      znew[lane]=s;
    }

    // ---- P9: CP = Ck@P (+CPT) ; rk ----
    {
      int qd=lane&7, a0=lane>>3;   // rows a0, a0+8
      float4 d0=make_float4(0.f,0.f,0.f,0.f), d1=d0;
      #pragma unroll 2
      for (int q=0;q<8;q++){
        float4 c0=*(const float4*)&Ck[a0*L6+q*4];
        float4 c1=*(const float4*)&Ck[(a0+8)*L6+q*4];
        float4 p0=*(const float4*)&P[(q*4+0)*L6+qd*4];
        float4 p1=*(const float4*)&P[(q*4+1)*L6+qd*4];
        float4 p2=*(const float4*)&P[(q*4+2)*L6+qd*4];
        float4 p3=*(const float4*)&P[(q*4+3)*L6+qd*4];
        d0.x+=c0.x*p0.x+c0.y*p1.x+c0.z*p2.x+c0.w*p3.x;
        d0.y+=c0.x*p0.y+c0.y*p1.y+c0.z*p2.y+c0.w*p3.y;
        d0.z+=c0.x*p0.z+c0.y*p1.z+c0.z*p2.z+c0.w*p3.z;
        d0.w+=c0.x*p0.w+c0.y*p1.w+c0.z*p2.w+c0.w*p3.w;
        d1.x+=c1.x*p0.x+c1.y*p1.x+c1.z*p2.x+c1.w*p3.x;
        d1.y+=c1.x*p0.y+c1.y*p1.y+c1.z*p2.y+c1.w*p3.y;
        d1.z+=c1.x*p0.z+c1.y*p1.z+c1.z*p2.z+c1.w*p3.z;
        d1.w+=c1.x*p0.w+c1.y*p1.w+c1.z*p2.w+c1.w*p3.w;
      }
      *(float4*)&CPm[a0*L6+qd*4]=d0;
      *(float4*)&CPm[(a0+8)*L6+qd*4]=d1;
      CPT[(qd*4+0)*L0+a0]=d0.x; CPT[(qd*4+1)*L0+a0]=d0.y;
      CPT[(qd*4+2)*L0+a0]=d0.z; CPT[(qd*4+3)*L0+a0]=d0.w;
      CPT[(qd*4+0)*L0+a0+8]=d1.x; CPT[(qd*4+1)*L0+a0+8]=d1.y;
      CPT[(qd*4+2)*L0+a0+8]=d1.z; CPT[(qd*4+3)*L0+a0+8]=d1.w;
    }
    if (lane<16){
      float s=0.f;
      #pragma unroll
      for (int q=0;q<8;q++) s+=dot4(*(const float4*)&Ck[lane*L6+q*4], *(const float4*)&znew[q*4]);
      rk[lane]=ak[lane]-s;
    }

    // ---- P10: S = CP@Ck^T + R + 1e-4 I ; chol16 ; Linv ; Sinv ----
    {
      int a2=lane>>2, cq=lane&3;
      float s0=0.f,s1=0.f,s2=0.f,s3=0.f;
      #pragma unroll 2
      for (int q=0;q<8;q++){
        float4 cp=*(const float4*)&CPm[a2*L6+q*4];
        s0+=dot4(cp,*(const float4*)&Ck[(cq*4+0)*L6+q*4]);
        s1+=dot4(cp,*(const float4*)&Ck[(cq*4+1)*L6+q*4]);
        s2+=dot4(cp,*(const float4*)&Ck[(cq*4+2)*L6+q*4]);
        s3+=dot4(cp,*(const float4*)&Ck[(cq*4+3)*L6+q*4]);
      }
      float4 rm=*(const float4*)&Rm[a2*L0+cq*4];
      s0+=rm.x+((a2==cq*4+0)?1e-4f:0.f);
      s1+=rm.y+((a2==cq*4+1)?1e-4f:0.f);
      s2+=rm.z+((a2==cq*4+2)?1e-4f:0.f);
      s3+=rm.w+((a2==cq*4+3)?1e-4f:0.f);
      float4 sv=make_float4(s0,s1,s2,s3);
      *(float4*)&Sm[a2*L0+cq*4]=sv;
      *(float4*)&out[off_S+bt*256+lane*4]=sv;
    }
    {
      int row=lane<16?lane:15;
      float Sr[16], Lr[16], invd[16];
      #pragma unroll
      for (int q=0;q<4;q++){
        float4 v=*(const float4*)&Sm[row*L0+q*4];
        Sr[q*4+0]=v.x; Sr[q*4+1]=v.y; Sr[q*4+2]=v.z; Sr[q*4+3]=v.w;
      }
      #pragma unroll
      for (int c=0;c<16;c++){
        float v=Sr[c];
        #pragma unroll
        for (int k=0;k<c;k++) v-=Lr[k]*rdlane(Lr[k],c);
        float d=rdlane(v,c);
        float inv=rsqrtf(d);
        invd[c]=inv;
        Lr[c]=(lane==c)?d*inv:v*inv;
      }
      float Li[16];
      #pragma unroll
      for (int r=0;r<16;r++){
        float tv=(lane==r)?1.f:0.f;
        #pragma unroll
        for (int k=0;k<r;k++) tv-=rdlane(Lr[k],r)*Li[k];
        Li[r]=tv*invd[r];
      }
      if (lane<16){
        #pragma unroll
        for (int r=0;r<16;r++) Linv[r*17+lane]=Li[r];
      }
      #pragma unroll
      for (int q=0;q<4;q++){
        int e=lane+64*q; int a2=e>>4, b2=e&15;
        float s=0.f;
        #pragma unroll
        for (int k=0;k<16;k++) s+=Linv[k*17+a2]*Linv[k*17+b2];
        Sinv[a2*L0+b2]=s;
      }
    }

    // ---- P11: Kg = CPT@Sinv * m (+KgT) ; KgR = Kg@R ; zloc ----
    {
      int i0=lane>>2, aq=lane&3;   // rows i0, i0+16
      float4 k0=make_float4(0.f,0.f,0.f,0.f), k1=k0;
      #pragma unroll
      for (int q=0;q<4;q++){
        float4 ca=*(const float4*)&CPT[i0*L0+q*4];
        float4 cb=*(const float4*)&CPT[(i0+16)*L0+q*4];
        float4 v0=*(const float4*)&Sinv[(q*4+0)*L0+aq*4];
        float4 v1=*(const float4*)&Sinv[(q*4+1)*L0+aq*4];
        float4 v2=*(const float4*)&Sinv[(q*4+2)*L0+aq*4];
        float4 v3=*(const float4*)&Sinv[(q*4+3)*L0+aq*4];
        k0.x+=ca.x*v0.x+ca.y*v1.x+ca.z*v2.x+ca.w*v3.x;
        k0.y+=ca.x*v0.y+ca.y*v1.y+ca.z*v2.y+ca.w*v3.y;
        k0.z+=ca.x*v0.z+ca.y*v1.z+ca.z*v2.z+ca.w*v3.z;
        k0.w+=ca.x*v0.w+ca.y*v1.w+ca.z*v2.w+ca.w*v3.w;
        k1.x+=cb.x*v0.x+cb.y*v1.x+cb.z*v2.x+cb.w*v3.x;
        k1.y+=cb.x*v0.y+cb.y*v1.y+cb.z*v2.y+cb.w*v3.y;
        k1.z+=cb.x*v0.z+cb.y*v1.z+cb.z*v2.z+cb.w*v3.z;
        k1.w+=cb.x*v0.w+cb.y*v1.w+cb.z*v2.w+cb.w*v3.w;
      }
      float m=mvs;
      k0.x*=m;k0.y*=m;k0.z*=m;k0.w*=m;
      k1.x*=m;k1.y*=m;k1.z*=m;k1.w*=m;
      *(float4*)&Kg[i0*L0+aq*4]=k0;
      *(float4*)&Kg[(i0+16)*L0+aq*4]=k1;
      KgT[(aq*4+0)*L6+i0]=k0.x; KgT[(aq*4+1)*L6+i0]=k0.y;
      KgT[(aq*4+2)*L6+i0]=k0.z; KgT[(aq*4+3)*L6+i0]=k0.w;
      KgT[(aq*4+0)*L6+i0+16]=k1.x; KgT[(aq*4+1)*L6+i0+16]=k1.y;
      KgT[(aq*4+2)*L6+i0+16]=k1.z; KgT[(aq*4+3)*L6+i0+16]=k1.w;
      // KgR (reads full Kg rows just written by this wave)
      float4 r0=make_float4(0.f,0.f,0.f,0.f), r1=r0;
      #pragma unroll
      for (int q=0;q<4;q++){
        float4 ka=*(const float4*)&Kg[i0*L0+q*4];
        float4 kb=*(const float4*)&Kg[(i0+16)*L0+q*4];
        float4 v0=*(const float4*)&Rm[(q*4+0)*L0+aq*4];
        float4 v1=*(const float4*)&Rm[(q*4+1)*L0+aq*4];
        float4 v2=*(const float4*)&Rm[(q*4+2)*L0+aq*4];
        float4 v3=*(const float4*)&Rm[(q*4+3)*L0+aq*4];
        r0.x+=ka.x*v0.x+ka.y*v1.x+ka.z*v2.x+ka.w*v3.x;
        r0.y+=ka.x*v0.y+ka.y*v1.y+ka.z*v2.y+ka.w*v3.y;
        r0.z+=ka.x*v0.z+ka.y*v1.z+ka.z*v2.z+ka.w*v3.z;
        r0.w+=ka.x*v0.w+ka.y*v1.w+ka.z*v2.w+ka.w*v3.w;
        r1.x+=kb.x*v0.x+kb.y*v1.x+kb.z*v2.x+kb.w*v3.x;
        r1.y+=kb.x*v0.y+kb.y*v1.y+kb.z*v2.y+kb.w*v3.y;
        r1.z+=kb.x*v0.z+kb.y*v1.z+kb.z*v2.z+kb.w*v3.z;
        r1.w+=kb.x*v0.w+kb.y*v1.w+kb.z*v2.w+kb.w*v3.w;
      }
      *(float4*)&KgR[i0*L0+aq*4]=r0;
      *(float4*)&KgR[(i0+16)*L0+aq*4]=r1;
    }
    if (lane<32){
      float s=znew[lane];
      #pragma unroll
      for (int q=0;q<4;q++)
        s+=dot4(*(const float4*)&Kg[lane*L0+q*4], *(const float4*)&rk[q*4]);
      zloc[lane]=s;
    }

    // ---- P12: IKC = I - Kg@Ck (+IKCT) ----
    {
      int jq=lane&7, i0=lane>>3;   // rows i0, i0+8, i0+16, i0+24
      float4 A0,A1,A2,A3;
      {
        int base=jq*4;
        A0=make_float4((i0==base+0)?1.f:0.f,(i0==base+1)?1.f:0.f,(i0==base+2)?1.f:0.f,(i0==base+3)?1.f:0.f);
        A1=make_float4((i0+8==base+0)?1.f:0.f,(i0+8==base+1)?1.f:0.f,(i0+8==base+2)?1.f:0.f,(i0+8==base+3)?1.f:0.f);
        A2=make_float4((i0+16==base+0)?1.f:0.f,(i0+16==base+1)?1.f:0.f,(i0+16==base+2)?1.f:0.f,(i0+16==base+3)?1.f:0.f);
        A3=make_float4((i0+24==base+0)?1.f:0.f,(i0+24==base+1)?1.f:0.f,(i0+24==base+2)?1.f:0.f,(i0+24==base+3)?1.f:0.f);
      }
      #pragma unroll
      for (int q=0;q<4;q++){
        float4 ka=*(const float4*)&Kg[(i0   )*L0+q*4];
        float4 kb=*(const float4*)&Kg[(i0+ 8)*L0+q*4];
        float4 kc=*(const float4*)&Kg[(i0+16)*L0+q*4];
        float4 kd=*(const float4*)&Kg[(i0+24)*L0+q*4];
        float4 c0=*(const float4*)&Ck[(q*4+0)*L6+jq*4];
        float4 c1=*(const float4*)&Ck[(q*4+1)*L6+jq*4];
        float4 c2=*(const float4*)&Ck[(q*4+2)*L6+jq*4];
        float4 c3=*(const float4*)&Ck[(q*4+3)*L6+jq*4];
        A0.x-=ka.x*c0.x+ka.y*c1.x+ka.z*c2.x+ka.w*c3.x;
        A0.y-=ka.x*c0.y+ka.y*c1.y+ka.z*c2.y+ka.w*c3.y;
        A0.z-=ka.x*c0.z+ka.y*c1.z+ka.z*c2.z+ka.w*c3.z;
        A0.w-=ka.x*c0.w+ka.y*c1.w+ka.z*c2.w+ka.w*c3.w;
        A1.x-=kb.x*c0.x+kb.y*c1.x+kb.z*c2.x+kb.w*c3.x;
        A1.y-=kb.x*c0.y+kb.y*c1.y+kb.z*c2.y+kb.w*c3.y;
        A1.z-=kb.x*c0.z+kb.y*c1.z+kb.z*c2.z+kb.w*c3.z;
        A1.w-=kb.x*c0.w+kb.y*c1.w+kb.z*c2.w+kb.w*c3.w;
        A2.x-=kc.x*c0.x+kc.y*c1.x+kc.z*c2.x+kc.w*c3.x;
        A2.y-=kc.x*c0.y+kc.y*c1.y+kc.z*c2.y+kc.w*c3.y;
        A2.z-=kc.x*c0.z+kc.y*c1.z+kc.z*c2.z+kc.w*c3.z;
        A2.w-=kc.x*c0.w+kc.y*c1.w+kc.z*c2.w+kc.w*c3.w;
        A3.x-=kd.x*c0.x+kd.y*c1.x+kd.z*c2.x+kd.w*c3.x;
        A3.y-=kd.x*c0.y+kd.y*c1.y+kd.z*c2.y+kd.w*c3.y;
        A3.z-=kd.x*c0.z+kd.y*c1.z+kd.z*c2.z+kd.w*c3.z;
        A3.w-=kd.x*c0.w+kd.y*c1.w+kd.z*c2.w+kd.w*c3.w;
      }
      *(float4*)&IKCm[(i0   )*L6+jq*4]=A0;
      *(float4*)&IKCm[(i0+ 8)*L6+jq*4]=A1;
      *(float4*)&IKCm[(i0+16)*L6+jq*4]=A2;
      *(float4*)&IKCm[(i0+24)*L6+jq*4]=A3;
      IKCT[(jq*4+0)*L6+i0]=A0.x; IKCT[(jq*4+1)*L6+i0]=A0.y; IKCT[(jq*4+2)*L6+i0]=A0.z; IKCT[(jq*4+3)*L6+i0]=A0.w;
      IKCT[(jq*4+0)*L6+i0+8]=A1.x; IKCT[(jq*4+1)*L6+i0+8]=A1.y; IKCT[(jq*4+2)*L6+i0+8]=A1.z; IKCT[(jq*4+3)*L6+i0+8]=A1.w;
      IKCT[(jq*4+0)*L6+i0+16]=A2.x; IKCT[(jq*4+1)*L6+i0+16]=A2.y; IKCT[(jq*4+2)*L6+i0+16]=A2.z; IKCT[(jq*4+3)*L6+i0+16]=A2.w;
      IKCT[(jq*4+0)*L6+i0+24]=A3.x; IKCT[(jq*4+1)*L6+i0+24]=A3.y; IKCT[(jq*4+2)*L6+i0+24]=A3.z; IKCT[(jq*4+3)*L6+i0+24]=A3.w;
    }

    // ---- P13: T1 = IKC@P ; T3 = T1@IKCT + KgR@KgT + .001I ----
    {
      const int i=lane>>1, h=lane&1, j0=h*16;
      float4 q0=make_float4(0.f,0.f,0.f,0.f), q1=q0, q2=q0, q3=q0;
      #pragma unroll 2
      for (int q=0;q<8;q++){
        float4 av=*(const float4*)&IKCm[i*L6+q*4];
        #pragma unroll
        for (int c=0;c<4;c++){
          float u=(c==0)?av.x:((c==1)?av.y:((c==2)?av.z:av.w));
          int j=q*4+c;
          float4 b0=*(const float4*)&P[j*L6+j0];
          float4 b1=*(const float4*)&P[j*L6+j0+4];
          float4 b2=*(const float4*)&P[j*L6+j0+8];
          float4 b3=*(const float4*)&P[j*L6+j0+12];
          q0.x+=u*b0.x; q0.y+=u*b0.y; q0.z+=u*b0.z; q0.w+=u*b0.w;
          q1.x+=u*b1.x; q1.y+=u*b1.y; q1.z+=u*b1.z; q1.w+=u*b1.w;
          q2.x+=u*b2.x; q2.y+=u*b2.y; q2.z+=u*b2.z; q2.w+=u*b2.w;
          q3.x+=u*b3.x; q3.y+=u*b3.y; q3.z+=u*b3.z; q3.w+=u*b3.w;
        }
      }
      *(float4*)&T1m[i*L6+j0   ]=q0;
      *(float4*)&T1m[i*L6+j0+ 4]=q1;
      *(float4*)&T1m[i*L6+j0+ 8]=q2;
      *(float4*)&T1m[i*L6+j0+12]=q3;
    }
    {
      const int i=lane>>1, h=lane&1, j0=h*16;
      float4 q0=make_float4(0.f,0.f,0.f,0.f), q1=q0, q2=q0, q3=q0;
      #pragma unroll 2
      for (int q=0;q<8;q++){
        float4 av=*(const float4*)&T1m[i*L6+q*4];
        #pragma unroll
        for (int c=0;c<4;c++){
          float u=(c==0)?av.x:((c==1)?av.y:((c==2)?av.z:av.w));
          int j=q*4+c;
          float4 b0=*(const float4*)&IKCT[j*L6+j0];
          float4 b1=*(const float4*)&IKCT[j*L6+j0+4];
          float4 b2=*(const float4*)&IKCT[j*L6+j0+8];
          float4 b3=*(const float4*)&IKCT[j*L6+j0+12];
          q0.x+=u*b0.x; q0.y+=u*b0.y; q0.z+=u*b0.z; q0.w+=u*b0.w;
          q1.x+=u*b1.x; q1.y+=u*b1.y; q1.z+=u*b1.z; q1.w+=u*b1.w;
          q2.x+=u*b2.x; q2.y+=u*b2.y; q2.z+=u*b2.z; q2.w+=u*b2.w;
          q3.x+=u*b3.x; q3.y+=u*b3.y; q3.z+=u*b3.z; q3.w+=u*b3.w;
        }
      }
      #pragma unroll
      for (int q=0;q<4;q++){
        float4 kv=*(const float4*)&KgR[i*L0+q*4];
        #pragma unroll
        for (int c=0;c<4;c++){
          float u=(c==0)?kv.x:((c==1)?kv.y:((c==2)?kv.z:kv.w));
          int j=q*4+c;
          float4 b0=*(const float4*)&KgT[j*L6+j0];
          float4 b1=*(const float4*)&KgT[j*L6+j0+4];
          float4 b2=*(const float4*)&KgT[j*L6+j0+8];
          float4 b3=*(const float4*)&KgT[j*L6+j0+12];
          q0.x+=u*b0.x; q0.y+=u*b0.y; q0.z+=u*b0.z; q0.w+=u*b0.w;
          q1.x+=u*b1.x; q1.y+=u*b1.y; q1.z+=u*b1.z; q1.w+=u*b1.w;
          q2.x+=u*b2.x; q2.y+=u*b2.y; q2.z+=u*b2.z; q2.w+=u*b2.w;
          q3.x+=u*b3.x; q3.y+=u*b3.y; q3.z+=u*b3.z; q3.w+=u*b3.w;
        }
      }
      int d=i-j0;
      q0.x+=(d==0)?1e-3f:0.f; q0.y+=(d==1)?1e-3f:0.f; q0.z+=(d==2)?1e-3f:0.f; q0.w+=(d==3)?1e-3f:0.f;
      q1.x+=(d==4)?1e-3f:0.f; q1.y+=(d==5)?1e-3f:0.f; q1.z+=(d==6)?1e-3f:0.f; q1.w+=(d==7)?1e-3f:0.f;
      q2.x+=(d==8)?1e-3f:0.f; q2.y+=(d==9)?1e-3f:0.f; q2.z+=(d==10)?1e-3f:0.f; q2.w+=(d==11)?1e-3f:0.f;
      q3.x+=(d==12)?1e-3f:0.f; q3.y+=(d==13)?1e-3f:0.f; q3.z+=(d==14)?1e-3f:0.f; q3.w+=(d==15)?1e-3f:0.f;
      *(float4*)&T3m[i*L6+j0   ]=q0;
      *(float4*)&T3m[i*L6+j0+ 4]=q1;
      *(float4*)&T3m[i*L6+j0+ 8]=q2;
      *(float4*)&T3m[i*L6+j0+12]=q3;
    }

    // ---- P14: zf/zl/zp/af stores ; zpred ; zc carry ; Pf store ----
    {
      float4 zl4[8];
      if (lane<32){
        float zl=zloc[lane];
        out[off_zf+bt*32+lane]=zl;
        out[off_zl+bt*32+lane]=zl;
      }
      #pragma unroll
      for (int q=0;q<8;q++) zl4[q]=*(const float4*)&zloc[q*4];
      if (lane<32){
        float s=0.f;
        #pragma unroll
        for (int q=0;q<8;q++) s+=dot4(*(const float4*)&Ak[lane*L6+q*4], zl4[q]);
        float4 bk=*(const float4*)&Bk[lane*4];
        float4 u4=*(const float4*)&uk[0];
        s+=dot4(bk,u4);
        zpred[lane]=s;
        out[off_zp+bt*32+lane]=s;
        zc[lane]=zloc[lane];
      }
      if (lane>=32 && lane<48){
        int a=lane-32;
        float s=0.f;
        #pragma unroll
        for (int q=0;q<8;q++) s+=dot4(*(const float4*)&Ck[a*L6+q*4], zl4[q]);
        out[off_af+bt*16+a]=s;
      }
      #pragma unroll
      for (int r=0;r<4;r++){
        int e=lane+64*r;
        *(float4*)&out[off_Pf+bt*1024+e*4]=*(const float4*)&T3m[(e>>3)*L6+(e&7)*4];
      }
    }

    // ---- P15: chol32(T3) -> tril store (direct from regs) ----
    {
      int row=lane<32?lane:31;
      float Pr[32], Lr[32];
      #pragma unroll
      for (int q=0;q<8;q++){
        float4 v=*(const float4*)&T3m[row*L6+q*4];
        Pr[q*4+0]=v.x; Pr[q*4+1]=v.y; Pr[q*4+2]=v.z; Pr[q*4+3]=v.w;
      }
      #pragma unroll
      for (int c=0;c<32;c++){
        float v=Pr[c];
        #pragma unroll
        for (int k=0;k<c;k++) v-=Lr[k]*rdlane(Lr[k],c);
        float d=rdlane(v,c);
        float inv=rsqrtf(d);
        Lr[c]=(lane==c)?d*inv:v*inv;
      }
      if (lane<32){
        #pragma unroll
        for (int q=0;q<8;q++){
          float t0=(q*4+0<=lane)?Lr[q*4+0]:0.f;
          float t1=(q*4+1<=lane)?Lr[q*4+1]:0.f;
          float t2=(q*4+2<=lane)?Lr[q*4+2]:0.f;
          float t3=(q*4+3<=lane)?Lr[q*4+3]:0.f;
          *(float4*)&out[off_tr+bt*1024+lane*32+q*4]=make_float4(t0,t1,t2,t3);
        }
      }
    }

    // ---- P16: M3 = Ak@T3 -> T1m ; Pp = M3@AkT + Q + .001I -> P (+store) ----
    {
      const int i=lane>>1, h=lane&1, j0=h*16;
      float4 q0=make_float4(0.f,0.f,0.f,0.f), q1=q0, q2=q0, q3=q0;
      #pragma unroll 2
      for (int q=0;q<8;q++){
        float4 av=*(const float4*)&Ak[i*L6+q*4];
        #pragma unroll
        for (int c=0;c<4;c++){
          float u=(c==0)?av.x:((c==1)?av.y:((c==2)?av.z:av.w));
          int j=q*4+c;
          float4 b0=*(const float4*)&T3m[j*L6+j0];
          float4 b1=*(const float4*)&T3m[j*L6+j0+4];
          float4 b2=*(const float4*)&T3m[j*L6+j0+8];
          float4 b3=*(const float4*)&T3m[j*L6+j0+12];
          q0.x+=u*b0.x; q0.y+=u*b0.y; q0.z+=u*b0.z; q0.w+=u*b0.w;
          q1.x+=u*b1.x; q1.y+=u*b1.y; q1.z+=u*b1.z; q1.w+=u*b1.w;
          q2.x+=u*b2.x; q2.y+=u*b2.y; q2.z+=u*b2.z; q2.w+=u*b2.w;
          q3.x+=u*b3.x; q3.y+=u*b3.y; q3.z+=u*b3.z; q3.w+=u*b3.w;
        }
      }
      *(float4*)&T1m[i*L6+j0   ]=q0;
      *(float4*)&T1m[i*L6+j0+ 4]=q1;
      *(float4*)&T1m[i*L6+j0+ 8]=q2;
      *(float4*)&T1m[i*L6+j0+12]=q3;
    }
    {
      const int i=lane>>1, h=lane&1, j0=h*16;
      float4 q0=*(const float4*)&Qm[i*L6+j0];
      float4 q1=*(const float4*)&Qm[i*L6+j0+4];
      float4 q2=*(const float4*)&Qm[i*L6+j0+8];
      float4 q3=*(const float4*)&Qm[i*L6+j0+12];
      int d=i-j0;
      q0.x+=(d==0)?1e-3f:0.f; q0.y+=(d==1)?1e-3f:0.f; q0.z+=(d==2)?1e-3f:0.f; q0.w+=(d==3)?1e-3f:0.f;
      q1.x+=(d==4)?1e-3f:0.f; q1.y+=(d==5)?1e-3f:0.f; q1.z+=(d==6)?1e-3f:0.f; q1.w+=(d==7)?1e-3f:0.f;
      q2.x+=(d==8)?1e-3f:0.f; q2.y+=(d==9)?1e-3f:0.f; q2.z+=(d==10)?1e-3f:0.f; q2.w+=(d==11)?1e-3f:0.f;
      q3.x+=(d==12)?1e-3f:0.f; q3.y+=(d==13)?1e-3f:0.f; q3.z+=(d==14)?1e-3f:0.f; q3.w+=(d==15)?1e-3f:0.f;
      #pragma unroll 2
      for (int q=0;q<8;q++){
        float4 av=*(const float4*)&T1m[i*L6+q*4];
        #pragma unroll
        for (int c=0;c<4;c++){
          float u=(c==0)?av.x:((c==1)?av.y:((c==2)?av.z:av.w));
          int j=q*4+c;
          float4 b0=*(const float4*)&AkT[j*L6+j0];
          float4 b1=*(const float4*)&AkT[j*L6+j0+4];
          float4 b2=*(const float4*)&AkT[j*L6+j0+8];
          float4 b3=*(const float4*)&AkT[j*L6+j0+12];
          q0.x+=u*b0.x; q0.y+=u*b0.y; q0.z+=u*b0.z; q0.w+=u*b0.w;
          q1.x+=u*b1.x; q1.y+=u*b1.y; q1.z+=u*b1.z; q1.w+=u*b1.w;
          q2.x+=u*b2.x; q2.y+=u*b2.y; q2.z+=u*b2.z; q2.w+=u*b2.w;
          q3.x+=u*b3.x; q3.y+=u*b3.y; q3.z+=u*b3.z; q3.w+=u*b3.w;
        }
      }
      *(float4*)&P[i*L6+j0   ]=q0;
      *(float4*)&P[i*L6+j0+ 4]=q1;
      *(float4*)&P[i*L6+j0+ 8]=q2;
      *(float4*)&P[i*L6+j0+12]=q3;
      *(float4*)&out[off_Pp+bt*1024+i*32+j0   ]=q0;
      *(float4*)&out[off_Pp+bt*1024+i*32+j0+ 4]=q1;
      *(float4*)&out[off_Pp+bt*1024+i*32+j0+ 8]=q2;
      *(float4*)&out[off_Pp+bt*1024+i*32+j0+12]=q3;
    }

    // ---- P17: a_pred ----
    if (lane<16){
      float s=0.f;
      #pragma unroll
      for (int q=0;q<8;q++)
        s+=dot4(*(const float4*)&Ck[lane*L6+q*4], *(const float4*)&zpred[q*4]);
      out[off_ap+bt*16+lane]=s;
    }
  }
}

extern "C" void kernel_launch(void* const* d_in, const int* in_sizes, int n_in,
                              void* d_out, int out_size, void* d_ws, size_t ws_size,
                              hipStream_t stream) {
  kf_fwd<<<128, NT, 0, stream>>>(
    (const float*)d_in[0],  // a_seq
    (const float*)d_in[1],  // h_obs
    (const float*)d_in[2],  // A_matrices
    (const float*)d_in[3],  // C_matrices
    (const float*)d_in[4],  // B_matrices
    (const float*)d_in[5],  // u_seq
    (const float*)d_in[6],  // mask
    (const float*)d_in[7],  // P_0
    (const float*)d_in[8],  // mat_Q
    (const float*)d_in[9],  // mat_R
    (const float*)d_in[10], // gru_Wx
    (const float*)d_in[11], // gru_Wh
    (const float*)d_in[12], // gru_b
    (const float*)d_in[13], // out_W
    (const float*)d_in[14], // out_b
    (float*)d_out);
}

// Round 8
// 5681.901 us; speedup vs baseline: 2.9609x; 1.4426x over previous
//
#include <hip/hip_runtime.h>
#include <math.h>

#define NT 64
#define FMA4(acc,u,bv) {acc.x+=(u)*(bv).x; acc.y+=(u)*(bv).y; acc.z+=(u)*(bv).z; acc.w+=(u)*(bv).w;}

__device__ __forceinline__ float sigf(float x){ return 1.0f/(1.0f+expf(-x)); }
__device__ __forceinline__ float rdlane(float v, int l){
  return __int_as_float(__builtin_amdgcn_readlane(__float_as_int(v), l));
}
__device__ __forceinline__ float dot4(float4 a, float4 b){
  return a.x*b.x + a.y*b.y + a.z*b.z + a.w*b.w;
}

__launch_bounds__(NT, 1)
__global__ void kf_fwd(const float* __restrict__ a_seq, const float* __restrict__ h_obs,
  const float* __restrict__ Amat, const float* __restrict__ Cmat, const float* __restrict__ Bmat,
  const float* __restrict__ u_seq, const float* __restrict__ mask, const float* __restrict__ P0,
  const float* __restrict__ matQ, const float* __restrict__ matR,
  const float* __restrict__ Wx, const float* __restrict__ Wh, const float* __restrict__ gbias,
  const float* __restrict__ outW, const float* __restrict__ outb, float* __restrict__ out)
{
  constexpr int T=256, B=128;
  constexpr int L6=36, L0=20;
  constexpr size_t BT=(size_t)B*T;
  const size_t off_zf=0;
  const size_t off_Pf=off_zf+BT*32;
  const size_t off_zl=off_Pf+BT*1024;
  const size_t off_tr=off_zl+BT*32;
  const size_t off_zp=off_tr+BT*1024;
  const size_t off_Pp=off_zp+BT*32;
  const size_t off_af=off_Pp+BT*1024;
  const size_t off_ap=off_af+BT*16;
  const size_t off_S =off_ap+BT*16;
  const size_t off_al=off_S +BT*256;
  const size_t off_ai=off_al+BT*8;
  const size_t off_R =off_ai+BT*8;
  const size_t off_Q =off_R +256;

  __shared__ __align__(16) float sA[8*32*L6];
  __shared__ __align__(16) float sC[8*16*L6];
  __shared__ __align__(16) float W12[48*192];    // rows 0-31: Wx[32:64]+M ; rows 32-47: Wx[0:16]
  __shared__ __align__(16) float gxh[192];       // gbias + hobs@Wx[16:32]
  __shared__ __align__(16) float sBm[1024];
  __shared__ __align__(16) float souWT[512];
  __shared__ __align__(16) float soutb8[8];
  __shared__ __align__(16) float P[32*L6], Ak[32*L6], AkT[32*L6], IKCm[32*L6], IKCT[32*L6];
  __shared__ __align__(16) float T1m[32*L6], T3m[32*L6], Qm[32*L6];
  __shared__ __align__(16) float Ck[16*L6], CPm[16*L6], KgT[16*L6];
  __shared__ __align__(16) float CPT[32*L0], Kg[32*L0], KgR[32*L0];
  __shared__ __align__(16) float Sm[16*L0], Rm[16*L0], Sinv[16*L0];
  __shared__ __align__(16) float Linv[16*17];
  __shared__ __align__(16) float Bk[128];
  __shared__ __align__(16) float zj[256], aj[128];
  __shared__ __align__(16) float gx[192], ghl[192];
  __shared__ __align__(16) float zc[32], znew[32], zloc[32], zpred[32], ghs[64];
  __shared__ __align__(16) float aprevv[16], hob[16];
  __shared__ __align__(16) float ak[16], uk[4], rk[16], alpha8[8];
  __shared__ float mvs;

  const int lane = threadIdx.x;
  const int b = blockIdx.x;

  // ---------- init ----------
  for (int e=lane; e<8192; e+=NT){ int k=e>>10, i=(e>>5)&31, j=e&31; sA[(k*32+i)*L6+j]=Amat[e]; }
  for (int e=lane; e<4096; e+=NT){ int k=e>>9, a=(e>>5)&15, i=e&31; sC[(k*16+a)*L6+i]=Cmat[e]; }
  for (int e=lane; e<1024; e+=NT) sBm[e]=Bmat[e];
  for (int e=lane; e<512; e+=NT){ int r=e>>6, q=e&63; souWT[r*64+q]=outW[q*8+r]; }
  if (lane<8) soutb8[lane]=outb[lane];
  for (int e=lane; e<1024; e+=NT){
    int i=e>>5, j=e&31;
    float s=0.f;
    #pragma unroll 8
    for (int k=0;k<32;k++) s += matQ[i*32+k]*matQ[j*32+k];
    Qm[i*L6+j]=s+(i==j?0.001f:0.f);
    P[i*L6+j]=P0[e];
  }
  for (int e=lane; e<256; e+=NT){
    int i=e>>4, j=e&15;
    float s=0.f;
    #pragma unroll
    for (int k=0;k<16;k++) s += matR[i*16+k]*matR[j*16+k];
    Rm[i*L0+j]=s+(i==j?0.001f:0.f);
  }
  for (int e=lane; e<16*L6; e+=NT) Ck[e]=0.f;   // t=0: aprev = 0
  if (lane<32) zc[lane]=0.f;
  ghs[lane]=0.f;
  if (lane<16) hob[lane]=h_obs[b*16+lane];

  // W1 rows + gxh
  if (lane<48){
    const int c0=lane*4;
    #pragma unroll
    for (int a=0;a<16;a++)
      *(float4*)&W12[(32+a)*192+c0] = *(const float4*)(Wx+(size_t)a*192+c0);
    float4 acc=*(const float4*)(gbias+c0);
    #pragma unroll
    for (int i=0;i<16;i++){
      float4 w=*(const float4*)(Wx+(size_t)(16+i)*192+c0);
      float hv=hob[i];
      FMA4(acc,hv,w);
    }
    *(float4*)&gxh[c0]=acc;
  }
  // W2 = Wx[32:64] + M,  M = sum_k CA_k^T @ Wx[64+16k : 80+16k]
  for (int ic=0; ic<4; ++ic){
    float4 Mi[8];
    if (lane<48){
      const int c0=lane*4;
      #pragma unroll
      for (int ii=0;ii<8;ii++)
        Mi[ii]=*(const float4*)(Wx+(size_t)(32+ic*8+ii)*192+c0);
    }
    for (int k=0;k<8;k++){
      // CA chunk into Kg[0:128]: CA[a][i], i=ic*8+ii
      #pragma unroll
      for (int r=0;r<2;r++){
        int e=lane+64*r; int a=e>>3, ii=e&7; int i=ic*8+ii;
        float s=0.f;
        #pragma unroll 8
        for (int j=0;j<32;j++) s+=sC[(k*16+a)*L6+j]*sA[(k*32+j)*L6+i];
        Kg[a*8+ii]=s;
      }
      if (lane<48){
        const int c0=lane*4;
        #pragma unroll
        for (int a=0;a<16;a++){
          float4 w=*(const float4*)(Wx+(size_t)(64+16*k+a)*192+c0);
          #pragma unroll
          for (int ii=0;ii<8;ii++){
            float ca=Kg[a*8+ii];
            FMA4(Mi[ii],ca,w);
          }
        }
      }
    }
    if (lane<48){
      const int c0=lane*4;
      #pragma unroll
      for (int ii=0;ii<8;ii++)
        *(float4*)&W12[(ic*8+ii)*192+c0]=Mi[ii];
    }
  }
  if (b==0){
    for (int e=lane;e<256;e+=NT) out[off_R+e]=Rm[(e>>4)*L0+(e&15)];
    for (int e=lane;e<1024;e+=NT) out[off_Q+e]=Qm[(e>>5)*L6+(e&31)];
  }

  for (int t=0;t<T;t++){
    const size_t bt=(size_t)b*T+t;

    // ---- P0: per-step loads ----
    if (lane<16) ak[lane]=a_seq[bt*16+lane];
    if (lane>=16 && lane<20) uk[lane-16]=u_seq[bt*4+(lane-16)];
    if (lane==20) mvs=mask[bt];

    // ---- P3: ghl = ghs @ Wh (issue early; L2 latency hides under P1/P2/P4) ----
    if (lane<48){
      const int c0=lane*4;
      float4 A0=make_float4(0.f,0.f,0.f,0.f), A1=A0, A2=A0, A3=A0;
      #pragma unroll
      for (int q=0;q<16;q++){
        float4 gv=*(const float4*)&ghs[q*4];
        float4 w0=*(const float4*)(Wh+(size_t)(q*4+0)*192+c0);
        float4 w1=*(const float4*)(Wh+(size_t)(q*4+1)*192+c0);
        float4 w2=*(const float4*)(Wh+(size_t)(q*4+2)*192+c0);
        float4 w3=*(const float4*)(Wh+(size_t)(q*4+3)*192+c0);
        FMA4(A0,gv.x,w0); FMA4(A1,gv.y,w1); FMA4(A2,gv.z,w2); FMA4(A3,gv.w,w3);
      }
      float4 g=make_float4(A0.x+A1.x+A2.x+A3.x, A0.y+A1.y+A2.y+A3.y,
                           A0.z+A1.z+A2.z+A3.z, A0.w+A1.w+A2.w+A3.w);
      *(float4*)&ghl[c0]=g;
    }

    float4 zq[8];
    #pragma unroll
    for (int q=0;q<8;q++) zq[q]=*(const float4*)&zc[q*4];

    // ---- P1: aprev (prev-step Ck) ----
    if (lane<16){
      float s=0.f;
      #pragma unroll
      for (int q=0;q<8;q++) s+=dot4(*(const float4*)&Ck[lane*L6+q*4], zq[q]);
      aprevv[lane]=s;
    }

    // ---- P2: zj (4/lane) then aj = C_k @ zj_k (2/lane) ----
    #pragma unroll
    for (int r=0;r<4;r++){
      int e=lane+64*r; int k=e>>5, i=e&31;
      float s=0.f;
      #pragma unroll
      for (int q=0;q<8;q++) s+=dot4(*(const float4*)&sA[(k*32+i)*L6+q*4], zq[q]);
      zj[e]=s;
    }
    #pragma unroll
    for (int r=0;r<2;r++){
      int e=lane+64*r; int k=e>>4, a=e&15;
      float s=0.f;
      #pragma unroll
      for (int q=0;q<8;q++) s+=dot4(*(const float4*)&sC[(k*16+a)*L6+q*4], *(const float4*)&zj[k*32+q*4]);
      aj[e]=s;
    }

    // ---- P4: gx = gxh + zc@W2 + aprev@W1  (all LDS) ----
    if (lane<48){
      const int c0=lane*4;
      float4 A0=*(const float4*)&gxh[c0];
      float4 A1=make_float4(0.f,0.f,0.f,0.f), A2=A1, A3=A1;
      #pragma unroll
      for (int q=0;q<8;q++){
        float4 zv=zq[q];
        float4 w0=*(const float4*)&W12[(q*4+0)*192+c0];
        float4 w1=*(const float4*)&W12[(q*4+1)*192+c0];
        float4 w2=*(const float4*)&W12[(q*4+2)*192+c0];
        float4 w3=*(const float4*)&W12[(q*4+3)*192+c0];
        FMA4(A0,zv.x,w0); FMA4(A1,zv.y,w1); FMA4(A2,zv.z,w2); FMA4(A3,zv.w,w3);
      }
      #pragma unroll
      for (int q=0;q<4;q++){
        float4 av=*(const float4*)&aprevv[q*4];
        float4 w0=*(const float4*)&W12[(32+q*4+0)*192+c0];
        float4 w1=*(const float4*)&W12[(32+q*4+1)*192+c0];
        float4 w2=*(const float4*)&W12[(32+q*4+2)*192+c0];
        float4 w3=*(const float4*)&W12[(32+q*4+3)*192+c0];
        FMA4(A0,av.x,w0); FMA4(A1,av.y,w1); FMA4(A2,av.z,w2); FMA4(A3,av.w,w3);
      }
      float4 g=make_float4(A0.x+A1.x+A2.x+A3.x, A0.y+A1.y+A2.y+A3.y,
                           A0.z+A1.z+A2.z+A3.z, A0.w+A1.w+A2.w+A3.w);
      *(float4*)&gx[c0]=g;
    }

    // ---- P5: ll + alpha_imm ----
    if (lane<8){
      float s=0.f;
      #pragma unroll
      for (int q=0;q<4;q++){
        float4 av=*(const float4*)&ak[q*4];
        float4 jv=*(const float4*)&aj[lane*16+q*4];
        float dx=av.x-jv.x, dy=av.y-jv.y, dz=av.z-jv.z, dw=av.w-jv.w;
        s+=dx*dx+dy*dy+dz*dz+dw*dw;
      }
      float llv=-s;
      float m8=llv;
      m8=fmaxf(m8,__shfl_xor(m8,1)); m8=fmaxf(m8,__shfl_xor(m8,2)); m8=fmaxf(m8,__shfl_xor(m8,4));
      float e2=expf(llv-m8);
      float ss=e2;
      ss+=__shfl_xor(ss,1); ss+=__shfl_xor(ss,2); ss+=__shfl_xor(ss,4);
      out[off_ai+bt*8+lane]=e2/ss*mvs;
    }

    // ---- P6: GRU gates ----
    {
      float r =sigf(gx[lane]+ghl[lane]);
      float zg=sigf(gx[64+lane]+ghl[64+lane]);
      float n =tanhf(gx[128+lane]+r*ghl[128+lane]);
      float h=ghs[lane];
      ghs[lane]=(1.f-zg)*n+zg*h;
    }

    // ---- P7: logits + alpha ----
    if (lane<8){
      float s=soutb8[lane];
      #pragma unroll
      for (int q=0;q<16;q++){
        float4 g=*(const float4*)&ghs[q*4];
        float4 w=*(const float4*)&souWT[lane*64+q*4];
        s+=dot4(g,w);
      }
      float m8=s;
      m8=fmaxf(m8,__shfl_xor(m8,1)); m8=fmaxf(m8,__shfl_xor(m8,2)); m8=fmaxf(m8,__shfl_xor(m8,4));
      float e2=expf(s-m8);
      float ss=e2;
      ss+=__shfl_xor(ss,1); ss+=__shfl_xor(ss,2); ss+=__shfl_xor(ss,4);
      float av=e2/ss;
      alpha8[lane]=av;
      out[off_al+bt*8+lane]=av;
    }

    // ---- P8: blends ----
    float alr[8];
    {
      float4 a0=*(const float4*)&alpha8[0], a1=*(const float4*)&alpha8[4];
      alr[0]=a0.x; alr[1]=a0.y; alr[2]=a0.z; alr[3]=a0.w;
      alr[4]=a1.x; alr[5]=a1.y; alr[6]=a1.z; alr[7]=a1.w;
    }
    #pragma unroll
    for (int r=0;r<4;r++){
      int e=lane+64*r; int i=e>>3, qd=e&7;
      float4 acc=make_float4(0.f,0.f,0.f,0.f);
      #pragma unroll
      for (int k=0;k<8;k++){
        float4 av=*(const float4*)&sA[(k*32+i)*L6+qd*4];
        FMA4(acc,alr[k],av);
      }
      *(float4*)&Ak[i*L6+qd*4]=acc;
      AkT[(qd*4+0)*L6+i]=acc.x; AkT[(qd*4+1)*L6+i]=acc.y;
      AkT[(qd*4+2)*L6+i]=acc.z; AkT[(qd*4+3)*L6+i]=acc.w;
    }
    #pragma unroll
    for (int r=0;r<2;r++){
      int e=lane+64*r; int a=e>>3, qd=e&7;
      float4 acc=make_float4(0.f,0.f,0.f,0.f);
      #pragma unroll
      for (int k=0;k<8;k++){
        float4 cv=*(const float4*)&sC[(k*16+a)*L6+qd*4];
        FMA4(acc,alr[k],cv);
      }
      *(float4*)&Ck[a*L6+qd*4]=acc;
    }
    #pragma unroll
    for (int r=0;r<2;r++){
      int e=lane+64*r;
      float s=0.f;
      #pragma unroll
      for (int k=0;k<8;k++) s+=alr[k]*sBm[k*128+e];
      Bk[e]=s;
    }
    if (lane<32){
      float s=0.f;
      #pragma unroll
      for (int k=0;k<8;k++) s+=alr[k]*zj[k*32+lane];
      znew[lane]=s;
    }

    // ---- P9: CP = Ck@P (+CPT) ; rk ----
    {
      int qd=lane&7, a0=lane>>3;
      float4 d0=make_float4(0.f,0.f,0.f,0.f), d1=d0;
      #pragma unroll 2
      for (int q=0;q<8;q++){
        float4 c0=*(const float4*)&Ck[a0*L6+q*4];
        float4 c1=*(const float4*)&Ck[(a0+8)*L6+q*4];
        float4 p0=*(const float4*)&P[(q*4+0)*L6+qd*4];
        float4 p1=*(const float4*)&P[(q*4+1)*L6+qd*4];
        float4 p2=*(const float4*)&P[(q*4+2)*L6+qd*4];
        float4 p3=*(const float4*)&P[(q*4+3)*L6+qd*4];
        FMA4(d0,c0.x,p0); FMA4(d0,c0.y,p1); FMA4(d0,c0.z,p2); FMA4(d0,c0.w,p3);
        FMA4(d1,c1.x,p0); FMA4(d1,c1.y,p1); FMA4(d1,c1.z,p2); FMA4(d1,c1.w,p3);
      }
      *(float4*)&CPm[a0*L6+qd*4]=d0;
      *(float4*)&CPm[(a0+8)*L6+qd*4]=d1;
      CPT[(qd*4+0)*L0+a0]=d0.x; CPT[(qd*4+1)*L0+a0]=d0.y;
      CPT[(qd*4+2)*L0+a0]=d0.z; CPT[(qd*4+3)*L0+a0]=d0.w;
      CPT[(qd*4+0)*L0+a0+8]=d1.x; CPT[(qd*4+1)*L0+a0+8]=d1.y;
      CPT[(qd*4+2)*L0+a0+8]=d1.z; CPT[(qd*4+3)*L0+a0+8]=d1.w;
    }
    if (lane<16){
      float s=0.f;
      #pragma unroll
      for (int q=0;q<8;q++) s+=dot4(*(const float4*)&Ck[lane*L6+q*4], *(const float4*)&znew[q*4]);
      rk[lane]=ak[lane]-s;
    }

    // ---- P10: S ; chol16 ; Linv ; Sinv ----
    {
      int a2=lane>>2, cq=lane&3;
      float s0=0.f,s1=0.f,s2=0.f,s3=0.f;
      #pragma unroll 2
      for (int q=0;q<8;q++){
        float4 cp=*(const float4*)&CPm[a2*L6+q*4];
        s0+=dot4(cp,*(const float4*)&Ck[(cq*4+0)*L6+q*4]);
        s1+=dot4(cp,*(const float4*)&Ck[(cq*4+1)*L6+q*4]);
        s2+=dot4(cp,*(const float4*)&Ck[(cq*4+2)*L6+q*4]);
        s3+=dot4(cp,*(const float4*)&Ck[(cq*4+3)*L6+q*4]);
      }
      float4 rm=*(const float4*)&Rm[a2*L0+cq*4];
      s0+=rm.x+((a2==cq*4+0)?1e-4f:0.f);
      s1+=rm.y+((a2==cq*4+1)?1e-4f:0.f);
      s2+=rm.z+((a2==cq*4+2)?1e-4f:0.f);
      s3+=rm.w+((a2==cq*4+3)?1e-4f:0.f);
      float4 sv=make_float4(s0,s1,s2,s3);
      *(float4*)&Sm[a2*L0+cq*4]=sv;
      *(float4*)&out[off_S+bt*256+lane*4]=sv;
    }
    {
      int row=lane<16?lane:15;
      float Sr[16], Lr[16], invd[16];
      #pragma unroll
      for (int q=0;q<4;q++){
        float4 v=*(const float4*)&Sm[row*L0+q*4];
        Sr[q*4+0]=v.x; Sr[q*4+1]=v.y; Sr[q*4+2]=v.z; Sr[q*4+3]=v.w;
      }
      #pragma unroll
      for (int c=0;c<16;c++){
        float v=Sr[c];
        #pragma unroll
        for (int k=0;k<c;k++) v-=Lr[k]*rdlane(Lr[k],c);
        float d=rdlane(v,c);
        float inv=rsqrtf(d);
        invd[c]=inv;
        Lr[c]=(lane==c)?d*inv:v*inv;
      }
      float Li[16];
      #pragma unroll
      for (int r=0;r<16;r++){
        float tv=(lane==r)?1.f:0.f;
        #pragma unroll
        for (int k=0;k<r;k++) tv-=rdlane(Lr[k],r)*Li[k];
        Li[r]=tv*invd[r];
      }
      if (lane<16){
        #pragma unroll
        for (int r=0;r<16;r++) Linv[r*17+lane]=Li[r];
      }
      #pragma unroll
      for (int q=0;q<4;q++){
        int e=lane+64*q; int a2=e>>4, b2=e&15;
        float s=0.f;
        #pragma unroll
        for (int k=0;k<16;k++) s+=Linv[k*17+a2]*Linv[k*17+b2];
        Sinv[a2*L0+b2]=s;
      }
    }

    // ---- P11: Kg (+KgT) ; KgR ; zloc ----
    {
      int i0=lane>>2, aq=lane&3;
      float4 k0=make_float4(0.f,0.f,0.f,0.f), k1=k0;
      #pragma unroll
      for (int q=0;q<4;q++){
        float4 ca=*(const float4*)&CPT[i0*L0+q*4];
        float4 cb=*(const float4*)&CPT[(i0+16)*L0+q*4];
        float4 v0=*(const float4*)&Sinv[(q*4+0)*L0+aq*4];
        float4 v1=*(const float4*)&Sinv[(q*4+1)*L0+aq*4];
        float4 v2=*(const float4*)&Sinv[(q*4+2)*L0+aq*4];
        float4 v3=*(const float4*)&Sinv[(q*4+3)*L0+aq*4];
        FMA4(k0,ca.x,v0); FMA4(k0,ca.y,v1); FMA4(k0,ca.z,v2); FMA4(k0,ca.w,v3);
        FMA4(k1,cb.x,v0); FMA4(k1,cb.y,v1); FMA4(k1,cb.z,v2); FMA4(k1,cb.w,v3);
      }
      float m=mvs;
      k0.x*=m;k0.y*=m;k0.z*=m;k0.w*=m;
      k1.x*=m;k1.y*=m;k1.z*=m;k1.w*=m;
      *(float4*)&Kg[i0*L0+aq*4]=k0;
      *(float4*)&Kg[(i0+16)*L0+aq*4]=k1;
      KgT[(aq*4+0)*L6+i0]=k0.x; KgT[(aq*4+1)*L6+i0]=k0.y;
      KgT[(aq*4+2)*L6+i0]=k0.z; KgT[(aq*4+3)*L6+i0]=k0.w;
      KgT[(aq*4+0)*L6+i0+16]=k1.x; KgT[(aq*4+1)*L6+i0+16]=k1.y;
      KgT[(aq*4+2)*L6+i0+16]=k1.z; KgT[(aq*4+3)*L6+i0+16]=k1.w;
      float4 r0=make_float4(0.f,0.f,0.f,0.f), r1=r0;
      #pragma unroll
      for (int q=0;q<4;q++){
        float4 ka=*(const float4*)&Kg[i0*L0+q*4];
        float4 kb=*(const float4*)&Kg[(i0+16)*L0+q*4];
        float4 v0=*(const float4*)&Rm[(q*4+0)*L0+aq*4];
        float4 v1=*(const float4*)&Rm[(q*4+1)*L0+aq*4];
        float4 v2=*(const float4*)&Rm[(q*4+2)*L0+aq*4];
        float4 v3=*(const float4*)&Rm[(q*4+3)*L0+aq*4];
        FMA4(r0,ka.x,v0); FMA4(r0,ka.y,v1); FMA4(r0,ka.z,v2); FMA4(r0,ka.w,v3);
        FMA4(r1,kb.x,v0); FMA4(r1,kb.y,v1); FMA4(r1,kb.z,v2); FMA4(r1,kb.w,v3);
      }
      *(float4*)&KgR[i0*L0+aq*4]=r0;
      *(float4*)&KgR[(i0+16)*L0+aq*4]=r1;
    }
    if (lane<32){
      float s=znew[lane];
      #pragma unroll
      for (int q=0;q<4;q++)
        s+=dot4(*(const float4*)&Kg[lane*L0+q*4], *(const float4*)&rk[q*4]);
      zloc[lane]=s;
    }

    // ---- P12: IKC = I - Kg@Ck (+IKCT) ----
    {
      int jq=lane&7, i0=lane>>3;
      float4 A0,A1,A2,A3;
      {
        int base=jq*4;
        A0=make_float4((i0==base+0)?1.f:0.f,(i0==base+1)?1.f:0.f,(i0==base+2)?1.f:0.f,(i0==base+3)?1.f:0.f);
        A1=make_float4((i0+8==base+0)?1.f:0.f,(i0+8==base+1)?1.f:0.f,(i0+8==base+2)?1.f:0.f,(i0+8==base+3)?1.f:0.f);
        A2=make_float4((i0+16==base+0)?1.f:0.f,(i0+16==base+1)?1.f:0.f,(i0+16==base+2)?1.f:0.f,(i0+16==base+3)?1.f:0.f);
        A3=make_float4((i0+24==base+0)?1.f:0.f,(i0+24==base+1)?1.f:0.f,(i0+24==base+2)?1.f:0.f,(i0+24==base+3)?1.f:0.f);
      }
      #pragma unroll
      for (int q=0;q<4;q++){
        float4 ka=*(const float4*)&Kg[(i0   )*L0+q*4];
        float4 kb=*(const float4*)&Kg[(i0+ 8)*L0+q*4];
        float4 kc=*(const float4*)&Kg[(i0+16)*L0+q*4];
        float4 kd=*(const float4*)&Kg[(i0+24)*L0+q*4];
        float4 c0=*(const float4*)&Ck[(q*4+0)*L6+jq*4];
        float4 c1=*(const float4*)&Ck[(q*4+1)*L6+jq*4];
        float4 c2=*(const float4*)&Ck[(q*4+2)*L6+jq*4];
        float4 c3=*(const float4*)&Ck[(q*4+3)*L6+jq*4];
        FMA4(A0,-ka.x,c0); FMA4(A0,-ka.y,c1); FMA4(A0,-ka.z,c2); FMA4(A0,-ka.w,c3);
        FMA4(A1,-kb.x,c0); FMA4(A1,-kb.y,c1); FMA4(A1,-kb.z,c2); FMA4(A1,-kb.w,c3);
        FMA4(A2,-kc.x,c0); FMA4(A2,-kc.y,c1); FMA4(A2,-kc.z,c2); FMA4(A2,-kc.w,c3);
        FMA4(A3,-kd.x,c0); FMA4(A3,-kd.y,c1); FMA4(A3,-kd.z,c2); FMA4(A3,-kd.w,c3);
      }
      *(float4*)&IKCm[(i0   )*L6+jq*4]=A0;
      *(float4*)&IKCm[(i0+ 8)*L6+jq*4]=A1;
      *(float4*)&IKCm[(i0+16)*L6+jq*4]=A2;
      *(float4*)&IKCm[(i0+24)*L6+jq*4]=A3;
      IKCT[(jq*4+0)*L6+i0]=A0.x; IKCT[(jq*4+1)*L6+i0]=A0.y; IKCT[(jq*4+2)*L6+i0]=A0.z; IKCT[(jq*4+3)*L6+i0]=A0.w;
      IKCT[(jq*4+0)*L6+i0+8]=A1.x; IKCT[(jq*4+1)*L6+i0+8]=A1.y; IKCT[(jq*4+2)*L6+i0+8]=A1.z; IKCT[(jq*4+3)*L6+i0+8]=A1.w;
      IKCT[(jq*4+0)*L6+i0+16]=A2.x; IKCT[(jq*4+1)*L6+i0+16]=A2.y; IKCT[(jq*4+2)*L6+i0+16]=A2.z; IKCT[(jq*4+3)*L6+i0+16]=A2.w;
      IKCT[(jq*4+0)*L6+i0+24]=A3.x; IKCT[(jq*4+1)*L6+i0+24]=A3.y; IKCT[(jq*4+2)*L6+i0+24]=A3.z; IKCT[(jq*4+3)*L6+i0+24]=A3.w;
    }

    // ---- P13: T1 = IKC@P (4x4 tiles) ; T3 = T1@IKCT + KgR@KgT + .001I (4x4) ----
    {
      const int i0=(lane>>3)*4, j0=(lane&7)*4;
      float4 q0=make_float4(0.f,0.f,0.f,0.f), q1=q0, q2=q0, q3=q0;
      #pragma unroll 2
      for (int q=0;q<8;q++){
        float4 a0=*(const float4*)&IKCm[(i0+0)*L6+q*4];
        float4 a1=*(const float4*)&IKCm[(i0+1)*L6+q*4];
        float4 a2=*(const float4*)&IKCm[(i0+2)*L6+q*4];
        float4 a3=*(const float4*)&IKCm[(i0+3)*L6+q*4];
        float4 bv;
        bv=*(const float4*)&P[(q*4+0)*L6+j0];
        FMA4(q0,a0.x,bv); FMA4(q1,a1.x,bv); FMA4(q2,a2.x,bv); FMA4(q3,a3.x,bv);
        bv=*(const float4*)&P[(q*4+1)*L6+j0];
        FMA4(q0,a0.y,bv); FMA4(q1,a1.y,bv); FMA4(q2,a2.y,bv); FMA4(q3,a3.y,bv);
        bv=*(const float4*)&P[(q*4+2)*L6+j0];
        FMA4(q0,a0.z,bv); FMA4(q1,a1.z,bv); FMA4(q2,a2.z,bv); FMA4(q3,a3.z,bv);
        bv=*(const float4*)&P[(q*4+3)*L6+j0];
        FMA4(q0,a0.w,bv); FMA4(q1,a1.w,bv); FMA4(q2,a2.w,bv); FMA4(q3,a3.w,bv);
      }
      *(float4*)&T1m[(i0+0)*L6+j0]=q0;
      *(float4*)&T1m[(i0+1)*L6+j0]=q1;
      *(float4*)&T1m[(i0+2)*L6+j0]=q2;
      *(float4*)&T1m[(i0+3)*L6+j0]=q3;
    }
    {
      const int i0=(lane>>3)*4, j0=(lane&7)*4;
      float4 q0=make_float4(0.f,0.f,0.f,0.f), q1=q0, q2=q0, q3=q0;
      #pragma unroll 2
      for (int q=0;q<8;q++){
        float4 a0=*(const float4*)&T1m[(i0+0)*L6+q*4];
        float4 a1=*(const float4*)&T1m[(i0+1)*L6+q*4];
        float4 a2=*(const float4*)&T1m[(i0+2)*L6+q*4];
        float4 a3=*(const float4*)&T1m[(i0+3)*L6+q*4];
        float4 bv;
        bv=*(const float4*)&IKCT[(q*4+0)*L6+j0];
        FMA4(q0,a0.x,bv); FMA4(q1,a1.x,bv); FMA4(q2,a2.x,bv); FMA4(q3,a3.x,bv);
        bv=*(const float4*)&IKCT[(q*4+1)*L6+j0];
        FMA4(q0,a0.y,bv); FMA4(q1,a1.y,bv); FMA4(q2,a2.y,bv); FMA4(q3,a3.y,bv);
        bv=*(const float4*)&IKCT[(q*4+2)*L6+j0];
        FMA4(q0,a0.z,bv); FMA4(q1,a1.z,bv); FMA4(q2,a2.z,bv); FMA4(q3,a3.z,bv);
        bv=*(const float4*)&IKCT[(q*4+3)*L6+j0];
        FMA4(q0,a0.w,bv); FMA4(q1,a1.w,bv); FMA4(q2,a2.w,bv); FMA4(q3,a3.w,bv);
      }
      #pragma unroll
      for (int q=0;q<4;q++){
        float4 a0=*(const float4*)&KgR[(i0+0)*L0+q*4];
        float4 a1=*(const float4*)&KgR[(i0+1)*L0+q*4];
        float4 a2=*(const float4*)&KgR[(i0+2)*L0+q*4];
        float4 a3=*(const float4*)&KgR[(i0+3)*L0+q*4];
        float4 bv;
        bv=*(const float4*)&KgT[(q*4+0)*L6+j0];
        FMA4(q0,a0.x,bv); FMA4(q1,a1.x,bv); FMA4(q2,a2.x,bv); FMA4(q3,a3.x,bv);
        bv=*(const float4*)&KgT[(q*4+1)*L6+j0];
        FMA4(q0,a0.y,bv); FMA4(q1,a1.y,bv); FMA4(q2,a2.y,bv); FMA4(q3,a3.y,bv);
        bv=*(const float4*)&KgT[(q*4+2)*L6+j0];
        FMA4(q0,a0.z,bv); FMA4(q1,a1.z,bv); FMA4(q2,a2.z,bv); FMA4(q3,a3.z,bv);
        bv=*(const float4*)&KgT[(q*4+3)*L6+j0];
        FMA4(q0,a0.w,bv); FMA4(q1,a1.w,bv); FMA4(q2,a2.w,bv); FMA4(q3,a3.w,bv);
      }
      int d0=i0-j0;
      if (d0>=0&&d0<4){ if(d0==0)q0.x+=1e-3f; else if(d0==1)q0.y+=1e-3f; else if(d0==2)q0.z+=1e-3f; else q0.w+=1e-3f; }
      int d1=i0+1-j0;
      if (d1>=0&&d1<4){ if(d1==0)q1.x+=1e-3f; else if(d1==1)q1.y+=1e-3f; else if(d1==2)q1.z+=1e-3f; else q1.w+=1e-3f; }
      int d2=i0+2-j0;
      if (d2>=0&&d2<4){ if(d2==0)q2.x+=1e-3f; else if(d2==1)q2.y+=1e-3f; else if(d2==2)q2.z+=1e-3f; else q2.w+=1e-3f; }
      int d3=i0+3-j0;
      if (d3>=0&&d3<4){ if(d3==0)q3.x+=1e-3f; else if(d3==1)q3.y+=1e-3f; else if(d3==2)q3.z+=1e-3f; else q3.w+=1e-3f; }
      *(float4*)&T3m[(i0+0)*L6+j0]=q0;
      *(float4*)&T3m[(i0+1)*L6+j0]=q1;
      *(float4*)&T3m[(i0+2)*L6+j0]=q2;
      *(float4*)&T3m[(i0+3)*L6+j0]=q3;
    }

    // ---- P14: zf/zl/zp/af ; zpred ; zc carry ; Pf store ----
    {
      float4 zl4[8];
      if (lane<32){
        float zl=zloc[lane];
        out[off_zf+bt*32+lane]=zl;
        out[off_zl+bt*32+lane]=zl;
      }
      #pragma unroll
      for (int q=0;q<8;q++) zl4[q]=*(const float4*)&zloc[q*4];
      if (lane<32){
        float s=0.f;
        #pragma unroll
        for (int q=0;q<8;q++) s+=dot4(*(const float4*)&Ak[lane*L6+q*4], zl4[q]);
        float4 bk=*(const float4*)&Bk[lane*4];
        float4 u4=*(const float4*)&uk[0];
        s+=dot4(bk,u4);
        zpred[lane]=s;
        out[off_zp+bt*32+lane]=s;
        zc[lane]=zloc[lane];
      }
      if (lane>=32 && lane<48){
        int a=lane-32;
        float s=0.f;
        #pragma unroll
        for (int q=0;q<8;q++) s+=dot4(*(const float4*)&Ck[a*L6+q*4], zl4[q]);
        out[off_af+bt*16+a]=s;
      }
      #pragma unroll
      for (int r=0;r<4;r++){
        int e=lane+64*r;
        *(float4*)&out[off_Pf+bt*1024+e*4]=*(const float4*)&T3m[(e>>3)*L6+(e&7)*4];
      }
    }

    // ---- P15: chol32(T3) -> tril ----
    {
      int row=lane<32?lane:31;
      float Pr[32], Lr[32];
      #pragma unroll
      for (int q=0;q<8;q++){
        float4 v=*(const float4*)&T3m[row*L6+q*4];
        Pr[q*4+0]=v.x; Pr[q*4+1]=v.y; Pr[q*4+2]=v.z; Pr[q*4+3]=v.w;
      }
      #pragma unroll
      for (int c=0;c<32;c++){
        float v=Pr[c];
        #pragma unroll
        for (int k=0;k<c;k++) v-=Lr[k]*rdlane(Lr[k],c);
        float d=rdlane(v,c);
        float inv=rsqrtf(d);
        Lr[c]=(lane==c)?d*inv:v*inv;
      }
      if (lane<32){
        #pragma unroll
        for (int q=0;q<8;q++){
          float t0=(q*4+0<=lane)?Lr[q*4+0]:0.f;
          float t1=(q*4+1<=lane)?Lr[q*4+1]:0.f;
          float t2=(q*4+2<=lane)?Lr[q*4+2]:0.f;
          float t3=(q*4+3<=lane)?Lr[q*4+3]:0.f;
          *(float4*)&out[off_tr+bt*1024+lane*32+q*4]=make_float4(t0,t1,t2,t3);
        }
      }
    }

    // ---- P16: M3 = Ak@T3 (4x4) -> T1m ; Pp = M3@AkT + Q + .001I (4x4) -> P + store ----
    {
      const int i0=(lane>>3)*4, j0=(lane&7)*4;
      float4 q0=make_float4(0.f,0.f,0.f,0.f), q1=q0, q2=q0, q3=q0;
      #pragma unroll 2
      for (int q=0;q<8;q++){
        float4 a0=*(const float4*)&Ak[(i0+0)*L6+q*4];
        float4 a1=*(const float4*)&Ak[(i0+1)*L6+q*4];
        float4 a2=*(const float4*)&Ak[(i0+2)*L6+q*4];
        float4 a3=*(const float4*)&Ak[(i0+3)*L6+q*4];
        float4 bv;
        bv=*(const float4*)&T3m[(q*4+0)*L6+j0];
        FMA4(q0,a0.x,bv); FMA4(q1,a1.x,bv); FMA4(q2,a2.x,bv); FMA4(q3,a3.x,bv);
        bv=*(const float4*)&T3m[(q*4+1)*L6+j0];
        FMA4(q0,a0.y,bv); FMA4(q1,a1.y,bv); FMA4(q2,a2.y,bv); FMA4(q3,a3.y,bv);
        bv=*(const float4*)&T3m[(q*4+2)*L6+j0];
        FMA4(q0,a0.z,bv); FMA4(q1,a1.z,bv); FMA4(q2,a2.z,bv); FMA4(q3,a3.z,bv);
        bv=*(const float4*)&T3m[(q*4+3)*L6+j0];
        FMA4(q0,a0.w,bv); FMA4(q1,a1.w,bv); FMA4(q2,a2.w,bv); FMA4(q3,a3.w,bv);
      }
      *(float4*)&T1m[(i0+0)*L6+j0]=q0;
      *(float4*)&T1m[(i0+1)*L6+j0]=q1;
      *(float4*)&T1m[(i0+2)*L6+j0]=q2;
      *(float4*)&T1m[(i0+3)*L6+j0]=q3;
    }
    {
      const int i0=(lane>>3)*4, j0=(lane&7)*4;
      float4 q0=*(const float4*)&Qm[(i0+0)*L6+j0];
      float4 q1=*(const float4*)&Qm[(i0+1)*L6+j0];
      float4 q2=*(const float4*)&Qm[(i0+2)*L6+j0];
      float4 q3=*(const float4*)&Qm[(i0+3)*L6+j0];
      int d0=i0-j0;
      if (d0>=0&&d0<4){ if(d0==0)q0.x+=1e-3f; else if(d0==1)q0.y+=1e-3f; else if(d0==2)q0.z+=1e-3f; else q0.w+=1e-3f; }
      int d1=i0+1-j0;
      if (d1>=0&&d1<4){ if(d1==0)q1.x+=1e-3f; else if(d1==1)q1.y+=1e-3f; else if(d1==2)q1.z+=1e-3f; else q1.w+=1e-3f; }
      int d2=i0+2-j0;
      if (d2>=0&&d2<4){ if(d2==0)q2.x+=1e-3f; else if(d2==1)q2.y+=1e-3f; else if(d2==2)q2.z+=1e-3f; else q2.w+=1e-3f; }
      int d3=i0+3-j0;
      if (d3>=0&&d3<4){ if(d3==0)q3.x+=1e-3f; else if(d3==1)q3.y+=1e-3f; else if(d3==2)q3.z+=1e-3f; else q3.w+=1e-3f; }
      #pragma unroll 2
      for (int q=0;q<8;q++){
        float4 a0=*(const float4*)&T1m[(i0+0)*L6+q*4];
        float4 a1=*(const float4*)&T1m[(i0+1)*L6+q*4];
        float4 a2=*(const float4*)&T1m[(i0+2)*L6+q*4];
        float4 a3=*(const float4*)&T1m[(i0+3)*L6+q*4];
        float4 bv;
        bv=*(const float4*)&AkT[(q*4+0)*L6+j0];
        FMA4(q0,a0.x,bv); FMA4(q1,a1.x,bv); FMA4(q2,a2.x,bv); FMA4(q3,a3.x,bv);
        bv=*(const float4*)&AkT[(q*4+1)*L6+j0];
        FMA4(q0,a0.y,bv); FMA4(q1,a1.y,bv); FMA4(q2,a2.y,bv); FMA4(q3,a3.y,bv);
        bv=*(const float4*)&AkT[(q*4+2)*L6+j0];
        FMA4(q0,a0.z,bv); FMA4(q1,a1.z,bv); FMA4(q2,a2.z,bv); FMA4(q3,a3.z,bv);
        bv=*(const float4*)&AkT[(q*4+3)*L6+j0];
        FMA4(q0,a0.w,bv); FMA4(q1,a1.w,bv); FMA4(q2,a2.w,bv); FMA4(q3,a3.w,bv);
      }
      *(float4*)&P[(i0+0)*L6+j0]=q0;
      *(float4*)&P[(i0+1)*L6+j0]=q1;
      *(float4*)&P[(i0+2)*L6+j0]=q2;
      *(float4*)&P[(i0+3)*L6+j0]=q3;
      *(float4*)&out[off_Pp+bt*1024+(i0+0)*32+j0]=q0;
      *(float4*)&out[off_Pp+bt*1024+(i0+1)*32+j0]=q1;
      *(float4*)&out[off_Pp+bt*1024+(i0+2)*32+j0]=q2;
      *(float4*)&out[off_Pp+bt*1024+(i0+3)*32+j0]=q3;
    }

    // ---- P17: a_pred ----
    if (lane<16){
      float s=0.f;
      #pragma unroll
      for (int q=0;q<8;q++)
        s+=dot4(*(const float4*)&Ck[lane*L6+q*4], *(const float4*)&zpred[q*4]);
      out[off_ap+bt*16+lane]=s;
    }
  }
}

extern "C" void kernel_launch(void* const* d_in, const int* in_sizes, int n_in,
                              void* d_out, int out_size, void* d_ws, size_t ws_size,
                              hipStream_t stream) {
  kf_fwd<<<128, NT, 0, stream>>>(
    (const float*)d_in[0],  // a_seq
    (const float*)d_in[1],  // h_obs
    (const float*)d_in[2],  // A_matrices
    (const float*)d_in[3],  // C_matrices
    (const float*)d_in[4],  // B_matrices
    (const float*)d_in[5],  // u_seq
    (const float*)d_in[6],  // mask
    (const float*)d_in[7],  // P_0
    (const float*)d_in[8],  // mat_Q
    (const float*)d_in[9],  // mat_R
    (const float*)d_in[10], // gru_Wx
    (const float*)d_in[11], // gru_Wh
    (const float*)d_in[12], // gru_b
    (const float*)d_in[13], // out_W
    (const float*)d_in[14], // out_b
    (float*)d_out);
}

// Round 9
// 4649.434 us; speedup vs baseline: 3.6184x; 1.2221x over previous
//
#include <hip/hip_runtime.h>
#include <math.h>

#define NT 64
#define FMA4(acc,u,bv) {acc.x+=(u)*(bv).x; acc.y+=(u)*(bv).y; acc.z+=(u)*(bv).z; acc.w+=(u)*(bv).w;}

__device__ __forceinline__ float sigf(float x){ return 1.0f/(1.0f+expf(-x)); }
__device__ __forceinline__ float rdlane(float v, int l){
  return __int_as_float(__builtin_amdgcn_readlane(__float_as_int(v), l));
}
__device__ __forceinline__ float dot4(float4 a, float4 b){
  return a.x*b.x + a.y*b.y + a.z*b.z + a.w*b.w;
}

__launch_bounds__(NT, 1)
__global__ void kf_fwd(const float* __restrict__ a_seq, const float* __restrict__ h_obs,
  const float* __restrict__ Amat, const float* __restrict__ Cmat, const float* __restrict__ Bmat,
  const float* __restrict__ u_seq, const float* __restrict__ mask, const float* __restrict__ P0,
  const float* __restrict__ matQ, const float* __restrict__ matR,
  const float* __restrict__ Wx, const float* __restrict__ Wh, const float* __restrict__ gbias,
  const float* __restrict__ outW, const float* __restrict__ outb, float* __restrict__ out)
{
  constexpr int T=256, B=128;
  constexpr int L6=36, L0=20;
  constexpr size_t BT=(size_t)B*T;
  const size_t off_zf=0;
  const size_t off_Pf=off_zf+BT*32;
  const size_t off_zl=off_Pf+BT*1024;
  const size_t off_tr=off_zl+BT*32;
  const size_t off_zp=off_tr+BT*1024;
  const size_t off_Pp=off_zp+BT*32;
  const size_t off_af=off_Pp+BT*1024;
  const size_t off_ap=off_af+BT*16;
  const size_t off_S =off_ap+BT*16;
  const size_t off_al=off_S +BT*256;
  const size_t off_ai=off_al+BT*8;
  const size_t off_R =off_ai+BT*8;
  const size_t off_Q =off_R +256;

  __shared__ __align__(16) float sA[8*32*L6];
  __shared__ __align__(16) float sC[8*16*L6];
  __shared__ __align__(16) float W12[48*192];    // rows 0-31: Wx[32:64]+M ; rows 32-47: Wx[0:16]
  __shared__ __align__(16) float gxh[192];       // gbias + hobs@Wx[16:32]
  __shared__ __align__(16) float sBm[1024];
  __shared__ __align__(16) float souWT[512];
  __shared__ __align__(16) float soutb8[8];
  __shared__ __align__(16) float P[32*L6], Ak[32*L6], AkT[32*L6];
  __shared__ __align__(16) float T1m[32*L6], T3m[32*L6], Qm[32*L6];
  __shared__ __align__(16) float Ck[16*L6], CPm[16*L6];
  __shared__ __align__(16) float CPT[32*L0], Kg[32*L0];
  __shared__ __align__(16) float Sm[16*L0], Rm[16*L0], Sinv[16*L0];
  __shared__ __align__(16) float Linv[16*17];
  __shared__ __align__(16) float Bk[128];
  __shared__ __align__(16) float zj[256], aj[128];
  __shared__ __align__(16) float gx[192], ghl[192];
  __shared__ __align__(16) float zc[32], znew[32], zloc[32], zpred[32], ghs[64];
  __shared__ __align__(16) float aprevv[16], hob[16];
  __shared__ __align__(16) float ak[16], uk[4], rk[16], alpha8[8];
  __shared__ float mvs;

  const int lane = threadIdx.x;
  const int b = blockIdx.x;

  // ---------- init ----------
  for (int e=lane; e<8192; e+=NT){ int k=e>>10, i=(e>>5)&31, j=e&31; sA[(k*32+i)*L6+j]=Amat[e]; }
  for (int e=lane; e<4096; e+=NT){ int k=e>>9, a=(e>>5)&15, i=e&31; sC[(k*16+a)*L6+i]=Cmat[e]; }
  for (int e=lane; e<1024; e+=NT) sBm[e]=Bmat[e];
  for (int e=lane; e<512; e+=NT){ int r=e>>6, q=e&63; souWT[r*64+q]=outW[q*8+r]; }
  if (lane<8) soutb8[lane]=outb[lane];
  for (int e=lane; e<1024; e+=NT){
    int i=e>>5, j=e&31;
    float s=0.f;
    #pragma unroll 8
    for (int k=0;k<32;k++) s += matQ[i*32+k]*matQ[j*32+k];
    Qm[i*L6+j]=s+(i==j?0.001f:0.f);
    P[i*L6+j]=P0[e];
  }
  for (int e=lane; e<256; e+=NT){
    int i=e>>4, j=e&15;
    float s=0.f;
    #pragma unroll
    for (int k=0;k<16;k++) s += matR[i*16+k]*matR[j*16+k];
    Rm[i*L0+j]=s+(i==j?0.001f:0.f);
  }
  for (int e=lane; e<16*L6; e+=NT) Ck[e]=0.f;   // t=0: aprev = 0
  if (lane<32) zc[lane]=0.f;
  ghs[lane]=0.f;
  if (lane<16) hob[lane]=h_obs[b*16+lane];

  // W1 rows + gxh
  if (lane<48){
    const int c0=lane*4;
    #pragma unroll
    for (int a=0;a<16;a++)
      *(float4*)&W12[(32+a)*192+c0] = *(const float4*)(Wx+(size_t)a*192+c0);
    float4 acc=*(const float4*)(gbias+c0);
    #pragma unroll
    for (int i=0;i<16;i++){
      float4 w=*(const float4*)(Wx+(size_t)(16+i)*192+c0);
      float hv=hob[i];
      FMA4(acc,hv,w);
    }
    *(float4*)&gxh[c0]=acc;
  }
  // W2 = Wx[32:64] + M,  M = sum_k CA_k^T @ Wx[64+16k : 80+16k]
  for (int ic=0; ic<4; ++ic){
    float4 Mi[8];
    if (lane<48){
      const int c0=lane*4;
      #pragma unroll
      for (int ii=0;ii<8;ii++)
        Mi[ii]=*(const float4*)(Wx+(size_t)(32+ic*8+ii)*192+c0);
    }
    for (int k=0;k<8;k++){
      #pragma unroll
      for (int r=0;r<2;r++){
        int e=lane+64*r; int a=e>>3, ii=e&7; int i=ic*8+ii;
        float s=0.f;
        #pragma unroll 8
        for (int j=0;j<32;j++) s+=sC[(k*16+a)*L6+j]*sA[(k*32+j)*L6+i];
        Kg[a*8+ii]=s;
      }
      if (lane<48){
        const int c0=lane*4;
        #pragma unroll
        for (int a=0;a<16;a++){
          float4 w=*(const float4*)(Wx+(size_t)(64+16*k+a)*192+c0);
          #pragma unroll
          for (int ii=0;ii<8;ii++){
            float ca=Kg[a*8+ii];
            FMA4(Mi[ii],ca,w);
          }
        }
      }
    }
    if (lane<48){
      const int c0=lane*4;
      #pragma unroll
      for (int ii=0;ii<8;ii++)
        *(float4*)&W12[(ic*8+ii)*192+c0]=Mi[ii];
    }
  }
  if (b==0){
    for (int e=lane;e<256;e+=NT) out[off_R+e]=Rm[(e>>4)*L0+(e&15)];
    for (int e=lane;e<1024;e+=NT) out[off_Q+e]=Qm[(e>>5)*L6+(e&31)];
  }

  for (int t=0;t<T;t++){
    const size_t bt=(size_t)b*T+t;

    // ---- P0: per-step loads ----
    if (lane<16) ak[lane]=a_seq[bt*16+lane];
    if (lane>=16 && lane<20) uk[lane-16]=u_seq[bt*4+(lane-16)];
    if (lane==20) mvs=mask[bt];

    // ---- P3: ghl = ghs @ Wh (issue early) ----
    if (lane<48){
      const int c0=lane*4;
      float4 A0=make_float4(0.f,0.f,0.f,0.f), A1=A0, A2=A0, A3=A0;
      #pragma unroll
      for (int q=0;q<16;q++){
        float4 gv=*(const float4*)&ghs[q*4];
        float4 w0=*(const float4*)(Wh+(size_t)(q*4+0)*192+c0);
        float4 w1=*(const float4*)(Wh+(size_t)(q*4+1)*192+c0);
        float4 w2=*(const float4*)(Wh+(size_t)(q*4+2)*192+c0);
        float4 w3=*(const float4*)(Wh+(size_t)(q*4+3)*192+c0);
        FMA4(A0,gv.x,w0); FMA4(A1,gv.y,w1); FMA4(A2,gv.z,w2); FMA4(A3,gv.w,w3);
      }
      float4 g=make_float4(A0.x+A1.x+A2.x+A3.x, A0.y+A1.y+A2.y+A3.y,
                           A0.z+A1.z+A2.z+A3.z, A0.w+A1.w+A2.w+A3.w);
      *(float4*)&ghl[c0]=g;
    }

    float4 zq[8];
    #pragma unroll
    for (int q=0;q<8;q++) zq[q]=*(const float4*)&zc[q*4];

    // ---- P1: aprev (prev-step Ck) ----
    if (lane<16){
      float s=0.f;
      #pragma unroll
      for (int q=0;q<8;q++) s+=dot4(*(const float4*)&Ck[lane*L6+q*4], zq[q]);
      aprevv[lane]=s;
    }

    // ---- P2: zj then aj ----
    #pragma unroll
    for (int r=0;r<4;r++){
      int e=lane+64*r; int k=e>>5, i=e&31;
      float s=0.f;
      #pragma unroll
      for (int q=0;q<8;q++) s+=dot4(*(const float4*)&sA[(k*32+i)*L6+q*4], zq[q]);
      zj[e]=s;
    }
    #pragma unroll
    for (int r=0;r<2;r++){
      int e=lane+64*r; int k=e>>4, a=e&15;
      float s=0.f;
      #pragma unroll
      for (int q=0;q<8;q++) s+=dot4(*(const float4*)&sC[(k*16+a)*L6+q*4], *(const float4*)&zj[k*32+q*4]);
      aj[e]=s;
    }

    // ---- P4: gx = gxh + zc@W2 + aprev@W1 ----
    if (lane<48){
      const int c0=lane*4;
      float4 A0=*(const float4*)&gxh[c0];
      float4 A1=make_float4(0.f,0.f,0.f,0.f), A2=A1, A3=A1;
      #pragma unroll
      for (int q=0;q<8;q++){
        float4 zv=zq[q];
        float4 w0=*(const float4*)&W12[(q*4+0)*192+c0];
        float4 w1=*(const float4*)&W12[(q*4+1)*192+c0];
        float4 w2=*(const float4*)&W12[(q*4+2)*192+c0];
        float4 w3=*(const float4*)&W12[(q*4+3)*192+c0];
        FMA4(A0,zv.x,w0); FMA4(A1,zv.y,w1); FMA4(A2,zv.z,w2); FMA4(A3,zv.w,w3);
      }
      #pragma unroll
      for (int q=0;q<4;q++){
        float4 av=*(const float4*)&aprevv[q*4];
        float4 w0=*(const float4*)&W12[(32+q*4+0)*192+c0];
        float4 w1=*(const float4*)&W12[(32+q*4+1)*192+c0];
        float4 w2=*(const float4*)&W12[(32+q*4+2)*192+c0];
        float4 w3=*(const float4*)&W12[(32+q*4+3)*192+c0];
        FMA4(A0,av.x,w0); FMA4(A1,av.y,w1); FMA4(A2,av.z,w2); FMA4(A3,av.w,w3);
      }
      float4 g=make_float4(A0.x+A1.x+A2.x+A3.x, A0.y+A1.y+A2.y+A3.y,
                           A0.z+A1.z+A2.z+A3.z, A0.w+A1.w+A2.w+A3.w);
      *(float4*)&gx[c0]=g;
    }

    // ---- P5: ll + alpha_imm ----
    if (lane<8){
      float s=0.f;
      #pragma unroll
      for (int q=0;q<4;q++){
        float4 av=*(const float4*)&ak[q*4];
        float4 jv=*(const float4*)&aj[lane*16+q*4];
        float dx=av.x-jv.x, dy=av.y-jv.y, dz=av.z-jv.z, dw=av.w-jv.w;
        s+=dx*dx+dy*dy+dz*dz+dw*dw;
      }
      float llv=-s;
      float m8=llv;
      m8=fmaxf(m8,__shfl_xor(m8,1)); m8=fmaxf(m8,__shfl_xor(m8,2)); m8=fmaxf(m8,__shfl_xor(m8,4));
      float e2=expf(llv-m8);
      float ss=e2;
      ss+=__shfl_xor(ss,1); ss+=__shfl_xor(ss,2); ss+=__shfl_xor(ss,4);
      out[off_ai+bt*8+lane]=e2/ss*mvs;
    }

    // ---- P6: GRU gates ----
    {
      float r =sigf(gx[lane]+ghl[lane]);
      float zg=sigf(gx[64+lane]+ghl[64+lane]);
      float n =tanhf(gx[128+lane]+r*ghl[128+lane]);
      float h=ghs[lane];
      ghs[lane]=(1.f-zg)*n+zg*h;
    }

    // ---- P7: logits + alpha ----
    if (lane<8){
      float s=soutb8[lane];
      #pragma unroll
      for (int q=0;q<16;q++){
        float4 g=*(const float4*)&ghs[q*4];
        float4 w=*(const float4*)&souWT[lane*64+q*4];
        s+=dot4(g,w);
      }
      float m8=s;
      m8=fmaxf(m8,__shfl_xor(m8,1)); m8=fmaxf(m8,__shfl_xor(m8,2)); m8=fmaxf(m8,__shfl_xor(m8,4));
      float e2=expf(s-m8);
      float ss=e2;
      ss+=__shfl_xor(ss,1); ss+=__shfl_xor(ss,2); ss+=__shfl_xor(ss,4);
      float av=e2/ss;
      alpha8[lane]=av;
      out[off_al+bt*8+lane]=av;
    }

    // ---- P8: blends ----
    float alr[8];
    {
      float4 a0=*(const float4*)&alpha8[0], a1=*(const float4*)&alpha8[4];
      alr[0]=a0.x; alr[1]=a0.y; alr[2]=a0.z; alr[3]=a0.w;
      alr[4]=a1.x; alr[5]=a1.y; alr[6]=a1.z; alr[7]=a1.w;
    }
    #pragma unroll
    for (int r=0;r<4;r++){
      int e=lane+64*r; int i=e>>3, qd=e&7;
      float4 acc=make_float4(0.f,0.f,0.f,0.f);
      #pragma unroll
      for (int k=0;k<8;k++){
        float4 av=*(const float4*)&sA[(k*32+i)*L6+qd*4];
        FMA4(acc,alr[k],av);
      }
      *(float4*)&Ak[i*L6+qd*4]=acc;
      AkT[(qd*4+0)*L6+i]=acc.x; AkT[(qd*4+1)*L6+i]=acc.y;
      AkT[(qd*4+2)*L6+i]=acc.z; AkT[(qd*4+3)*L6+i]=acc.w;
    }
    #pragma unroll
    for (int r=0;r<2;r++){
      int e=lane+64*r; int a=e>>3, qd=e&7;
      float4 acc=make_float4(0.f,0.f,0.f,0.f);
      #pragma unroll
      for (int k=0;k<8;k++){
        float4 cv=*(const float4*)&sC[(k*16+a)*L6+qd*4];
        FMA4(acc,alr[k],cv);
      }
      *(float4*)&Ck[a*L6+qd*4]=acc;
    }
    #pragma unroll
    for (int r=0;r<2;r++){
      int e=lane+64*r;
      float s=0.f;
      #pragma unroll
      for (int k=0;k<8;k++) s+=alr[k]*sBm[k*128+e];
      Bk[e]=s;
    }
    if (lane<32){
      float s=0.f;
      #pragma unroll
      for (int k=0;k<8;k++) s+=alr[k]*zj[k*32+lane];
      znew[lane]=s;
    }

    // ---- P9: CP = Ck@P (+CPT) ; rk ----
    {
      int qd=lane&7, a0=lane>>3;
      float4 d0=make_float4(0.f,0.f,0.f,0.f), d1=d0;
      #pragma unroll 2
      for (int q=0;q<8;q++){
        float4 c0=*(const float4*)&Ck[a0*L6+q*4];
        float4 c1=*(const float4*)&Ck[(a0+8)*L6+q*4];
        float4 p0=*(const float4*)&P[(q*4+0)*L6+qd*4];
        float4 p1=*(const float4*)&P[(q*4+1)*L6+qd*4];
        float4 p2=*(const float4*)&P[(q*4+2)*L6+qd*4];
        float4 p3=*(const float4*)&P[(q*4+3)*L6+qd*4];
        FMA4(d0,c0.x,p0); FMA4(d0,c0.y,p1); FMA4(d0,c0.z,p2); FMA4(d0,c0.w,p3);
        FMA4(d1,c1.x,p0); FMA4(d1,c1.y,p1); FMA4(d1,c1.z,p2); FMA4(d1,c1.w,p3);
      }
      *(float4*)&CPm[a0*L6+qd*4]=d0;
      *(float4*)&CPm[(a0+8)*L6+qd*4]=d1;
      CPT[(qd*4+0)*L0+a0]=d0.x; CPT[(qd*4+1)*L0+a0]=d0.y;
      CPT[(qd*4+2)*L0+a0]=d0.z; CPT[(qd*4+3)*L0+a0]=d0.w;
      CPT[(qd*4+0)*L0+a0+8]=d1.x; CPT[(qd*4+1)*L0+a0+8]=d1.y;
      CPT[(qd*4+2)*L0+a0+8]=d1.z; CPT[(qd*4+3)*L0+a0+8]=d1.w;
    }
    if (lane<16){
      float s=0.f;
      #pragma unroll
      for (int q=0;q<8;q++) s+=dot4(*(const float4*)&Ck[lane*L6+q*4], *(const float4*)&znew[q*4]);
      rk[lane]=ak[lane]-s;
    }

    // ---- P10: S ; chol16 ; Linv ; Sinv (right-looking, short critical path) ----
    {
      int a2=lane>>2, cq=lane&3;
      float s0=0.f,s1=0.f,s2=0.f,s3=0.f;
      #pragma unroll 2
      for (int q=0;q<8;q++){
        float4 cp=*(const float4*)&CPm[a2*L6+q*4];
        s0+=dot4(cp,*(const float4*)&Ck[(cq*4+0)*L6+q*4]);
        s1+=dot4(cp,*(const float4*)&Ck[(cq*4+1)*L6+q*4]);
        s2+=dot4(cp,*(const float4*)&Ck[(cq*4+2)*L6+q*4]);
        s3+=dot4(cp,*(const float4*)&Ck[(cq*4+3)*L6+q*4]);
      }
      float4 rm=*(const float4*)&Rm[a2*L0+cq*4];
      s0+=rm.x+((a2==cq*4+0)?1e-4f:0.f);
      s1+=rm.y+((a2==cq*4+1)?1e-4f:0.f);
      s2+=rm.z+((a2==cq*4+2)?1e-4f:0.f);
      s3+=rm.w+((a2==cq*4+3)?1e-4f:0.f);
      float4 sv=make_float4(s0,s1,s2,s3);
      *(float4*)&Sm[a2*L0+cq*4]=sv;
      *(float4*)&out[off_S+bt*256+lane*4]=sv;
    }
    {
      int row=lane<16?lane:15;
      float Sr[16], invd[16];
      #pragma unroll
      for (int q=0;q<4;q++){
        float4 v=*(const float4*)&Sm[row*L0+q*4];
        Sr[q*4+0]=v.x; Sr[q*4+1]=v.y; Sr[q*4+2]=v.z; Sr[q*4+3]=v.w;
      }
      // right-looking chol16: Sr[c] becomes column c of L (lane=row)
      #pragma unroll
      for (int c=0;c<16;c++){
        float d=rdlane(Sr[c],c);
        float inv=rsqrtf(d);
        invd[c]=inv;
        float lc=(lane==c)?d*inv:Sr[c]*inv;
        Sr[c]=lc;
        #pragma unroll
        for (int j=c+1;j<16;j++) Sr[j]-=lc*rdlane(lc,j);
      }
      // forward solve L * Linv = I  (right-looking; lane = column of Linv)
      float Li[16], rhs[16];
      #pragma unroll
      for (int r=0;r<16;r++) rhs[r]=(lane==r)?1.f:0.f;
      #pragma unroll
      for (int k=0;k<16;k++){
        float lik=rhs[k]*invd[k];
        Li[k]=lik;
        #pragma unroll
        for (int r=k+1;r<16;r++) rhs[r]-=rdlane(Sr[k],r)*lik;
      }
      if (lane<16){
        #pragma unroll
        for (int r=0;r<16;r++) Linv[r*17+lane]=Li[r];
      }
      #pragma unroll
      for (int q=0;q<4;q++){
        int e=lane+64*q; int a2=e>>4, b2=e&15;
        float s=0.f;
        #pragma unroll
        for (int k=0;k<16;k++) s+=Linv[k*17+a2]*Linv[k*17+b2];
        Sinv[a2*L0+b2]=s;
      }
    }

    // ---- P11: Kg = CPT@Sinv * m ; zloc ----
    {
      int i0=lane>>2, aq=lane&3;
      float4 k0=make_float4(0.f,0.f,0.f,0.f), k1=k0;
      #pragma unroll
      for (int q=0;q<4;q++){
        float4 ca=*(const float4*)&CPT[i0*L0+q*4];
        float4 cb=*(const float4*)&CPT[(i0+16)*L0+q*4];
        float4 v0=*(const float4*)&Sinv[(q*4+0)*L0+aq*4];
        float4 v1=*(const float4*)&Sinv[(q*4+1)*L0+aq*4];
        float4 v2=*(const float4*)&Sinv[(q*4+2)*L0+aq*4];
        float4 v3=*(const float4*)&Sinv[(q*4+3)*L0+aq*4];
        FMA4(k0,ca.x,v0); FMA4(k0,ca.y,v1); FMA4(k0,ca.z,v2); FMA4(k0,ca.w,v3);
        FMA4(k1,cb.x,v0); FMA4(k1,cb.y,v1); FMA4(k1,cb.z,v2); FMA4(k1,cb.w,v3);
      }
      float m=mvs;
      k0.x*=m;k0.y*=m;k0.z*=m;k0.w*=m;
      k1.x*=m;k1.y*=m;k1.z*=m;k1.w*=m;
      *(float4*)&Kg[i0*L0+aq*4]=k0;
      *(float4*)&Kg[(i0+16)*L0+aq*4]=k1;
    }
    if (lane<32){
      float s=znew[lane];
      #pragma unroll
      for (int q=0;q<4;q++)
        s+=dot4(*(const float4*)&Kg[lane*L0+q*4], *(const float4*)&rk[q*4]);
      zloc[lane]=s;
    }

    // ---- P14: z stores ; zpred ; af ; a_pred ; zc carry ----
    {
      float4 zl4[8];
      if (lane<32){
        float zl=zloc[lane];
        out[off_zf+bt*32+lane]=zl;
        out[off_zl+bt*32+lane]=zl;
      }
      #pragma unroll
      for (int q=0;q<8;q++) zl4[q]=*(const float4*)&zloc[q*4];
      if (lane<32){
        float s=0.f;
        #pragma unroll
        for (int q=0;q<8;q++) s+=dot4(*(const float4*)&Ak[lane*L6+q*4], zl4[q]);
        float4 bk=*(const float4*)&Bk[lane*4];
        float4 u4=*(const float4*)&uk[0];
        s+=dot4(bk,u4);
        zpred[lane]=s;
        out[off_zp+bt*32+lane]=s;
        zc[lane]=zloc[lane];
      }
      if (lane>=32 && lane<48){
        int a=lane-32;
        float s=0.f;
        #pragma unroll
        for (int q=0;q<8;q++) s+=dot4(*(const float4*)&Ck[a*L6+q*4], zl4[q]);
        out[off_af+bt*16+a]=s;
      }
      if (lane<16){
        float s=0.f;
        #pragma unroll
        for (int q=0;q<8;q++)
          s+=dot4(*(const float4*)&Ck[lane*L6+q*4], *(const float4*)&zpred[q*4]);
        out[off_ap+bt*16+lane]=s;
      }
    }

    // ---- P13: Pf = P - Kg@CP + 1e-3 I -> T3m ; Pf store (K=16 half-matmul) ----
    {
      const int i0=(lane>>3)*4, j0=(lane&7)*4;
      float4 q0=*(const float4*)&P[(i0+0)*L6+j0];
      float4 q1=*(const float4*)&P[(i0+1)*L6+j0];
      float4 q2=*(const float4*)&P[(i0+2)*L6+j0];
      float4 q3=*(const float4*)&P[(i0+3)*L6+j0];
      #pragma unroll
      for (int q=0;q<4;q++){
        float4 a0=*(const float4*)&Kg[(i0+0)*L0+q*4];
        float4 a1=*(const float4*)&Kg[(i0+1)*L0+q*4];
        float4 a2=*(const float4*)&Kg[(i0+2)*L0+q*4];
        float4 a3=*(const float4*)&Kg[(i0+3)*L0+q*4];
        float4 bv;
        bv=*(const float4*)&CPm[(q*4+0)*L6+j0];
        FMA4(q0,-a0.x,bv); FMA4(q1,-a1.x,bv); FMA4(q2,-a2.x,bv); FMA4(q3,-a3.x,bv);
        bv=*(const float4*)&CPm[(q*4+1)*L6+j0];
        FMA4(q0,-a0.y,bv); FMA4(q1,-a1.y,bv); FMA4(q2,-a2.y,bv); FMA4(q3,-a3.y,bv);
        bv=*(const float4*)&CPm[(q*4+2)*L6+j0];
        FMA4(q0,-a0.z,bv); FMA4(q1,-a1.z,bv); FMA4(q2,-a2.z,bv); FMA4(q3,-a3.z,bv);
        bv=*(const float4*)&CPm[(q*4+3)*L6+j0];
        FMA4(q0,-a0.w,bv); FMA4(q1,-a1.w,bv); FMA4(q2,-a2.w,bv); FMA4(q3,-a3.w,bv);
      }
      int d0=i0-j0;
      if (d0>=0&&d0<4){ if(d0==0)q0.x+=1e-3f; else if(d0==1)q0.y+=1e-3f; else if(d0==2)q0.z+=1e-3f; else q0.w+=1e-3f; }
      int d1=i0+1-j0;
      if (d1>=0&&d1<4){ if(d1==0)q1.x+=1e-3f; else if(d1==1)q1.y+=1e-3f; else if(d1==2)q1.z+=1e-3f; else q1.w+=1e-3f; }
      int d2=i0+2-j0;
      if (d2>=0&&d2<4){ if(d2==0)q2.x+=1e-3f; else if(d2==1)q2.y+=1e-3f; else if(d2==2)q2.z+=1e-3f; else q2.w+=1e-3f; }
      int d3=i0+3-j0;
      if (d3>=0&&d3<4){ if(d3==0)q3.x+=1e-3f; else if(d3==1)q3.y+=1e-3f; else if(d3==2)q3.z+=1e-3f; else q3.w+=1e-3f; }
      *(float4*)&T3m[(i0+0)*L6+j0]=q0;
      *(float4*)&T3m[(i0+1)*L6+j0]=q1;
      *(float4*)&T3m[(i0+2)*L6+j0]=q2;
      *(float4*)&T3m[(i0+3)*L6+j0]=q3;
      *(float4*)&out[off_Pf+bt*1024+(i0+0)*32+j0]=q0;
      *(float4*)&out[off_Pf+bt*1024+(i0+1)*32+j0]=q1;
      *(float4*)&out[off_Pf+bt*1024+(i0+2)*32+j0]=q2;
      *(float4*)&out[off_Pf+bt*1024+(i0+3)*32+j0]=q3;
    }

    // ---- P16a: M3 = Ak@T3m -> T1m (load-heavy; adjacent to chol32 for interleave) ----
    {
      const int i0=(lane>>3)*4, j0=(lane&7)*4;
      float4 q0=make_float4(0.f,0.f,0.f,0.f), q1=q0, q2=q0, q3=q0;
      #pragma unroll 4
      for (int q=0;q<8;q++){
        float4 a0=*(const float4*)&Ak[(i0+0)*L6+q*4];
        float4 a1=*(const float4*)&Ak[(i0+1)*L6+q*4];
        float4 a2=*(const float4*)&Ak[(i0+2)*L6+q*4];
        float4 a3=*(const float4*)&Ak[(i0+3)*L6+q*4];
        float4 bv;
        bv=*(const float4*)&T3m[(q*4+0)*L6+j0];
        FMA4(q0,a0.x,bv); FMA4(q1,a1.x,bv); FMA4(q2,a2.x,bv); FMA4(q3,a3.x,bv);
        bv=*(const float4*)&T3m[(q*4+1)*L6+j0];
        FMA4(q0,a0.y,bv); FMA4(q1,a1.y,bv); FMA4(q2,a2.y,bv); FMA4(q3,a3.y,bv);
        bv=*(const float4*)&T3m[(q*4+2)*L6+j0];
        FMA4(q0,a0.z,bv); FMA4(q1,a1.z,bv); FMA4(q2,a2.z,bv); FMA4(q3,a3.z,bv);
        bv=*(const float4*)&T3m[(q*4+3)*L6+j0];
        FMA4(q0,a0.w,bv); FMA4(q1,a1.w,bv); FMA4(q2,a2.w,bv); FMA4(q3,a3.w,bv);
      }
      *(float4*)&T1m[(i0+0)*L6+j0]=q0;
      *(float4*)&T1m[(i0+1)*L6+j0]=q1;
      *(float4*)&T1m[(i0+2)*L6+j0]=q2;
      *(float4*)&T1m[(i0+3)*L6+j0]=q3;
    }

    // ---- P15: chol32 (right-looking, registers) ----
    float trl[32];
    {
      int row=lane<32?lane:31;
      #pragma unroll
      for (int q=0;q<8;q++){
        float4 v=*(const float4*)&T3m[row*L6+q*4];
        trl[q*4+0]=v.x; trl[q*4+1]=v.y; trl[q*4+2]=v.z; trl[q*4+3]=v.w;
      }
      #pragma unroll
      for (int c=0;c<32;c++){
        float d=rdlane(trl[c],c);
        float inv=rsqrtf(d);
        float lc=(lane==c)?d*inv:trl[c]*inv;
        trl[c]=lc;
        #pragma unroll
        for (int j=c+1;j<32;j++) trl[j]-=lc*rdlane(lc,j);
      }
    }

    // ---- P16b: Pp = T1m@AkT + Q + 1e-3 I -> P + store ----
    {
      const int i0=(lane>>3)*4, j0=(lane&7)*4;
      float4 q0=*(const float4*)&Qm[(i0+0)*L6+j0];
      float4 q1=*(const float4*)&Qm[(i0+1)*L6+j0];
      float4 q2=*(const float4*)&Qm[(i0+2)*L6+j0];
      float4 q3=*(const float4*)&Qm[(i0+3)*L6+j0];
      int d0=i0-j0;
      if (d0>=0&&d0<4){ if(d0==0)q0.x+=1e-3f; else if(d0==1)q0.y+=1e-3f; else if(d0==2)q0.z+=1e-3f; else q0.w+=1e-3f; }
      int d1=i0+1-j0;
      if (d1>=0&&d1<4){ if(d1==0)q1.x+=1e-3f; else if(d1==1)q1.y+=1e-3f; else if(d1==2)q1.z+=1e-3f; else q1.w+=1e-3f; }
      int d2=i0+2-j0;
      if (d2>=0&&d2<4){ if(d2==0)q2.x+=1e-3f; else if(d2==1)q2.y+=1e-3f; else if(d2==2)q2.z+=1e-3f; else q2.w+=1e-3f; }
      int d3=i0+3-j0;
      if (d3>=0&&d3<4){ if(d3==0)q3.x+=1e-3f; else if(d3==1)q3.y+=1e-3f; else if(d3==2)q3.z+=1e-3f; else q3.w+=1e-3f; }
      #pragma unroll 4
      for (int q=0;q<8;q++){
        float4 a0=*(const float4*)&T1m[(i0+0)*L6+q*4];
        float4 a1=*(const float4*)&T1m[(i0+1)*L6+q*4];
        float4 a2=*(const float4*)&T1m[(i0+2)*L6+q*4];
        float4 a3=*(const float4*)&T1m[(i0+3)*L6+q*4];
        float4 bv;
        bv=*(const float4*)&AkT[(q*4+0)*L6+j0];
        FMA4(q0,a0.x,bv); FMA4(q1,a1.x,bv); FMA4(q2,a2.x,bv); FMA4(q3,a3.x,bv);
        bv=*(const float4*)&AkT[(q*4+1)*L6+j0];
        FMA4(q0,a0.y,bv); FMA4(q1,a1.y,bv); FMA4(q2,a2.y,bv); FMA4(q3,a3.y,bv);
        bv=*(const float4*)&AkT[(q*4+2)*L6+j0];
        FMA4(q0,a0.z,bv); FMA4(q1,a1.z,bv); FMA4(q2,a2.z,bv); FMA4(q3,a3.z,bv);
        bv=*(const float4*)&AkT[(q*4+3)*L6+j0];
        FMA4(q0,a0.w,bv); FMA4(q1,a1.w,bv); FMA4(q2,a2.w,bv); FMA4(q3,a3.w,bv);
      }
      *(float4*)&P[(i0+0)*L6+j0]=q0;
      *(float4*)&P[(i0+1)*L6+j0]=q1;
      *(float4*)&P[(i0+2)*L6+j0]=q2;
      *(float4*)&P[(i0+3)*L6+j0]=q3;
      *(float4*)&out[off_Pp+bt*1024+(i0+0)*32+j0]=q0;
      *(float4*)&out[off_Pp+bt*1024+(i0+1)*32+j0]=q1;
      *(float4*)&out[off_Pp+bt*1024+(i0+2)*32+j0]=q2;
      *(float4*)&out[off_Pp+bt*1024+(i0+3)*32+j0]=q3;
    }

    // ---- tril store (upper zeroed) ----
    if (lane<32){
      #pragma unroll
      for (int q=0;q<8;q++){
        float t0=(q*4+0<=lane)?trl[q*4+0]:0.f;
        float t1=(q*4+1<=lane)?trl[q*4+1]:0.f;
        float t2=(q*4+2<=lane)?trl[q*4+2]:0.f;
        float t3=(q*4+3<=lane)?trl[q*4+3]:0.f;
        *(float4*)&out[off_tr+bt*1024+lane*32+q*4]=make_float4(t0,t1,t2,t3);
      }
    }
  }
}

extern "C" void kernel_launch(void* const* d_in, const int* in_sizes, int n_in,
                              void* d_out, int out_size, void* d_ws, size_t ws_size,
                              hipStream_t stream) {
  kf_fwd<<<128, NT, 0, stream>>>(
    (const float*)d_in[0],  // a_seq
    (const float*)d_in[1],  // h_obs
    (const float*)d_in[2],  // A_matrices
    (const float*)d_in[3],  // C_matrices
    (const float*)d_in[4],  // B_matrices
    (const float*)d_in[5],  // u_seq
    (const float*)d_in[6],  // mask
    (const float*)d_in[7],  // P_0
    (const float*)d_in[8],  // mat_Q
    (const float*)d_in[9],  // mat_R
    (const float*)d_in[10], // gru_Wx
    (const float*)d_in[11], // gru_Wh
    (const float*)d_in[12], // gru_b
    (const float*)d_in[13], // out_W
    (const float*)d_in[14], // out_b
    (float*)d_out);
}

// Round 10
// 3354.724 us; speedup vs baseline: 5.0149x; 1.3859x over previous
//
#include <hip/hip_runtime.h>
#include <math.h>

#define NT 128
#define FMA4(acc,u,bv) {acc.x+=(u)*(bv).x; acc.y+=(u)*(bv).y; acc.z+=(u)*(bv).z; acc.w+=(u)*(bv).w;}

__device__ __forceinline__ float sigf(float x){ return 1.0f/(1.0f+expf(-x)); }
__device__ __forceinline__ float rdlane(float v, int l){
  return __int_as_float(__builtin_amdgcn_readlane(__float_as_int(v), l));
}
__device__ __forceinline__ float dot4(float4 a, float4 b){
  return a.x*b.x + a.y*b.y + a.z*b.z + a.w*b.w;
}

__launch_bounds__(NT, 1)
__global__ void kf_fwd(const float* __restrict__ a_seq, const float* __restrict__ h_obs,
  const float* __restrict__ Amat, const float* __restrict__ Cmat, const float* __restrict__ Bmat,
  const float* __restrict__ u_seq, const float* __restrict__ mask, const float* __restrict__ P0,
  const float* __restrict__ matQ, const float* __restrict__ matR,
  const float* __restrict__ Wx, const float* __restrict__ Wh, const float* __restrict__ gbias,
  const float* __restrict__ outW, const float* __restrict__ outb, float* __restrict__ out)
{
  constexpr int T=256, B=128;
  constexpr int L6=36, L0=20;
  constexpr size_t BT=(size_t)B*T;
  const size_t off_zf=0;
  const size_t off_Pf=off_zf+BT*32;
  const size_t off_zl=off_Pf+BT*1024;
  const size_t off_tr=off_zl+BT*32;
  const size_t off_zp=off_tr+BT*1024;
  const size_t off_Pp=off_zp+BT*32;
  const size_t off_af=off_Pp+BT*1024;
  const size_t off_ap=off_af+BT*16;
  const size_t off_S =off_ap+BT*16;
  const size_t off_al=off_S +BT*256;
  const size_t off_ai=off_al+BT*8;
  const size_t off_R =off_ai+BT*8;
  const size_t off_Q =off_R +256;

  __shared__ __align__(16) float sA[8*32*L6];
  __shared__ __align__(16) float sC[8*16*L6];
  __shared__ __align__(16) float W12[48*192];
  __shared__ __align__(16) float gxh[192];
  __shared__ __align__(16) float sBm[1024];
  __shared__ __align__(16) float souWT[512];
  __shared__ __align__(16) float soutb8[8];
  __shared__ __align__(16) float P[32*L6], Ak[32*L6], AkT[32*L6];
  __shared__ __align__(16) float T1m[32*L6], T3m[32*L6], Qm[32*L6];
  __shared__ __align__(16) float Ck[16*L6], CPm[16*L6];
  __shared__ __align__(16) float CPT[32*L0], Kg[32*L0];
  __shared__ __align__(16) float Sm[16*L0], Rm[16*L0], Sinv[16*L0];
  __shared__ __align__(16) float Linv[16*17];
  __shared__ __align__(16) float Bk[128];
  __shared__ __align__(16) float zj[256], aj[128];
  __shared__ __align__(16) float gx[192], ghl[192];
  __shared__ __align__(16) float zc[32], znew[32], zloc[32], zpred[32], ghs[64];
  __shared__ __align__(16) float aprevv[16], hob[16];
  __shared__ __align__(16) float ak[16], uk[4], rk[16], alpha8[8];
  __shared__ float mvs;

  const int tid  = threadIdx.x;
  const int wid  = tid>>6;
  const int lane = tid&63;
  const int b = blockIdx.x;

  // ---------- init ----------
  for (int e=tid; e<8192; e+=NT){ int k=e>>10, i=(e>>5)&31, j=e&31; sA[(k*32+i)*L6+j]=Amat[e]; }
  for (int e=tid; e<4096; e+=NT){ int k=e>>9, a=(e>>5)&15, i=e&31; sC[(k*16+a)*L6+i]=Cmat[e]; }
  for (int e=tid; e<1024; e+=NT) sBm[e]=Bmat[e];
  for (int e=tid; e<512; e+=NT){ int r=e>>6, q=e&63; souWT[r*64+q]=outW[q*8+r]; }
  if (tid<8) soutb8[tid]=outb[tid];
  for (int e=tid; e<1024; e+=NT){
    int i=e>>5, j=e&31;
    float s=0.f;
    #pragma unroll 8
    for (int k=0;k<32;k++) s += matQ[i*32+k]*matQ[j*32+k];
    Qm[i*L6+j]=s+(i==j?0.001f:0.f);
    P[i*L6+j]=P0[e];
  }
  for (int e=tid; e<256; e+=NT){
    int i=e>>4, j=e&15;
    float s=0.f;
    #pragma unroll
    for (int k=0;k<16;k++) s += matR[i*16+k]*matR[j*16+k];
    Rm[i*L0+j]=s+(i==j?0.001f:0.f);
  }
  for (int e=tid; e<16*L6; e+=NT) Ck[e]=0.f;     // t=0: aprev = 0
  if (tid<32) zc[tid]=0.f;
  if (tid<64) ghs[tid]=0.f;
  for (int e=tid; e<192; e+=NT) ghl[e]=0.f;      // ghs(t=-1)=0 -> ghl(t=0)=0
  if (tid<16) hob[tid]=h_obs[b*16+tid];
  __syncthreads();

  // W1 rows + gxh
  if (tid<48){
    const int c0=tid*4;
    #pragma unroll
    for (int a=0;a<16;a++)
      *(float4*)&W12[(32+a)*192+c0] = *(const float4*)(Wx+(size_t)a*192+c0);
    float4 acc=*(const float4*)(gbias+c0);
    #pragma unroll
    for (int i=0;i<16;i++){
      float4 w=*(const float4*)(Wx+(size_t)(16+i)*192+c0);
      float hv=hob[i];
      FMA4(acc,hv,w);
    }
    *(float4*)&gxh[c0]=acc;
  }
  // W2 = Wx[32:64] + M,  M = sum_k CA_k^T @ Wx[64+16k : 80+16k]
  for (int ic=0; ic<4; ++ic){
    float4 Mi[8];
    if (tid<48){
      const int c0=tid*4;
      #pragma unroll
      for (int ii=0;ii<8;ii++)
        Mi[ii]=*(const float4*)(Wx+(size_t)(32+ic*8+ii)*192+c0);
    }
    for (int k=0;k<8;k++){
      __syncthreads();
      {
        int e=tid; int a=e>>3, ii=e&7; int i=ic*8+ii;
        float s=0.f;
        #pragma unroll 8
        for (int j=0;j<32;j++) s+=sC[(k*16+a)*L6+j]*sA[(k*32+j)*L6+i];
        Kg[a*8+ii]=s;
      }
      __syncthreads();
      if (tid<48){
        const int c0=tid*4;
        #pragma unroll
        for (int a=0;a<16;a++){
          float4 w=*(const float4*)(Wx+(size_t)(64+16*k+a)*192+c0);
          #pragma unroll
          for (int ii=0;ii<8;ii++){
            float ca=Kg[a*8+ii];
            FMA4(Mi[ii],ca,w);
          }
        }
      }
    }
    if (tid<48){
      const int c0=tid*4;
      #pragma unroll
      for (int ii=0;ii<8;ii++)
        *(float4*)&W12[(ic*8+ii)*192+c0]=Mi[ii];
    }
  }
  if (b==0){
    for (int e=tid;e<256;e+=NT) out[off_R+e]=Rm[(e>>4)*L0+(e&15)];
    for (int e=tid;e<1024;e+=NT) out[off_Q+e]=Qm[(e>>5)*L6+(e&31)];
  }
  __syncthreads();

  for (int t=0;t<T;t++){
    const size_t bt=(size_t)b*T+t;

    // ================= Phase A: wave0 = head(t) | wave1 = tail(t-1) =================
    if (wid==0){
      if (lane<16) ak[lane]=a_seq[bt*16+lane];
      if (lane==20) mvs=mask[bt];
      float4 zq[8];
      #pragma unroll
      for (int q=0;q<8;q++) zq[q]=*(const float4*)&zc[q*4];
      // aprev
      if (lane<16){
        float s=0.f;
        #pragma unroll
        for (int q=0;q<8;q++) s+=dot4(*(const float4*)&Ck[lane*L6+q*4], zq[q]);
        aprevv[lane]=s;
      }
      // zj then aj
      #pragma unroll
      for (int r=0;r<4;r++){
        int e=lane+64*r; int k=e>>5, i=e&31;
        float s=0.f;
        #pragma unroll
        for (int q=0;q<8;q++) s+=dot4(*(const float4*)&sA[(k*32+i)*L6+q*4], zq[q]);
        zj[e]=s;
      }
      #pragma unroll
      for (int r=0;r<2;r++){
        int e=lane+64*r; int k=e>>4, a=e&15;
        float s=0.f;
        #pragma unroll
        for (int q=0;q<8;q++) s+=dot4(*(const float4*)&sC[(k*16+a)*L6+q*4], *(const float4*)&zj[k*32+q*4]);
        aj[e]=s;
      }
      // gx = gxh + zc@W2 + aprev@W1
      if (lane<48){
        const int c0=lane*4;
        float4 A0=*(const float4*)&gxh[c0];
        float4 A1=make_float4(0.f,0.f,0.f,0.f), A2=A1, A3=A1;
        #pragma unroll
        for (int q=0;q<8;q++){
          float4 zv=zq[q];
          float4 w0=*(const float4*)&W12[(q*4+0)*192+c0];
          float4 w1=*(const float4*)&W12[(q*4+1)*192+c0];
          float4 w2=*(const float4*)&W12[(q*4+2)*192+c0];
          float4 w3=*(const float4*)&W12[(q*4+3)*192+c0];
          FMA4(A0,zv.x,w0); FMA4(A1,zv.y,w1); FMA4(A2,zv.z,w2); FMA4(A3,zv.w,w3);
        }
        #pragma unroll
        for (int q=0;q<4;q++){
          float4 av=*(const float4*)&aprevv[q*4];
          float4 w0=*(const float4*)&W12[(32+q*4+0)*192+c0];
          float4 w1=*(const float4*)&W12[(32+q*4+1)*192+c0];
          float4 w2=*(const float4*)&W12[(32+q*4+2)*192+c0];
          float4 w3=*(const float4*)&W12[(32+q*4+3)*192+c0];
          FMA4(A0,av.x,w0); FMA4(A1,av.y,w1); FMA4(A2,av.z,w2); FMA4(A3,av.w,w3);
        }
        float4 g=make_float4(A0.x+A1.x+A2.x+A3.x, A0.y+A1.y+A2.y+A3.y,
                             A0.z+A1.z+A2.z+A3.z, A0.w+A1.w+A2.w+A3.w);
        *(float4*)&gx[c0]=g;
      }
      // ll + alpha_imm
      if (lane<8){
        float s=0.f;
        #pragma unroll
        for (int q=0;q<4;q++){
          float4 av=*(const float4*)&ak[q*4];
          float4 jv=*(const float4*)&aj[lane*16+q*4];
          float dx=av.x-jv.x, dy=av.y-jv.y, dz=av.z-jv.z, dw=av.w-jv.w;
          s+=dx*dx+dy*dy+dz*dz+dw*dw;
        }
        float llv=-s;
        float m8=llv;
        m8=fmaxf(m8,__shfl_xor(m8,1)); m8=fmaxf(m8,__shfl_xor(m8,2)); m8=fmaxf(m8,__shfl_xor(m8,4));
        float e2=expf(llv-m8);
        float ss=e2;
        ss+=__shfl_xor(ss,1); ss+=__shfl_xor(ss,2); ss+=__shfl_xor(ss,4);
        out[off_ai+bt*8+lane]=e2/ss*mvs;
      }
      // GRU gates
      {
        float r =sigf(gx[lane]+ghl[lane]);
        float zg=sigf(gx[64+lane]+ghl[64+lane]);
        float n =tanhf(gx[128+lane]+r*ghl[128+lane]);
        float h=ghs[lane];
        ghs[lane]=(1.f-zg)*n+zg*h;
      }
      // logits + alpha
      if (lane<8){
        float s=soutb8[lane];
        #pragma unroll
        for (int q=0;q<16;q++){
          float4 g=*(const float4*)&ghs[q*4];
          float4 w=*(const float4*)&souWT[lane*64+q*4];
          s+=dot4(g,w);
        }
        float m8=s;
        m8=fmaxf(m8,__shfl_xor(m8,1)); m8=fmaxf(m8,__shfl_xor(m8,2)); m8=fmaxf(m8,__shfl_xor(m8,4));
        float e2=expf(s-m8);
        float ss=e2;
        ss+=__shfl_xor(ss,1); ss+=__shfl_xor(ss,2); ss+=__shfl_xor(ss,4);
        float av=e2/ss;
        alpha8[lane]=av;
        out[off_al+bt*8+lane]=av;
      }
    } else if (t>0){
      const size_t bt1=bt-1;
      float4 zq[8];
      #pragma unroll
      for (int q=0;q<8;q++) zq[q]=*(const float4*)&zc[q*4];
      // zpred + zp store ; af store
      if (lane<32){
        float s=0.f;
        #pragma unroll
        for (int q=0;q<8;q++) s+=dot4(*(const float4*)&Ak[lane*L6+q*4], zq[q]);
        float4 bk=*(const float4*)&Bk[lane*4];
        float4 u4=*(const float4*)&uk[0];
        s+=dot4(bk,u4);
        zpred[lane]=s;
        out[off_zp+bt1*32+lane]=s;
      }
      if (lane>=32 && lane<48){
        int a=lane-32;
        float s=0.f;
        #pragma unroll
        for (int q=0;q<8;q++) s+=dot4(*(const float4*)&Ck[a*L6+q*4], zq[q]);
        out[off_af+bt1*16+a]=s;
      }
      // Pf = P - Kg@CP + 1e-3 I -> T3m + store
      {
        const int i0=(lane>>3)*4, j0=(lane&7)*4;
        float4 q0=*(const float4*)&P[(i0+0)*L6+j0];
        float4 q1=*(const float4*)&P[(i0+1)*L6+j0];
        float4 q2=*(const float4*)&P[(i0+2)*L6+j0];
        float4 q3=*(const float4*)&P[(i0+3)*L6+j0];
        #pragma unroll
        for (int q=0;q<4;q++){
          float4 a0=*(const float4*)&Kg[(i0+0)*L0+q*4];
          float4 a1=*(const float4*)&Kg[(i0+1)*L0+q*4];
          float4 a2=*(const float4*)&Kg[(i0+2)*L0+q*4];
          float4 a3=*(const float4*)&Kg[(i0+3)*L0+q*4];
          float4 bv;
          bv=*(const float4*)&CPm[(q*4+0)*L6+j0];
          FMA4(q0,-a0.x,bv); FMA4(q1,-a1.x,bv); FMA4(q2,-a2.x,bv); FMA4(q3,-a3.x,bv);
          bv=*(const float4*)&CPm[(q*4+1)*L6+j0];
          FMA4(q0,-a0.y,bv); FMA4(q1,-a1.y,bv); FMA4(q2,-a2.y,bv); FMA4(q3,-a3.y,bv);
          bv=*(const float4*)&CPm[(q*4+2)*L6+j0];
          FMA4(q0,-a0.z,bv); FMA4(q1,-a1.z,bv); FMA4(q2,-a2.z,bv); FMA4(q3,-a3.z,bv);
          bv=*(const float4*)&CPm[(q*4+3)*L6+j0];
          FMA4(q0,-a0.w,bv); FMA4(q1,-a1.w,bv); FMA4(q2,-a2.w,bv); FMA4(q3,-a3.w,bv);
        }
        int d0=i0-j0;
        if (d0>=0&&d0<4){ if(d0==0)q0.x+=1e-3f; else if(d0==1)q0.y+=1e-3f; else if(d0==2)q0.z+=1e-3f; else q0.w+=1e-3f; }
        int d1=i0+1-j0;
        if (d1>=0&&d1<4){ if(d1==0)q1.x+=1e-3f; else if(d1==1)q1.y+=1e-3f; else if(d1==2)q1.z+=1e-3f; else q1.w+=1e-3f; }
        int d2=i0+2-j0;
        if (d2>=0&&d2<4){ if(d2==0)q2.x+=1e-3f; else if(d2==1)q2.y+=1e-3f; else if(d2==2)q2.z+=1e-3f; else q2.w+=1e-3f; }
        int d3=i0+3-j0;
        if (d3>=0&&d3<4){ if(d3==0)q3.x+=1e-3f; else if(d3==1)q3.y+=1e-3f; else if(d3==2)q3.z+=1e-3f; else q3.w+=1e-3f; }
        *(float4*)&T3m[(i0+0)*L6+j0]=q0;
        *(float4*)&T3m[(i0+1)*L6+j0]=q1;
        *(float4*)&T3m[(i0+2)*L6+j0]=q2;
        *(float4*)&T3m[(i0+3)*L6+j0]=q3;
        *(float4*)&out[off_Pf+bt1*1024+(i0+0)*32+j0]=q0;
        *(float4*)&out[off_Pf+bt1*1024+(i0+1)*32+j0]=q1;
        *(float4*)&out[off_Pf+bt1*1024+(i0+2)*32+j0]=q2;
        *(float4*)&out[off_Pf+bt1*1024+(i0+3)*32+j0]=q3;
      }
      // a_pred
      if (lane<16){
        float s=0.f;
        #pragma unroll
        for (int q=0;q<8;q++)
          s+=dot4(*(const float4*)&Ck[lane*L6+q*4], *(const float4*)&zpred[q*4]);
        out[off_ap+bt1*16+lane]=s;
      }
      // M3 = Ak@T3m -> T1m
      {
        const int i0=(lane>>3)*4, j0=(lane&7)*4;
        float4 q0=make_float4(0.f,0.f,0.f,0.f), q1=q0, q2=q0, q3=q0;
        #pragma unroll 4
        for (int q=0;q<8;q++){
          float4 a0=*(const float4*)&Ak[(i0+0)*L6+q*4];
          float4 a1=*(const float4*)&Ak[(i0+1)*L6+q*4];
          float4 a2=*(const float4*)&Ak[(i0+2)*L6+q*4];
          float4 a3=*(const float4*)&Ak[(i0+3)*L6+q*4];
          float4 bv;
          bv=*(const float4*)&T3m[(q*4+0)*L6+j0];
          FMA4(q0,a0.x,bv); FMA4(q1,a1.x,bv); FMA4(q2,a2.x,bv); FMA4(q3,a3.x,bv);
          bv=*(const float4*)&T3m[(q*4+1)*L6+j0];
          FMA4(q0,a0.y,bv); FMA4(q1,a1.y,bv); FMA4(q2,a2.y,bv); FMA4(q3,a3.y,bv);
          bv=*(const float4*)&T3m[(q*4+2)*L6+j0];
          FMA4(q0,a0.z,bv); FMA4(q1,a1.z,bv); FMA4(q2,a2.z,bv); FMA4(q3,a3.z,bv);
          bv=*(const float4*)&T3m[(q*4+3)*L6+j0];
          FMA4(q0,a0.w,bv); FMA4(q1,a1.w,bv); FMA4(q2,a2.w,bv); FMA4(q3,a3.w,bv);
        }
        *(float4*)&T1m[(i0+0)*L6+j0]=q0;
        *(float4*)&T1m[(i0+1)*L6+j0]=q1;
        *(float4*)&T1m[(i0+2)*L6+j0]=q2;
        *(float4*)&T1m[(i0+3)*L6+j0]=q3;
      }
      // chol32 (right-looking) -> tril store
      {
        int row=lane<32?lane:31;
        float trl[32];
        #pragma unroll
        for (int q=0;q<8;q++){
          float4 v=*(const float4*)&T3m[row*L6+q*4];
          trl[q*4+0]=v.x; trl[q*4+1]=v.y; trl[q*4+2]=v.z; trl[q*4+3]=v.w;
        }
        #pragma unroll
        for (int c=0;c<32;c++){
          float d=rdlane(trl[c],c);
          float inv=rsqrtf(d);
          float lc=(lane==c)?d*inv:trl[c]*inv;
          trl[c]=lc;
          #pragma unroll
          for (int j=c+1;j<32;j++) trl[j]-=lc*rdlane(lc,j);
        }
        if (lane<32){
          #pragma unroll
          for (int q=0;q<8;q++){
            float t0=(q*4+0<=lane)?trl[q*4+0]:0.f;
            float t1=(q*4+1<=lane)?trl[q*4+1]:0.f;
            float t2=(q*4+2<=lane)?trl[q*4+2]:0.f;
            float t3=(q*4+3<=lane)?trl[q*4+3]:0.f;
            *(float4*)&out[off_tr+bt1*1024+lane*32+q*4]=make_float4(t0,t1,t2,t3);
          }
        }
      }
      // Pp = T1m@AkT + Q + 1e-3 I -> P + store
      {
        const int i0=(lane>>3)*4, j0=(lane&7)*4;
        float4 q0=*(const float4*)&Qm[(i0+0)*L6+j0];
        float4 q1=*(const float4*)&Qm[(i0+1)*L6+j0];
        float4 q2=*(const float4*)&Qm[(i0+2)*L6+j0];
        float4 q3=*(const float4*)&Qm[(i0+3)*L6+j0];
        int d0=i0-j0;
        if (d0>=0&&d0<4){ if(d0==0)q0.x+=1e-3f; else if(d0==1)q0.y+=1e-3f; else if(d0==2)q0.z+=1e-3f; else q0.w+=1e-3f; }
        int d1=i0+1-j0;
        if (d1>=0&&d1<4){ if(d1==0)q1.x+=1e-3f; else if(d1==1)q1.y+=1e-3f; else if(d1==2)q1.z+=1e-3f; else q1.w+=1e-3f; }
        int d2=i0+2-j0;
        if (d2>=0&&d2<4){ if(d2==0)q2.x+=1e-3f; else if(d2==1)q2.y+=1e-3f; else if(d2==2)q2.z+=1e-3f; else q2.w+=1e-3f; }
        int d3=i0+3-j0;
        if (d3>=0&&d3<4){ if(d3==0)q3.x+=1e-3f; else if(d3==1)q3.y+=1e-3f; else if(d3==2)q3.z+=1e-3f; else q3.w+=1e-3f; }
        #pragma unroll 4
        for (int q=0;q<8;q++){
          float4 a0=*(const float4*)&T1m[(i0+0)*L6+q*4];
          float4 a1=*(const float4*)&T1m[(i0+1)*L6+q*4];
          float4 a2=*(const float4*)&T1m[(i0+2)*L6+q*4];
          float4 a3=*(const float4*)&T1m[(i0+3)*L6+q*4];
          float4 bv;
          bv=*(const float4*)&AkT[(q*4+0)*L6+j0];
          FMA4(q0,a0.x,bv); FMA4(q1,a1.x,bv); FMA4(q2,a2.x,bv); FMA4(q3,a3.x,bv);
          bv=*(const float4*)&AkT[(q*4+1)*L6+j0];
          FMA4(q0,a0.y,bv); FMA4(q1,a1.y,bv); FMA4(q2,a2.y,bv); FMA4(q3,a3.y,bv);
          bv=*(const float4*)&AkT[(q*4+2)*L6+j0];
          FMA4(q0,a0.z,bv); FMA4(q1,a1.z,bv); FMA4(q2,a2.z,bv); FMA4(q3,a3.z,bv);
          bv=*(const float4*)&AkT[(q*4+3)*L6+j0];
          FMA4(q0,a0.w,bv); FMA4(q1,a1.w,bv); FMA4(q2,a2.w,bv); FMA4(q3,a3.w,bv);
        }
        *(float4*)&P[(i0+0)*L6+j0]=q0;
        *(float4*)&P[(i0+1)*L6+j0]=q1;
        *(float4*)&P[(i0+2)*L6+j0]=q2;
        *(float4*)&P[(i0+3)*L6+j0]=q3;
        *(float4*)&out[off_Pp+bt1*1024+(i0+0)*32+j0]=q0;
        *(float4*)&out[off_Pp+bt1*1024+(i0+1)*32+j0]=q1;
        *(float4*)&out[off_Pp+bt1*1024+(i0+2)*32+j0]=q2;
        *(float4*)&out[off_Pp+bt1*1024+(i0+3)*32+j0]=q3;
      }
    }
    __syncthreads();

    // ================= Phase B: blends (split across waves) =================
    {
      float alr[8];
      float4 a0v=*(const float4*)&alpha8[0], a1v=*(const float4*)&alpha8[4];
      alr[0]=a0v.x; alr[1]=a0v.y; alr[2]=a0v.z; alr[3]=a0v.w;
      alr[4]=a1v.x; alr[5]=a1v.y; alr[6]=a1v.z; alr[7]=a1v.w;
      if (wid==0){
        #pragma unroll
        for (int r=0;r<2;r++){
          int e=lane+64*r; int i=e>>3, qd=e&7;
          float4 acc=make_float4(0.f,0.f,0.f,0.f);
          #pragma unroll
          for (int k=0;k<8;k++){
            float4 av=*(const float4*)&sA[(k*32+i)*L6+qd*4];
            FMA4(acc,alr[k],av);
          }
          *(float4*)&Ak[i*L6+qd*4]=acc;
          AkT[(qd*4+0)*L6+i]=acc.x; AkT[(qd*4+1)*L6+i]=acc.y;
          AkT[(qd*4+2)*L6+i]=acc.z; AkT[(qd*4+3)*L6+i]=acc.w;
        }
        #pragma unroll
        for (int r=0;r<2;r++){
          int e=lane+64*r; int a=e>>3, qd=e&7;
          float4 acc=make_float4(0.f,0.f,0.f,0.f);
          #pragma unroll
          for (int k=0;k<8;k++){
            float4 cv=*(const float4*)&sC[(k*16+a)*L6+qd*4];
            FMA4(acc,alr[k],cv);
          }
          *(float4*)&Ck[a*L6+qd*4]=acc;
        }
      } else {
        #pragma unroll
        for (int r=0;r<2;r++){
          int e=128+lane+64*r; int i=e>>3, qd=e&7;
          float4 acc=make_float4(0.f,0.f,0.f,0.f);
          #pragma unroll
          for (int k=0;k<8;k++){
            float4 av=*(const float4*)&sA[(k*32+i)*L6+qd*4];
            FMA4(acc,alr[k],av);
          }
          *(float4*)&Ak[i*L6+qd*4]=acc;
          AkT[(qd*4+0)*L6+i]=acc.x; AkT[(qd*4+1)*L6+i]=acc.y;
          AkT[(qd*4+2)*L6+i]=acc.z; AkT[(qd*4+3)*L6+i]=acc.w;
        }
        #pragma unroll
        for (int r=0;r<2;r++){
          int e=lane+64*r;
          float s=0.f;
          #pragma unroll
          for (int k=0;k<8;k++) s+=alr[k]*sBm[k*128+e];
          Bk[e]=s;
        }
        if (lane<32){
          float s=0.f;
          #pragma unroll
          for (int k=0;k<8;k++) s+=alr[k]*zj[k*32+lane];
          znew[lane]=s;
        }
      }
    }
    __syncthreads();

    // ================= Phase C: wave0 = CP..Kg..zloc | wave1 = ghl(t+1), uk(t) =================
    if (wid==0){
      // CP = Ck@P (+CPT)
      {
        int qd=lane&7, a0=lane>>3;
        float4 d0=make_float4(0.f,0.f,0.f,0.f), d1=d0;
        #pragma unroll 2
        for (int q=0;q<8;q++){
          float4 c0=*(const float4*)&Ck[a0*L6+q*4];
          float4 c1=*(const float4*)&Ck[(a0+8)*L6+q*4];
          float4 p0=*(const float4*)&P[(q*4+0)*L6+qd*4];
          float4 p1=*(const float4*)&P[(q*4+1)*L6+qd*4];
          float4 p2=*(const float4*)&P[(q*4+2)*L6+qd*4];
          float4 p3=*(const float4*)&P[(q*4+3)*L6+qd*4];
          FMA4(d0,c0.x,p0); FMA4(d0,c0.y,p1); FMA4(d0,c0.z,p2); FMA4(d0,c0.w,p3);
          FMA4(d1,c1.x,p0); FMA4(d1,c1.y,p1); FMA4(d1,c1.z,p2); FMA4(d1,c1.w,p3);
        }
        *(float4*)&CPm[a0*L6+qd*4]=d0;
        *(float4*)&CPm[(a0+8)*L6+qd*4]=d1;
        CPT[(qd*4+0)*L0+a0]=d0.x; CPT[(qd*4+1)*L0+a0]=d0.y;
        CPT[(qd*4+2)*L0+a0]=d0.z; CPT[(qd*4+3)*L0+a0]=d0.w;
        CPT[(qd*4+0)*L0+a0+8]=d1.x; CPT[(qd*4+1)*L0+a0+8]=d1.y;
        CPT[(qd*4+2)*L0+a0+8]=d1.z; CPT[(qd*4+3)*L0+a0+8]=d1.w;
      }
      // rk = ak - Ck@znew
      if (lane<16){
        float s=0.f;
        #pragma unroll
        for (int q=0;q<8;q++) s+=dot4(*(const float4*)&Ck[lane*L6+q*4], *(const float4*)&znew[q*4]);
        rk[lane]=ak[lane]-s;
      }
      // S + store
      {
        int a2=lane>>2, cq=lane&3;
        float s0=0.f,s1=0.f,s2=0.f,s3=0.f;
        #pragma unroll 2
        for (int q=0;q<8;q++){
          float4 cp=*(const float4*)&CPm[a2*L6+q*4];
          s0+=dot4(cp,*(const float4*)&Ck[(cq*4+0)*L6+q*4]);
          s1+=dot4(cp,*(const float4*)&Ck[(cq*4+1)*L6+q*4]);
          s2+=dot4(cp,*(const float4*)&Ck[(cq*4+2)*L6+q*4]);
          s3+=dot4(cp,*(const float4*)&Ck[(cq*4+3)*L6+q*4]);
        }
        float4 rm=*(const float4*)&Rm[a2*L0+cq*4];
        s0+=rm.x+((a2==cq*4+0)?1e-4f:0.f);
        s1+=rm.y+((a2==cq*4+1)?1e-4f:0.f);
        s2+=rm.z+((a2==cq*4+2)?1e-4f:0.f);
        s3+=rm.w+((a2==cq*4+3)?1e-4f:0.f);
        float4 sv=make_float4(s0,s1,s2,s3);
        *(float4*)&Sm[a2*L0+cq*4]=sv;
        *(float4*)&out[off_S+bt*256+lane*4]=sv;
      }
      // chol16 + forward solve + Sinv (right-looking)
      {
        int row=lane<16?lane:15;
        float Sr[16], invd[16];
        #pragma unroll
        for (int q=0;q<4;q++){
          float4 v=*(const float4*)&Sm[row*L0+q*4];
          Sr[q*4+0]=v.x; Sr[q*4+1]=v.y; Sr[q*4+2]=v.z; Sr[q*4+3]=v.w;
        }
        #pragma unroll
        for (int c=0;c<16;c++){
          float d=rdlane(Sr[c],c);
          float inv=rsqrtf(d);
          invd[c]=inv;
          float lc=(lane==c)?d*inv:Sr[c]*inv;
          Sr[c]=lc;
          #pragma unroll
          for (int j=c+1;j<16;j++) Sr[j]-=lc*rdlane(lc,j);
        }
        float Li[16], rhs[16];
        #pragma unroll
        for (int r=0;r<16;r++) rhs[r]=(lane==r)?1.f:0.f;
        #pragma unroll
        for (int k=0;k<16;k++){
          float lik=rhs[k]*invd[k];
          Li[k]=lik;
          #pragma unroll
          for (int r=k+1;r<16;r++) rhs[r]-=rdlane(Sr[k],r)*lik;
        }
        if (lane<16){
          #pragma unroll
          for (int r=0;r<16;r++) Linv[r*17+lane]=Li[r];
        }
        #pragma unroll
        for (int q=0;q<4;q++){
          int e=lane+64*q; int a2=e>>4, b2=e&15;
          float s=0.f;
          #pragma unroll
          for (int k=0;k<16;k++) s+=Linv[k*17+a2]*Linv[k*17+b2];
          Sinv[a2*L0+b2]=s;
        }
      }
      // Kg = CPT@Sinv * m
      {
        int i0=lane>>2, aq=lane&3;
        float4 k0=make_float4(0.f,0.f,0.f,0.f), k1=k0;
        #pragma unroll
        for (int q=0;q<4;q++){
          float4 ca=*(const float4*)&CPT[i0*L0+q*4];
          float4 cb=*(const float4*)&CPT[(i0+16)*L0+q*4];
          float4 v0=*(const float4*)&Sinv[(q*4+0)*L0+aq*4];
          float4 v1=*(const float4*)&Sinv[(q*4+1)*L0+aq*4];
          float4 v2=*(const float4*)&Sinv[(q*4+2)*L0+aq*4];
          float4 v3=*(const float4*)&Sinv[(q*4+3)*L0+aq*4];
          FMA4(k0,ca.x,v0); FMA4(k0,ca.y,v1); FMA4(k0,ca.z,v2); FMA4(k0,ca.w,v3);
          FMA4(k1,cb.x,v0); FMA4(k1,cb.y,v1); FMA4(k1,cb.z,v2); FMA4(k1,cb.w,v3);
        }
        float m=mvs;
        k0.x*=m;k0.y*=m;k0.z*=m;k0.w*=m;
        k1.x*=m;k1.y*=m;k1.z*=m;k1.w*=m;
        *(float4*)&Kg[i0*L0+aq*4]=k0;
        *(float4*)&Kg[(i0+16)*L0+aq*4]=k1;
      }
      // zloc ; zc carry ; zf/zl stores
      if (lane<32){
        float s=znew[lane];
        #pragma unroll
        for (int q=0;q<4;q++)
          s+=dot4(*(const float4*)&Kg[lane*L0+q*4], *(const float4*)&rk[q*4]);
        zloc[lane]=s;
        zc[lane]=s;
        out[off_zf+bt*32+lane]=s;
        out[off_zl+bt*32+lane]=s;
      }
    } else {
      // ghl(t+1) = ghs(t) @ Wh   (L2-heavy; overlaps wave0's serial chol16 chain)
      if (lane<48){
        const int c0=lane*4;
        float4 A0=make_float4(0.f,0.f,0.f,0.f), A1=A0, A2=A0, A3=A0;
        #pragma unroll
        for (int q=0;q<16;q++){
          float4 gv=*(const float4*)&ghs[q*4];
          float4 w0=*(const float4*)(Wh+(size_t)(q*4+0)*192+c0);
          float4 w1=*(const float4*)(Wh+(size_t)(q*4+1)*192+c0);
          float4 w2=*(const float4*)(Wh+(size_t)(q*4+2)*192+c0);
          float4 w3=*(const float4*)(Wh+(size_t)(q*4+3)*192+c0);
          FMA4(A0,gv.x,w0); FMA4(A1,gv.y,w1); FMA4(A2,gv.z,w2); FMA4(A3,gv.w,w3);
        }
        float4 g=make_float4(A0.x+A1.x+A2.x+A3.x, A0.y+A1.y+A2.y+A3.y,
                             A0.z+A1.z+A2.z+A3.z, A0.w+A1.w+A2.w+A3.w);
        *(float4*)&ghl[c0]=g;
      }
      if (lane>=48 && lane<52) uk[lane-48]=u_seq[bt*4+(lane-48)];
    }
    __syncthreads();
  }

  // ================= Epilogue: tail(T-1) on wave1 =================
  if (wid==1){
    const size_t bt1=(size_t)b*T+(T-1);
    float4 zq[8];
    #pragma unroll
    for (int q=0;q<8;q++) zq[q]=*(const float4*)&zc[q*4];
    if (lane<32){
      float s=0.f;
      #pragma unroll
      for (int q=0;q<8;q++) s+=dot4(*(const float4*)&Ak[lane*L6+q*4], zq[q]);
      float4 bk=*(const float4*)&Bk[lane*4];
      float4 u4=*(const float4*)&uk[0];
      s+=dot4(bk,u4);
      zpred[lane]=s;
      out[off_zp+bt1*32+lane]=s;
    }
    if (lane>=32 && lane<48){
      int a=lane-32;
      float s=0.f;
      #pragma unroll
      for (int q=0;q<8;q++) s+=dot4(*(const float4*)&Ck[a*L6+q*4], zq[q]);
      out[off_af+bt1*16+a]=s;
    }
    {
      const int i0=(lane>>3)*4, j0=(lane&7)*4;
      float4 q0=*(const float4*)&P[(i0+0)*L6+j0];
      float4 q1=*(const float4*)&P[(i0+1)*L6+j0];
      float4 q2=*(const float4*)&P[(i0+2)*L6+j0];
      float4 q3=*(const float4*)&P[(i0+3)*L6+j0];
      #pragma unroll
      for (int q=0;q<4;q++){
        float4 a0=*(const float4*)&Kg[(i0+0)*L0+q*4];
        float4 a1=*(const float4*)&Kg[(i0+1)*L0+q*4];
        float4 a2=*(const float4*)&Kg[(i0+2)*L0+q*4];
        float4 a3=*(const float4*)&Kg[(i0+3)*L0+q*4];
        float4 bv;
        bv=*(const float4*)&CPm[(q*4+0)*L6+j0];
        FMA4(q0,-a0.x,bv); FMA4(q1,-a1.x,bv); FMA4(q2,-a2.x,bv); FMA4(q3,-a3.x,bv);
        bv=*(const float4*)&CPm[(q*4+1)*L6+j0];
        FMA4(q0,-a0.y,bv); FMA4(q1,-a1.y,bv); FMA4(q2,-a2.y,bv); FMA4(q3,-a3.y,bv);
        bv=*(const float4*)&CPm[(q*4+2)*L6+j0];
        FMA4(q0,-a0.z,bv); FMA4(q1,-a1.z,bv); FMA4(q2,-a2.z,bv); FMA4(q3,-a3.z,bv);
        bv=*(const float4*)&CPm[(q*4+3)*L6+j0];
        FMA4(q0,-a0.w,bv); FMA4(q1,-a1.w,bv); FMA4(q2,-a2.w,bv); FMA4(q3,-a3.w,bv);
      }
      int d0=i0-j0;
      if (d0>=0&&d0<4){ if(d0==0)q0.x+=1e-3f; else if(d0==1)q0.y+=1e-3f; else if(d0==2)q0.z+=1e-3f; else q0.w+=1e-3f; }
      int d1=i0+1-j0;
      if (d1>=0&&d1<4){ if(d1==0)q1.x+=1e-3f; else if(d1==1)q1.y+=1e-3f; else if(d1==2)q1.z+=1e-3f; else q1.w+=1e-3f; }
      int d2=i0+2-j0;
      if (d2>=0&&d2<4){ if(d2==0)q2.x+=1e-3f; else if(d2==1)q2.y+=1e-3f; else if(d2==2)q2.z+=1e-3f; else q2.w+=1e-3f; }
      int d3=i0+3-j0;
      if (d3>=0&&d3<4){ if(d3==0)q3.x+=1e-3f; else if(d3==1)q3.y+=1e-3f; else if(d3==2)q3.z+=1e-3f; else q3.w+=1e-3f; }
      *(float4*)&T3m[(i0+0)*L6+j0]=q0;
      *(float4*)&T3m[(i0+1)*L6+j0]=q1;
      *(float4*)&T3m[(i0+2)*L6+j0]=q2;
      *(float4*)&T3m[(i0+3)*L6+j0]=q3;
      *(float4*)&out[off_Pf+bt1*1024+(i0+0)*32+j0]=q0;
      *(float4*)&out[off_Pf+bt1*1024+(i0+1)*32+j0]=q1;
      *(float4*)&out[off_Pf+bt1*1024+(i0+2)*32+j0]=q2;
      *(float4*)&out[off_Pf+bt1*1024+(i0+3)*32+j0]=q3;
    }
    if (lane<16){
      float s=0.f;
      #pragma unroll
      for (int q=0;q<8;q++)
        s+=dot4(*(const float4*)&Ck[lane*L6+q*4], *(const float4*)&zpred[q*4]);
      out[off_ap+bt1*16+lane]=s;
    }
    {
      const int i0=(lane>>3)*4, j0=(lane&7)*4;
      float4 q0=make_float4(0.f,0.f,0.f,0.f), q1=q0, q2=q0, q3=q0;
      #pragma unroll 4
      for (int q=0;q<8;q++){
        float4 a0=*(const float4*)&Ak[(i0+0)*L6+q*4];
        float4 a1=*(const float4*)&Ak[(i0+1)*L6+q*4];
        float4 a2=*(const float4*)&Ak[(i0+2)*L6+q*4];
        float4 a3=*(const float4*)&Ak[(i0+3)*L6+q*4];
        float4 bv;
        bv=*(const float4*)&T3m[(q*4+0)*L6+j0];
        FMA4(q0,a0.x,bv); FMA4(q1,a1.x,bv); FMA4(q2,a2.x,bv); FMA4(q3,a3.x,bv);
        bv=*(const float4*)&T3m[(q*4+1)*L6+j0];
        FMA4(q0,a0.y,bv); FMA4(q1,a1.y,bv); FMA4(q2,a2.y,bv); FMA4(q3,a3.y,bv);
        bv=*(const float4*)&T3m[(q*4+2)*L6+j0];
        FMA4(q0,a0.z,bv); FMA4(q1,a1.z,bv); FMA4(q2,a2.z,bv); FMA4(q3,a3.z,bv);
        bv=*(const float4*)&T3m[(q*4+3)*L6+j0];
        FMA4(q0,a0.w,bv); FMA4(q1,a1.w,bv); FMA4(q2,a2.w,bv); FMA4(q3,a3.w,bv);
      }
      *(float4*)&T1m[(i0+0)*L6+j0]=q0;
      *(float4*)&T1m[(i0+1)*L6+j0]=q1;
      *(float4*)&T1m[(i0+2)*L6+j0]=q2;
      *(float4*)&T1m[(i0+3)*L6+j0]=q3;
    }
    {
      int row=lane<32?lane:31;
      float trl[32];
      #pragma unroll
      for (int q=0;q<8;q++){
        float4 v=*(const float4*)&T3m[row*L6+q*4];
        trl[q*4+0]=v.x; trl[q*4+1]=v.y; trl[q*4+2]=v.z; trl[q*4+3]=v.w;
      }
      #pragma unroll
      for (int c=0;c<32;c++){
        float d=rdlane(trl[c],c);
        float inv=rsqrtf(d);
        float lc=(lane==c)?d*inv:trl[c]*inv;
        trl[c]=lc;
        #pragma unroll
        for (int j=c+1;j<32;j++) trl[j]-=lc*rdlane(lc,j);
      }
      if (lane<32){
        #pragma unroll
        for (int q=0;q<8;q++){
          float t0=(q*4+0<=lane)?trl[q*4+0]:0.f;
          float t1=(q*4+1<=lane)?trl[q*4+1]:0.f;
          float t2=(q*4+2<=lane)?trl[q*4+2]:0.f;
          float t3=(q*4+3<=lane)?trl[q*4+3]:0.f;
          *(float4*)&out[off_tr+bt1*1024+lane*32+q*4]=make_float4(t0,t1,t2,t3);
        }
      }
    }
    {
      const int i0=(lane>>3)*4, j0=(lane&7)*4;
      float4 q0=*(const float4*)&Qm[(i0+0)*L6+j0];
      float4 q1=*(const float4*)&Qm[(i0+1)*L6+j0];
      float4 q2=*(const float4*)&Qm[(i0+2)*L6+j0];
      float4 q3=*(const float4*)&Qm[(i0+3)*L6+j0];
      int d0=i0-j0;
      if (d0>=0&&d0<4){ if(d0==0)q0.x+=1e-3f; else if(d0==1)q0.y+=1e-3f; else if(d0==2)q0.z+=1e-3f; else q0.w+=1e-3f; }
      int d1=i0+1-j0;
      if (d1>=0&&d1<4){ if(d1==0)q1.x+=1e-3f; else if(d1==1)q1.y+=1e-3f; else if(d1==2)q1.z+=1e-3f; else q1.w+=1e-3f; }
      int d2=i0+2-j0;
      if (d2>=0&&d2<4){ if(d2==0)q2.x+=1e-3f; else if(d2==1)q2.y+=1e-3f; else if(d2==2)q2.z+=1e-3f; else q2.w+=1e-3f; }
      int d3=i0+3-j0;
      if (d3>=0&&d3<4){ if(d3==0)q3.x+=1e-3f; else if(d3==1)q3.y+=1e-3f; else if(d3==2)q3.z+=1e-3f; else q3.w+=1e-3f; }
      #pragma unroll 4
      for (int q=0;q<8;q++){
        float4 a0=*(const float4*)&T1m[(i0+0)*L6+q*4];
        float4 a1=*(const float4*)&T1m[(i0+1)*L6+q*4];
        float4 a2=*(const float4*)&T1m[(i0+2)*L6+q*4];
        float4 a3=*(const float4*)&T1m[(i0+3)*L6+q*4];
        float4 bv;
        bv=*(const float4*)&AkT[(q*4+0)*L6+j0];
        FMA4(q0,a0.x,bv); FMA4(q1,a1.x,bv); FMA4(q2,a2.x,bv); FMA4(q3,a3.x,bv);
        bv=*(const float4*)&AkT[(q*4+1)*L6+j0];
        FMA4(q0,a0.y,bv); FMA4(q1,a1.y,bv); FMA4(q2,a2.y,bv); FMA4(q3,a3.y,bv);
        bv=*(const float4*)&AkT[(q*4+2)*L6+j0];
        FMA4(q0,a0.z,bv); FMA4(q1,a1.z,bv); FMA4(q2,a2.z,bv); FMA4(q3,a3.z,bv);
        bv=*(const float4*)&AkT[(q*4+3)*L6+j0];
        FMA4(q0,a0.w,bv); FMA4(q1,a1.w,bv); FMA4(q2,a2.w,bv); FMA4(q3,a3.w,bv);
      }
      *(float4*)&out[off_Pp+bt1*1024+(i0+0)*32+j0]=q0;
      *(float4*)&out[off_Pp+bt1*1024+(i0+1)*32+j0]=q1;
      *(float4*)&out[off_Pp+bt1*1024+(i0+2)*32+j0]=q2;
      *(float4*)&out[off_Pp+bt1*1024+(i0+3)*32+j0]=q3;
    }
  }
}

extern "C" void kernel_launch(void* const* d_in, const int* in_sizes, int n_in,
                              void* d_out, int out_size, void* d_ws, size_t ws_size,
                              hipStream_t stream) {
  kf_fwd<<<128, NT, 0, stream>>>(
    (const float*)d_in[0],  // a_seq
    (const float*)d_in[1],  // h_obs
    (const float*)d_in[2],  // A_matrices
    (const float*)d_in[3],  // C_matrices
    (const float*)d_in[4],  // B_matrices
    (const float*)d_in[5],  // u_seq
    (const float*)d_in[6],  // mask
    (const float*)d_in[7],  // P_0
    (const float*)d_in[8],  // mat_Q
    (const float*)d_in[9],  // mat_R
    (const float*)d_in[10], // gru_Wx
    (const float*)d_in[11], // gru_Wh
    (const float*)d_in[12], // gru_b
    (const float*)d_in[13], // out_W
    (const float*)d_in[14], // out_b
    (float*)d_out);
}

// Round 11
// 2625.676 us; speedup vs baseline: 6.4073x; 1.2777x over previous
//
#include <hip/hip_runtime.h>
#include <math.h>

#define NT 256
#define FMA4(acc,u,bv) {acc.x+=(u)*(bv).x; acc.y+=(u)*(bv).y; acc.z+=(u)*(bv).z; acc.w+=(u)*(bv).w;}

__device__ __forceinline__ float sigf(float x){ return 1.0f/(1.0f+expf(-x)); }
__device__ __forceinline__ float rdlane(float v, int l){
  return __int_as_float(__builtin_amdgcn_readlane(__float_as_int(v), l));
}
__device__ __forceinline__ float dot4(float4 a, float4 b){
  return a.x*b.x + a.y*b.y + a.z*b.z + a.w*b.w;
}

__launch_bounds__(NT, 1)
__global__ void kf_fwd(const float* __restrict__ a_seq, const float* __restrict__ h_obs,
  const float* __restrict__ Amat, const float* __restrict__ Cmat, const float* __restrict__ Bmat,
  const float* __restrict__ u_seq, const float* __restrict__ mask, const float* __restrict__ P0,
  const float* __restrict__ matQ, const float* __restrict__ matR,
  const float* __restrict__ Wx, const float* __restrict__ Wh, const float* __restrict__ gbias,
  const float* __restrict__ outW, const float* __restrict__ outb, float* __restrict__ out)
{
  constexpr int T=256, B=128;
  constexpr int L6=36, L0=20;
  constexpr size_t BT=(size_t)B*T;
  const size_t off_zf=0;
  const size_t off_Pf=off_zf+BT*32;
  const size_t off_zl=off_Pf+BT*1024;
  const size_t off_tr=off_zl+BT*32;
  const size_t off_zp=off_tr+BT*1024;
  const size_t off_Pp=off_zp+BT*32;
  const size_t off_af=off_Pp+BT*1024;
  const size_t off_ap=off_af+BT*16;
  const size_t off_S =off_ap+BT*16;
  const size_t off_al=off_S +BT*256;
  const size_t off_ai=off_al+BT*8;
  const size_t off_R =off_ai+BT*8;
  const size_t off_Q =off_R +256;

  __shared__ __align__(16) float sA[8*32*L6];
  __shared__ __align__(16) float sC[8*16*L6];
  __shared__ __align__(16) float W12[48*192];
  __shared__ __align__(16) float gxh[192];
  __shared__ __align__(16) float sBm[1024];
  __shared__ __align__(16) float souWT[512];
  __shared__ __align__(16) float soutb8[8];
  __shared__ __align__(16) float P[32*L6], T1m[32*L6], T3m[32*L6], Qm[32*L6];
  __shared__ __align__(16) float Ak2[2][32*L6], AkT2[2][32*L6];
  __shared__ __align__(16) float Ck[16*L6], CPm[16*L6];
  __shared__ __align__(16) float CPT[32*L0], Kg[32*L0];
  __shared__ __align__(16) float Sm[16*L0], Rm[16*L0], Sinv[16*L0];
  __shared__ __align__(16) float Linv[16*17];
  __shared__ __align__(16) float Bk[128];
  __shared__ __align__(16) float zj[256], aj[128];
  __shared__ __align__(16) float gx[192], ghl[192];
  __shared__ __align__(16) float zc[32], znew[32], zloc[32], zpred[32], ghs[64];
  __shared__ __align__(16) float aprevv[16], hob[16];
  __shared__ __align__(16) float ak[16], uk[4], rk[16], alpha8[8];
  __shared__ __align__(16) float ys[16], ws[16];
  __shared__ float mvs2[2];

  const int tid  = threadIdx.x;
  const int wid  = tid>>6;
  const int lane = tid&63;
  const int b = blockIdx.x;

  // ---------- init ----------
  for (int e=tid; e<8192; e+=NT){ int k=e>>10, i=(e>>5)&31, j=e&31; sA[(k*32+i)*L6+j]=Amat[e]; }
  for (int e=tid; e<4096; e+=NT){ int k=e>>9, a=(e>>5)&15, i=e&31; sC[(k*16+a)*L6+i]=Cmat[e]; }
  for (int e=tid; e<1024; e+=NT) sBm[e]=Bmat[e];
  for (int e=tid; e<512; e+=NT){ int r=e>>6, q=e&63; souWT[r*64+q]=outW[q*8+r]; }
  if (tid<8) soutb8[tid]=outb[tid];
  for (int e=tid; e<1024; e+=NT){
    int i=e>>5, j=e&31;
    float s=0.f;
    #pragma unroll 8
    for (int k=0;k<32;k++) s += matQ[i*32+k]*matQ[j*32+k];
    Qm[i*L6+j]=s+(i==j?0.001f:0.f);
    P[i*L6+j]=P0[e];
  }
  for (int e=tid; e<256; e+=NT){
    int i=e>>4, j=e&15;
    float s=0.f;
    #pragma unroll
    for (int k=0;k<16;k++) s += matR[i*16+k]*matR[j*16+k];
    Rm[i*L0+j]=s+(i==j?0.001f:0.f);
  }
  for (int e=tid; e<16*L6; e+=NT) Ck[e]=0.f;     // t=0: aprev = 0
  if (tid<32) zc[tid]=0.f;
  if (tid<64) ghs[tid]=0.f;
  for (int e=tid; e<192; e+=NT) ghl[e]=0.f;
  if (tid<16) hob[tid]=h_obs[b*16+tid];
  __syncthreads();

  // W1 rows + gxh
  if (tid<48){
    const int c0=tid*4;
    #pragma unroll
    for (int a=0;a<16;a++)
      *(float4*)&W12[(32+a)*192+c0] = *(const float4*)(Wx+(size_t)a*192+c0);
    float4 acc=*(const float4*)(gbias+c0);
    #pragma unroll
    for (int i=0;i<16;i++){
      float4 w=*(const float4*)(Wx+(size_t)(16+i)*192+c0);
      float hv=hob[i];
      FMA4(acc,hv,w);
    }
    *(float4*)&gxh[c0]=acc;
  }
  // W2 = Wx[32:64] + M,  M = sum_k CA_k^T @ Wx[64+16k : 80+16k]
  for (int ic=0; ic<4; ++ic){
    float4 Mi[8];
    if (tid<48){
      const int c0=tid*4;
      #pragma unroll
      for (int ii=0;ii<8;ii++)
        Mi[ii]=*(const float4*)(Wx+(size_t)(32+ic*8+ii)*192+c0);
    }
    for (int k=0;k<8;k++){
      __syncthreads();
      if (tid<128){
        int e=tid; int a=e>>3, ii=e&7; int i=ic*8+ii;
        float s=0.f;
        #pragma unroll 8
        for (int j=0;j<32;j++) s+=sC[(k*16+a)*L6+j]*sA[(k*32+j)*L6+i];
        Kg[a*8+ii]=s;
      }
      __syncthreads();
      if (tid<48){
        const int c0=tid*4;
        #pragma unroll
        for (int a=0;a<16;a++){
          float4 w=*(const float4*)(Wx+(size_t)(64+16*k+a)*192+c0);
          #pragma unroll
          for (int ii=0;ii<8;ii++){
            float ca=Kg[a*8+ii];
            FMA4(Mi[ii],ca,w);
          }
        }
      }
    }
    if (tid<48){
      const int c0=tid*4;
      #pragma unroll
      for (int ii=0;ii<8;ii++)
        *(float4*)&W12[(ic*8+ii)*192+c0]=Mi[ii];
    }
  }
  if (b==0){
    for (int e=tid;e<256;e+=NT) out[off_R+e]=Rm[(e>>4)*L0+(e&15)];
    for (int e=tid;e<1024;e+=NT) out[off_Q+e]=Qm[(e>>5)*L6+(e&31)];
  }
  __syncthreads();

  for (int t=0;t<T;t++){
    const size_t bt=(size_t)b*T+t;
    const int pc=t&1, pp=pc^1;

    // ===== Phase A =====
    if (wid==0){
      // head(t): aprev -> gx -> gates -> logits -> alpha
      if (lane==0) mvs2[pc]=mask[bt];
      float4 zq[8];
      #pragma unroll
      for (int q=0;q<8;q++) zq[q]=*(const float4*)&zc[q*4];
      if (lane<16){
        float s=0.f;
        #pragma unroll
        for (int q=0;q<8;q++) s+=dot4(*(const float4*)&Ck[lane*L6+q*4], zq[q]);
        aprevv[lane]=s;
      }
      if (lane<48){
        const int c0=lane*4;
        float4 A0=*(const float4*)&gxh[c0];
        float4 A1=make_float4(0.f,0.f,0.f,0.f), A2=A1, A3=A1;
        #pragma unroll
        for (int q=0;q<8;q++){
          float4 zv=zq[q];
          float4 w0=*(const float4*)&W12[(q*4+0)*192+c0];
          float4 w1=*(const float4*)&W12[(q*4+1)*192+c0];
          float4 w2=*(const float4*)&W12[(q*4+2)*192+c0];
          float4 w3=*(const float4*)&W12[(q*4+3)*192+c0];
          FMA4(A0,zv.x,w0); FMA4(A1,zv.y,w1); FMA4(A2,zv.z,w2); FMA4(A3,zv.w,w3);
        }
        #pragma unroll
        for (int q=0;q<4;q++){
          float4 av=*(const float4*)&aprevv[q*4];
          float4 w0=*(const float4*)&W12[(32+q*4+0)*192+c0];
          float4 w1=*(const float4*)&W12[(32+q*4+1)*192+c0];
          float4 w2=*(const float4*)&W12[(32+q*4+2)*192+c0];
          float4 w3=*(const float4*)&W12[(32+q*4+3)*192+c0];
          FMA4(A0,av.x,w0); FMA4(A1,av.y,w1); FMA4(A2,av.z,w2); FMA4(A3,av.w,w3);
        }
        float4 g=make_float4(A0.x+A1.x+A2.x+A3.x, A0.y+A1.y+A2.y+A3.y,
                             A0.z+A1.z+A2.z+A3.z, A0.w+A1.w+A2.w+A3.w);
        *(float4*)&gx[c0]=g;
      }
      {
        float r =sigf(gx[lane]+ghl[lane]);
        float zg=sigf(gx[64+lane]+ghl[64+lane]);
        float n =tanhf(gx[128+lane]+r*ghl[128+lane]);
        float h=ghs[lane];
        ghs[lane]=(1.f-zg)*n+zg*h;
      }
      if (lane<8){
        float s=soutb8[lane];
        #pragma unroll
        for (int q=0;q<16;q++){
          float4 g=*(const float4*)&ghs[q*4];
          float4 w=*(const float4*)&souWT[lane*64+q*4];
          s+=dot4(g,w);
        }
        float m8=s;
        m8=fmaxf(m8,__shfl_xor(m8,1)); m8=fmaxf(m8,__shfl_xor(m8,2)); m8=fmaxf(m8,__shfl_xor(m8,4));
        float e2=expf(s-m8);
        float ss=e2;
        ss+=__shfl_xor(ss,1); ss+=__shfl_xor(ss,2); ss+=__shfl_xor(ss,4);
        float av=e2/ss;
        alpha8[lane]=av;
        out[off_al+bt*8+lane]=av;
      }
    } else if (wid==1){
      if (t>0){
        const size_t bt1=bt-1;
        // Sinv = Linv^T @ Linv
        #pragma unroll
        for (int q=0;q<4;q++){
          int e=lane+64*q; int a2=e>>4, b2=e&15;
          float s=0.f;
          #pragma unroll
          for (int k=0;k<16;k++) s+=Linv[k*17+a2]*Linv[k*17+b2];
          Sinv[a2*L0+b2]=s;
        }
        // Kg = CPT@Sinv * m(t-1)
        {
          int i0=lane>>2, aq=lane&3;
          float4 k0=make_float4(0.f,0.f,0.f,0.f), k1=k0;
          #pragma unroll
          for (int q=0;q<4;q++){
            float4 ca=*(const float4*)&CPT[i0*L0+q*4];
            float4 cb=*(const float4*)&CPT[(i0+16)*L0+q*4];
            float4 v0=*(const float4*)&Sinv[(q*4+0)*L0+aq*4];
            float4 v1=*(const float4*)&Sinv[(q*4+1)*L0+aq*4];
            float4 v2=*(const float4*)&Sinv[(q*4+2)*L0+aq*4];
            float4 v3=*(const float4*)&Sinv[(q*4+3)*L0+aq*4];
            FMA4(k0,ca.x,v0); FMA4(k0,ca.y,v1); FMA4(k0,ca.z,v2); FMA4(k0,ca.w,v3);
            FMA4(k1,cb.x,v0); FMA4(k1,cb.y,v1); FMA4(k1,cb.z,v2); FMA4(k1,cb.w,v3);
          }
          float m=mvs2[pp];
          k0.x*=m;k0.y*=m;k0.z*=m;k0.w*=m;
          k1.x*=m;k1.y*=m;k1.z*=m;k1.w*=m;
          *(float4*)&Kg[i0*L0+aq*4]=k0;
          *(float4*)&Kg[(i0+16)*L0+aq*4]=k1;
        }
        // Pf = P - Kg@CP + 1e-3 I -> T3m + store
        {
          const int i0=(lane>>3)*4, j0=(lane&7)*4;
          float4 q0=*(const float4*)&P[(i0+0)*L6+j0];
          float4 q1=*(const float4*)&P[(i0+1)*L6+j0];
          float4 q2=*(const float4*)&P[(i0+2)*L6+j0];
          float4 q3=*(const float4*)&P[(i0+3)*L6+j0];
          #pragma unroll
          for (int q=0;q<4;q++){
            float4 a0=*(const float4*)&Kg[(i0+0)*L0+q*4];
            float4 a1=*(const float4*)&Kg[(i0+1)*L0+q*4];
            float4 a2=*(const float4*)&Kg[(i0+2)*L0+q*4];
            float4 a3=*(const float4*)&Kg[(i0+3)*L0+q*4];
            float4 bv;
            bv=*(const float4*)&CPm[(q*4+0)*L6+j0];
            FMA4(q0,-a0.x,bv); FMA4(q1,-a1.x,bv); FMA4(q2,-a2.x,bv); FMA4(q3,-a3.x,bv);
            bv=*(const float4*)&CPm[(q*4+1)*L6+j0];
            FMA4(q0,-a0.y,bv); FMA4(q1,-a1.y,bv); FMA4(q2,-a2.y,bv); FMA4(q3,-a3.y,bv);
            bv=*(const float4*)&CPm[(q*4+2)*L6+j0];
            FMA4(q0,-a0.z,bv); FMA4(q1,-a1.z,bv); FMA4(q2,-a2.z,bv); FMA4(q3,-a3.z,bv);
            bv=*(const float4*)&CPm[(q*4+3)*L6+j0];
            FMA4(q0,-a0.w,bv); FMA4(q1,-a1.w,bv); FMA4(q2,-a2.w,bv); FMA4(q3,-a3.w,bv);
          }
          int d0=i0-j0;
          if (d0>=0&&d0<4){ if(d0==0)q0.x+=1e-3f; else if(d0==1)q0.y+=1e-3f; else if(d0==2)q0.z+=1e-3f; else q0.w+=1e-3f; }
          int d1=i0+1-j0;
          if (d1>=0&&d1<4){ if(d1==0)q1.x+=1e-3f; else if(d1==1)q1.y+=1e-3f; else if(d1==2)q1.z+=1e-3f; else q1.w+=1e-3f; }
          int d2=i0+2-j0;
          if (d2>=0&&d2<4){ if(d2==0)q2.x+=1e-3f; else if(d2==1)q2.y+=1e-3f; else if(d2==2)q2.z+=1e-3f; else q2.w+=1e-3f; }
          int d3=i0+3-j0;
          if (d3>=0&&d3<4){ if(d3==0)q3.x+=1e-3f; else if(d3==1)q3.y+=1e-3f; else if(d3==2)q3.z+=1e-3f; else q3.w+=1e-3f; }
          *(float4*)&T3m[(i0+0)*L6+j0]=q0;
          *(float4*)&T3m[(i0+1)*L6+j0]=q1;
          *(float4*)&T3m[(i0+2)*L6+j0]=q2;
          *(float4*)&T3m[(i0+3)*L6+j0]=q3;
          *(float4*)&out[off_Pf+bt1*1024+(i0+0)*32+j0]=q0;
          *(float4*)&out[off_Pf+bt1*1024+(i0+1)*32+j0]=q1;
          *(float4*)&out[off_Pf+bt1*1024+(i0+2)*32+j0]=q2;
          *(float4*)&out[off_Pf+bt1*1024+(i0+3)*32+j0]=q3;
        }
      }
    } else if (wid==2){
      if (t>0){
        const size_t bt1=bt-1;
        float4 zq[8];
        #pragma unroll
        for (int q=0;q<8;q++) zq[q]=*(const float4*)&zc[q*4];
        if (lane<32){
          float s=0.f;
          #pragma unroll
          for (int q=0;q<8;q++) s+=dot4(*(const float4*)&Ak2[pp][lane*L6+q*4], zq[q]);
          float4 bk=*(const float4*)&Bk[lane*4];
          float4 u4=*(const float4*)&uk[0];
          s+=dot4(bk,u4);
          zpred[lane]=s;
          out[off_zp+bt1*32+lane]=s;
        }
        if (lane>=32 && lane<48){
          int a=lane-32;
          float s=0.f;
          #pragma unroll
          for (int q=0;q<8;q++) s+=dot4(*(const float4*)&Ck[a*L6+q*4], zq[q]);
          out[off_af+bt1*16+a]=s;
        }
        if (lane<16){
          float s=0.f;
          #pragma unroll
          for (int q=0;q<8;q++)
            s+=dot4(*(const float4*)&Ck[lane*L6+q*4], *(const float4*)&zpred[q*4]);
          out[off_ap+bt1*16+lane]=s;
        }
      }
    } else {
      // wid==3: ak load, zj, aj, ll+alpha_imm
      if (lane<16) ak[lane]=a_seq[bt*16+lane];
      float mv=mask[bt];
      float4 zq[8];
      #pragma unroll
      for (int q=0;q<8;q++) zq[q]=*(const float4*)&zc[q*4];
      #pragma unroll
      for (int r=0;r<4;r++){
        int e=lane+64*r; int k=e>>5, i=e&31;
        float s=0.f;
        #pragma unroll
        for (int q=0;q<8;q++) s+=dot4(*(const float4*)&sA[(k*32+i)*L6+q*4], zq[q]);
        zj[e]=s;
      }
      #pragma unroll
      for (int r=0;r<2;r++){
        int e=lane+64*r; int k=e>>4, a=e&15;
        float s=0.f;
        #pragma unroll
        for (int q=0;q<8;q++) s+=dot4(*(const float4*)&sC[(k*16+a)*L6+q*4], *(const float4*)&zj[k*32+q*4]);
        aj[e]=s;
      }
      if (lane<8){
        float s=0.f;
        #pragma unroll
        for (int q=0;q<4;q++){
          float4 av=*(const float4*)&ak[q*4];
          float4 jv=*(const float4*)&aj[lane*16+q*4];
          float dx=av.x-jv.x, dy=av.y-jv.y, dz=av.z-jv.z, dw=av.w-jv.w;
          s+=dx*dx+dy*dy+dz*dz+dw*dw;
        }
        float llv=-s;
        float m8=llv;
        m8=fmaxf(m8,__shfl_xor(m8,1)); m8=fmaxf(m8,__shfl_xor(m8,2)); m8=fmaxf(m8,__shfl_xor(m8,4));
        float e2=expf(llv-m8);
        float ss=e2;
        ss+=__shfl_xor(ss,1); ss+=__shfl_xor(ss,2); ss+=__shfl_xor(ss,4);
        out[off_ai+bt*8+lane]=e2/ss*mv;
      }
    }
    __syncthreads();

    // ===== Phase B =====
    if (wid==0 || wid==3){
      float alr[8];
      float4 a0v=*(const float4*)&alpha8[0], a1v=*(const float4*)&alpha8[4];
      alr[0]=a0v.x; alr[1]=a0v.y; alr[2]=a0v.z; alr[3]=a0v.w;
      alr[4]=a1v.x; alr[5]=a1v.y; alr[6]=a1v.z; alr[7]=a1v.w;
      if (wid==0){
        #pragma unroll
        for (int r=0;r<2;r++){
          int e=lane+64*r; int i=e>>3, qd=e&7;
          float4 acc=make_float4(0.f,0.f,0.f,0.f);
          #pragma unroll
          for (int k=0;k<8;k++){
            float4 av=*(const float4*)&sA[(k*32+i)*L6+qd*4];
            FMA4(acc,alr[k],av);
          }
          *(float4*)&Ak2[pc][i*L6+qd*4]=acc;
          AkT2[pc][(qd*4+0)*L6+i]=acc.x; AkT2[pc][(qd*4+1)*L6+i]=acc.y;
          AkT2[pc][(qd*4+2)*L6+i]=acc.z; AkT2[pc][(qd*4+3)*L6+i]=acc.w;
        }
        #pragma unroll
        for (int r=0;r<2;r++){
          int e=lane+64*r;
          float s=0.f;
          #pragma unroll
          for (int k=0;k<8;k++) s+=alr[k]*sBm[k*128+e];
          Bk[e]=s;
        }
        if (lane<32){
          float s=0.f;
          #pragma unroll
          for (int k=0;k<8;k++) s+=alr[k]*zj[k*32+lane];
          znew[lane]=s;
        }
      } else {
        #pragma unroll
        for (int r=2;r<4;r++){
          int e=lane+64*r; int i=e>>3, qd=e&7;
          float4 acc=make_float4(0.f,0.f,0.f,0.f);
          #pragma unroll
          for (int k=0;k<8;k++){
            float4 av=*(const float4*)&sA[(k*32+i)*L6+qd*4];
            FMA4(acc,alr[k],av);
          }
          *(float4*)&Ak2[pc][i*L6+qd*4]=acc;
          AkT2[pc][(qd*4+0)*L6+i]=acc.x; AkT2[pc][(qd*4+1)*L6+i]=acc.y;
          AkT2[pc][(qd*4+2)*L6+i]=acc.z; AkT2[pc][(qd*4+3)*L6+i]=acc.w;
        }
        #pragma unroll
        for (int r=0;r<2;r++){
          int e=lane+64*r; int a=e>>3, qd=e&7;
          float4 acc=make_float4(0.f,0.f,0.f,0.f);
          #pragma unroll
          for (int k=0;k<8;k++){
            float4 cv=*(const float4*)&sC[(k*16+a)*L6+qd*4];
            FMA4(acc,alr[k],cv);
          }
          *(float4*)&Ck[a*L6+qd*4]=acc;
        }
      }
    } else if (wid==1){
      if (t>0){
        const size_t bt1=bt-1;
        int row=lane<32?lane:31;
        float trl[32];
        #pragma unroll
        for (int q=0;q<8;q++){
          float4 v=*(const float4*)&T3m[row*L6+q*4];
          trl[q*4+0]=v.x; trl[q*4+1]=v.y; trl[q*4+2]=v.z; trl[q*4+3]=v.w;
        }
        #pragma unroll
        for (int c=0;c<32;c++){
          float d=rdlane(trl[c],c);
          float inv=rsqrtf(d);
          float lc=(lane==c)?d*inv:trl[c]*inv;
          trl[c]=lc;
          #pragma unroll
          for (int j=c+1;j<32;j++) trl[j]-=lc*rdlane(lc,j);
        }
        if (lane<32){
          #pragma unroll
          for (int q=0;q<8;q++){
            float t0=(q*4+0<=lane)?trl[q*4+0]:0.f;
            float t1=(q*4+1<=lane)?trl[q*4+1]:0.f;
            float t2=(q*4+2<=lane)?trl[q*4+2]:0.f;
            float t3=(q*4+3<=lane)?trl[q*4+3]:0.f;
            *(float4*)&out[off_tr+bt1*1024+lane*32+q*4]=make_float4(t0,t1,t2,t3);
          }
        }
      }
    } else {
      // wid==2: M3 = Ak(t-1)@T3m -> T1m ; Pp = T1m@AkT(t-1) + Q + 1e-3I -> P + store
      if (t>0){
        const size_t bt1=bt-1;
        {
          const int i0=(lane>>3)*4, j0=(lane&7)*4;
          float4 q0=make_float4(0.f,0.f,0.f,0.f), q1=q0, q2=q0, q3=q0;
          #pragma unroll 4
          for (int q=0;q<8;q++){
            float4 a0=*(const float4*)&Ak2[pp][(i0+0)*L6+q*4];
            float4 a1=*(const float4*)&Ak2[pp][(i0+1)*L6+q*4];
            float4 a2=*(const float4*)&Ak2[pp][(i0+2)*L6+q*4];
            float4 a3=*(const float4*)&Ak2[pp][(i0+3)*L6+q*4];
            float4 bv;
            bv=*(const float4*)&T3m[(q*4+0)*L6+j0];
            FMA4(q0,a0.x,bv); FMA4(q1,a1.x,bv); FMA4(q2,a2.x,bv); FMA4(q3,a3.x,bv);
            bv=*(const float4*)&T3m[(q*4+1)*L6+j0];
            FMA4(q0,a0.y,bv); FMA4(q1,a1.y,bv); FMA4(q2,a2.y,bv); FMA4(q3,a3.y,bv);
            bv=*(const float4*)&T3m[(q*4+2)*L6+j0];
            FMA4(q0,a0.z,bv); FMA4(q1,a1.z,bv); FMA4(q2,a2.z,bv); FMA4(q3,a3.z,bv);
            bv=*(const float4*)&T3m[(q*4+3)*L6+j0];
            FMA4(q0,a0.w,bv); FMA4(q1,a1.w,bv); FMA4(q2,a2.w,bv); FMA4(q3,a3.w,bv);
          }
          *(float4*)&T1m[(i0+0)*L6+j0]=q0;
          *(float4*)&T1m[(i0+1)*L6+j0]=q1;
          *(float4*)&T1m[(i0+2)*L6+j0]=q2;
          *(float4*)&T1m[(i0+3)*L6+j0]=q3;
        }
        {
          const int i0=(lane>>3)*4, j0=(lane&7)*4;
          float4 q0=*(const float4*)&Qm[(i0+0)*L6+j0];
          float4 q1=*(const float4*)&Qm[(i0+1)*L6+j0];
          float4 q2=*(const float4*)&Qm[(i0+2)*L6+j0];
          float4 q3=*(const float4*)&Qm[(i0+3)*L6+j0];
          int d0=i0-j0;
          if (d0>=0&&d0<4){ if(d0==0)q0.x+=1e-3f; else if(d0==1)q0.y+=1e-3f; else if(d0==2)q0.z+=1e-3f; else q0.w+=1e-3f; }
          int d1=i0+1-j0;
          if (d1>=0&&d1<4){ if(d1==0)q1.x+=1e-3f; else if(d1==1)q1.y+=1e-3f; else if(d1==2)q1.z+=1e-3f; else q1.w+=1e-3f; }
          int d2=i0+2-j0;
          if (d2>=0&&d2<4){ if(d2==0)q2.x+=1e-3f; else if(d2==1)q2.y+=1e-3f; else if(d2==2)q2.z+=1e-3f; else q2.w+=1e-3f; }
          int d3=i0+3-j0;
          if (d3>=0&&d3<4){ if(d3==0)q3.x+=1e-3f; else if(d3==1)q3.y+=1e-3f; else if(d3==2)q3.z+=1e-3f; else q3.w+=1e-3f; }
          #pragma unroll 4
          for (int q=0;q<8;q++){
            float4 a0=*(const float4*)&T1m[(i0+0)*L6+q*4];
            float4 a1=*(const float4*)&T1m[(i0+1)*L6+q*4];
            float4 a2=*(const float4*)&T1m[(i0+2)*L6+q*4];
            float4 a3=*(const float4*)&T1m[(i0+3)*L6+q*4];
            float4 bv;
            bv=*(const float4*)&AkT2[pp][(q*4+0)*L6+j0];
            FMA4(q0,a0.x,bv); FMA4(q1,a1.x,bv); FMA4(q2,a2.x,bv); FMA4(q3,a3.x,bv);
            bv=*(const float4*)&AkT2[pp][(q*4+1)*L6+j0];
            FMA4(q0,a0.y,bv); FMA4(q1,a1.y,bv); FMA4(q2,a2.y,bv); FMA4(q3,a3.y,bv);
            bv=*(const float4*)&AkT2[pp][(q*4+2)*L6+j0];
            FMA4(q0,a0.z,bv); FMA4(q1,a1.z,bv); FMA4(q2,a2.z,bv); FMA4(q3,a3.z,bv);
            bv=*(const float4*)&AkT2[pp][(q*4+3)*L6+j0];
            FMA4(q0,a0.w,bv); FMA4(q1,a1.w,bv); FMA4(q2,a2.w,bv); FMA4(q3,a3.w,bv);
          }
          *(float4*)&P[(i0+0)*L6+j0]=q0;
          *(float4*)&P[(i0+1)*L6+j0]=q1;
          *(float4*)&P[(i0+2)*L6+j0]=q2;
          *(float4*)&P[(i0+3)*L6+j0]=q3;
          *(float4*)&out[off_Pp+bt1*1024+(i0+0)*32+j0]=q0;
          *(float4*)&out[off_Pp+bt1*1024+(i0+1)*32+j0]=q1;
          *(float4*)&out[off_Pp+bt1*1024+(i0+2)*32+j0]=q2;
          *(float4*)&out[off_Pp+bt1*1024+(i0+3)*32+j0]=q3;
        }
      }
    }
    __syncthreads();

    // ===== Phase C =====
    if (wid==0){
      // CP = Ck@P (+CPT)
      {
        int qd=lane&7, a0=lane>>3;
        float4 d0=make_float4(0.f,0.f,0.f,0.f), d1=d0;
        #pragma unroll 2
        for (int q=0;q<8;q++){
          float4 c0=*(const float4*)&Ck[a0*L6+q*4];
          float4 c1=*(const float4*)&Ck[(a0+8)*L6+q*4];
          float4 p0=*(const float4*)&P[(q*4+0)*L6+qd*4];
          float4 p1=*(const float4*)&P[(q*4+1)*L6+qd*4];
          float4 p2=*(const float4*)&P[(q*4+2)*L6+qd*4];
          float4 p3=*(const float4*)&P[(q*4+3)*L6+qd*4];
          FMA4(d0,c0.x,p0); FMA4(d0,c0.y,p1); FMA4(d0,c0.z,p2); FMA4(d0,c0.w,p3);
          FMA4(d1,c1.x,p0); FMA4(d1,c1.y,p1); FMA4(d1,c1.z,p2); FMA4(d1,c1.w,p3);
        }
        *(float4*)&CPm[a0*L6+qd*4]=d0;
        *(float4*)&CPm[(a0+8)*L6+qd*4]=d1;
        CPT[(qd*4+0)*L0+a0]=d0.x; CPT[(qd*4+1)*L0+a0]=d0.y;
        CPT[(qd*4+2)*L0+a0]=d0.z; CPT[(qd*4+3)*L0+a0]=d0.w;
        CPT[(qd*4+0)*L0+a0+8]=d1.x; CPT[(qd*4+1)*L0+a0+8]=d1.y;
        CPT[(qd*4+2)*L0+a0+8]=d1.z; CPT[(qd*4+3)*L0+a0+8]=d1.w;
      }
      // rk = ak - Ck@znew
      if (lane<16){
        float s=0.f;
        #pragma unroll
        for (int q=0;q<8;q++) s+=dot4(*(const float4*)&Ck[lane*L6+q*4], *(const float4*)&znew[q*4]);
        rk[lane]=ak[lane]-s;
      }
      // S + store
      {
        int a2=lane>>2, cq=lane&3;
        float s0=0.f,s1=0.f,s2=0.f,s3=0.f;
        #pragma unroll 2
        for (int q=0;q<8;q++){
          float4 cp=*(const float4*)&CPm[a2*L6+q*4];
          s0+=dot4(cp,*(const float4*)&Ck[(cq*4+0)*L6+q*4]);
          s1+=dot4(cp,*(const float4*)&Ck[(cq*4+1)*L6+q*4]);
          s2+=dot4(cp,*(const float4*)&Ck[(cq*4+2)*L6+q*4]);
          s3+=dot4(cp,*(const float4*)&Ck[(cq*4+3)*L6+q*4]);
        }
        float4 rm=*(const float4*)&Rm[a2*L0+cq*4];
        s0+=rm.x+((a2==cq*4+0)?1e-4f:0.f);
        s1+=rm.y+((a2==cq*4+1)?1e-4f:0.f);
        s2+=rm.z+((a2==cq*4+2)?1e-4f:0.f);
        s3+=rm.w+((a2==cq*4+3)?1e-4f:0.f);
        float4 sv=make_float4(s0,s1,s2,s3);
        *(float4*)&Sm[a2*L0+cq*4]=sv;
        *(float4*)&out[off_S+bt*256+lane*4]=sv;
      }
      // chol16 + forward solve -> Linv
      {
        int row=lane<16?lane:15;
        float Sr[16], invd[16];
        #pragma unroll
        for (int q=0;q<4;q++){
          float4 v=*(const float4*)&Sm[row*L0+q*4];
          Sr[q*4+0]=v.x; Sr[q*4+1]=v.y; Sr[q*4+2]=v.z; Sr[q*4+3]=v.w;
        }
        #pragma unroll
        for (int c=0;c<16;c++){
          float d=rdlane(Sr[c],c);
          float inv=rsqrtf(d);
          invd[c]=inv;
          float lc=(lane==c)?d*inv:Sr[c]*inv;
          Sr[c]=lc;
          #pragma unroll
          for (int j=c+1;j<16;j++) Sr[j]-=lc*rdlane(lc,j);
        }
        float Li[16], rhs[16];
        #pragma unroll
        for (int r=0;r<16;r++) rhs[r]=(lane==r)?1.f:0.f;
        #pragma unroll
        for (int k=0;k<16;k++){
          float lik=rhs[k]*invd[k];
          Li[k]=lik;
          #pragma unroll
          for (int r=k+1;r<16;r++) rhs[r]-=rdlane(Sr[k],r)*lik;
        }
        if (lane<16){
          #pragma unroll
          for (int r=0;r<16;r++) Linv[r*17+lane]=Li[r];
        }
      }
      // y = Linv @ (m*rk) ; w = Linv^T @ y
      if (lane<16){
        float m=mvs2[pc];
        float s=0.f;
        #pragma unroll
        for (int k=0;k<16;k++) s+=Linv[lane*17+k]*(m*rk[k]);
        ys[lane]=s;
      }
      if (lane<16){
        float s=0.f;
        #pragma unroll
        for (int r=0;r<16;r++) s+=Linv[r*17+lane]*ys[r];
        ws[lane]=s;
      }
      // zloc = znew + CPT@w ; carries + stores
      if (lane<32){
        float s=znew[lane];
        #pragma unroll
        for (int q=0;q<4;q++)
          s+=dot4(*(const float4*)&CPT[lane*L0+q*4], *(const float4*)&ws[q*4]);
        zloc[lane]=s;
        zc[lane]=s;
        out[off_zf+bt*32+lane]=s;
        out[off_zl+bt*32+lane]=s;
      }
    } else if (wid==1){
      // ghl(t+1) = ghs(t) @ Wh
      if (lane<48){
        const int c0=lane*4;
        float4 A0=make_float4(0.f,0.f,0.f,0.f), A1=A0, A2=A0, A3=A0;
        #pragma unroll
        for (int q=0;q<16;q++){
          float4 gv=*(const float4*)&ghs[q*4];
          float4 w0=*(const float4*)(Wh+(size_t)(q*4+0)*192+c0);
          float4 w1=*(const float4*)(Wh+(size_t)(q*4+1)*192+c0);
          float4 w2=*(const float4*)(Wh+(size_t)(q*4+2)*192+c0);
          float4 w3=*(const float4*)(Wh+(size_t)(q*4+3)*192+c0);
          FMA4(A0,gv.x,w0); FMA4(A1,gv.y,w1); FMA4(A2,gv.z,w2); FMA4(A3,gv.w,w3);
        }
        float4 g=make_float4(A0.x+A1.x+A2.x+A3.x, A0.y+A1.y+A2.y+A3.y,
                             A0.z+A1.z+A2.z+A3.z, A0.w+A1.w+A2.w+A3.w);
        *(float4*)&ghl[c0]=g;
      }
    } else if (wid==2){
      if (lane<4) uk[lane]=u_seq[bt*4+lane];
    }
    __syncthreads();
  }

  // ===== Epilogue: tail(T-1) =====
  {
    const size_t btL=(size_t)b*T+(T-1);
    const int pl=(T-1)&1;
    if (wid==1){
      #pragma unroll
      for (int q=0;q<4;q++){
        int e=lane+64*q; int a2=e>>4, b2=e&15;
        float s=0.f;
        #pragma unroll
        for (int k=0;k<16;k++) s+=Linv[k*17+a2]*Linv[k*17+b2];
        Sinv[a2*L0+b2]=s;
      }
      {
        int i0=lane>>2, aq=lane&3;
        float4 k0=make_float4(0.f,0.f,0.f,0.f), k1=k0;
        #pragma unroll
        for (int q=0;q<4;q++){
          float4 ca=*(const float4*)&CPT[i0*L0+q*4];
          float4 cb=*(const float4*)&CPT[(i0+16)*L0+q*4];
          float4 v0=*(const float4*)&Sinv[(q*4+0)*L0+aq*4];
          float4 v1=*(const float4*)&Sinv[(q*4+1)*L0+aq*4];
          float4 v2=*(const float4*)&Sinv[(q*4+2)*L0+aq*4];
          float4 v3=*(const float4*)&Sinv[(q*4+3)*L0+aq*4];
          FMA4(k0,ca.x,v0); FMA4(k0,ca.y,v1); FMA4(k0,ca.z,v2); FMA4(k0,ca.w,v3);
          FMA4(k1,cb.x,v0); FMA4(k1,cb.y,v1); FMA4(k1,cb.z,v2); FMA4(k1,cb.w,v3);
        }
        float m=mvs2[pl];
        k0.x*=m;k0.y*=m;k0.z*=m;k0.w*=m;
        k1.x*=m;k1.y*=m;k1.z*=m;k1.w*=m;
        *(float4*)&Kg[i0*L0+aq*4]=k0;
        *(float4*)&Kg[(i0+16)*L0+aq*4]=k1;
      }
      {
        const int i0=(lane>>3)*4, j0=(lane&7)*4;
        float4 q0=*(const float4*)&P[(i0+0)*L6+j0];
        float4 q1=*(const float4*)&P[(i0+1)*L6+j0];
        float4 q2=*(const float4*)&P[(i0+2)*L6+j0];
        float4 q3=*(const float4*)&P[(i0+3)*L6+j0];
        #pragma unroll
        for (int q=0;q<4;q++){
          float4 a0=*(const float4*)&Kg[(i0+0)*L0+q*4];
          float4 a1=*(const float4*)&Kg[(i0+1)*L0+q*4];
          float4 a2=*(const float4*)&Kg[(i0+2)*L0+q*4];
          float4 a3=*(const float4*)&Kg[(i0+3)*L0+q*4];
          float4 bv;
          bv=*(const float4*)&CPm[(q*4+0)*L6+j0];
          FMA4(q0,-a0.x,bv); FMA4(q1,-a1.x,bv); FMA4(q2,-a2.x,bv); FMA4(q3,-a3.x,bv);
          bv=*(const float4*)&CPm[(q*4+1)*L6+j0];
          FMA4(q0,-a0.y,bv); FMA4(q1,-a1.y,bv); FMA4(q2,-a2.y,bv); FMA4(q3,-a3.y,bv);
          bv=*(const float4*)&CPm[(q*4+2)*L6+j0];
          FMA4(q0,-a0.z,bv); FMA4(q1,-a1.z,bv); FMA4(q2,-a2.z,bv); FMA4(q3,-a3.z,bv);
          bv=*(const float4*)&CPm[(q*4+3)*L6+j0];
          FMA4(q0,-a0.w,bv); FMA4(q1,-a1.w,bv); FMA4(q2,-a2.w,bv); FMA4(q3,-a3.w,bv);
        }
        int d0=i0-j0;
        if (d0>=0&&d0<4){ if(d0==0)q0.x+=1e-3f; else if(d0==1)q0.y+=1e-3f; else if(d0==2)q0.z+=1e-3f; else q0.w+=1e-3f; }
        int d1=i0+1-j0;
        if (d1>=0&&d1<4){ if(d1==0)q1.x+=1e-3f; else if(d1==1)q1.y+=1e-3f; else if(d1==2)q1.z+=1e-3f; else q1.w+=1e-3f; }
        int d2=i0+2-j0;
        if (d2>=0&&d2<4){ if(d2==0)q2.x+=1e-3f; else if(d2==1)q2.y+=1e-3f; else if(d2==2)q2.z+=1e-3f; else q2.w+=1e-3f; }
        int d3=i0+3-j0;
        if (d3>=0&&d3<4){ if(d3==0)q3.x+=1e-3f; else if(d3==1)q3.y+=1e-3f; else if(d3==2)q3.z+=1e-3f; else q3.w+=1e-3f; }
        *(float4*)&T3m[(i0+0)*L6+j0]=q0;
        *(float4*)&T3m[(i0+1)*L6+j0]=q1;
        *(float4*)&T3m[(i0+2)*L6+j0]=q2;
        *(float4*)&T3m[(i0+3)*L6+j0]=q3;
        *(float4*)&out[off_Pf+btL*1024+(i0+0)*32+j0]=q0;
        *(float4*)&out[off_Pf+btL*1024+(i0+1)*32+j0]=q1;
        *(float4*)&out[off_Pf+btL*1024+(i0+2)*32+j0]=q2;
        *(float4*)&out[off_Pf+btL*1024+(i0+3)*32+j0]=q3;
      }
    } else if (wid==2){
      float4 zq[8];
      #pragma unroll
      for (int q=0;q<8;q++) zq[q]=*(const float4*)&zc[q*4];
      if (lane<32){
        float s=0.f;
        #pragma unroll
        for (int q=0;q<8;q++) s+=dot4(*(const float4*)&Ak2[pl][lane*L6+q*4], zq[q]);
        float4 bk=*(const float4*)&Bk[lane*4];
        float4 u4=*(const float4*)&uk[0];
        s+=dot4(bk,u4);
        zpred[lane]=s;
        out[off_zp+btL*32+lane]=s;
      }
      if (lane>=32 && lane<48){
        int a=lane-32;
        float s=0.f;
        #pragma unroll
        for (int q=0;q<8;q++) s+=dot4(*(const float4*)&Ck[a*L6+q*4], zq[q]);
        out[off_af+btL*16+a]=s;
      }
      if (lane<16){
        float s=0.f;
        #pragma unroll
        for (int q=0;q<8;q++)
          s+=dot4(*(const float4*)&Ck[lane*L6+q*4], *(const float4*)&zpred[q*4]);
        out[off_ap+btL*16+lane]=s;
      }
    }
    __syncthreads();
    if (wid==1){
      int row=lane<32?lane:31;
      float trl[32];
      #pragma unroll
      for (int q=0;q<8;q++){
        float4 v=*(const float4*)&T3m[row*L6+q*4];
        trl[q*4+0]=v.x; trl[q*4+1]=v.y; trl[q*4+2]=v.z; trl[q*4+3]=v.w;
      }
      #pragma unroll
      for (int c=0;c<32;c++){
        float d=rdlane(trl[c],c);
        float inv=rsqrtf(d);
        float lc=(lane==c)?d*inv:trl[c]*inv;
        trl[c]=lc;
        #pragma unroll
        for (int j=c+1;j<32;j++) trl[j]-=lc*rdlane(lc,j);
      }
      if (lane<32){
        #pragma unroll
        for (int q=0;q<8;q++){
          float t0=(q*4+0<=lane)?trl[q*4+0]:0.f;
          float t1=(q*4+1<=lane)?trl[q*4+1]:0.f;
          float t2=(q*4+2<=lane)?trl[q*4+2]:0.f;
          float t3=(q*4+3<=lane)?trl[q*4+3]:0.f;
          *(float4*)&out[off_tr+btL*1024+lane*32+q*4]=make_float4(t0,t1,t2,t3);
        }
      }
    } else if (wid==2){
      {
        const int i0=(lane>>3)*4, j0=(lane&7)*4;
        float4 q0=make_float4(0.f,0.f,0.f,0.f), q1=q0, q2=q0, q3=q0;
        #pragma unroll 4
        for (int q=0;q<8;q++){
          float4 a0=*(const float4*)&Ak2[pl][(i0+0)*L6+q*4];
          float4 a1=*(const float4*)&Ak2[pl][(i0+1)*L6+q*4];
          float4 a2=*(const float4*)&Ak2[pl][(i0+2)*L6+q*4];
          float4 a3=*(const float4*)&Ak2[pl][(i0+3)*L6+q*4];
          float4 bv;
          bv=*(const float4*)&T3m[(q*4+0)*L6+j0];
          FMA4(q0,a0.x,bv); FMA4(q1,a1.x,bv); FMA4(q2,a2.x,bv); FMA4(q3,a3.x,bv);
          bv=*(const float4*)&T3m[(q*4+1)*L6+j0];
          FMA4(q0,a0.y,bv); FMA4(q1,a1.y,bv); FMA4(q2,a2.y,bv); FMA4(q3,a3.y,bv);
          bv=*(const float4*)&T3m[(q*4+2)*L6+j0];
          FMA4(q0,a0.z,bv); FMA4(q1,a1.z,bv); FMA4(q2,a2.z,bv); FMA4(q3,a3.z,bv);
          bv=*(const float4*)&T3m[(q*4+3)*L6+j0];
          FMA4(q0,a0.w,bv); FMA4(q1,a1.w,bv); FMA4(q2,a2.w,bv); FMA4(q3,a3.w,bv);
        }
        *(float4*)&T1m[(i0+0)*L6+j0]=q0;
        *(float4*)&T1m[(i0+1)*L6+j0]=q1;
        *(float4*)&T1m[(i0+2)*L6+j0]=q2;
        *(float4*)&T1m[(i0+3)*L6+j0]=q3;
      }
      {
        const int i0=(lane>>3)*4, j0=(lane&7)*4;
        float4 q0=*(const float4*)&Qm[(i0+0)*L6+j0];
        float4 q1=*(const float4*)&Qm[(i0+1)*L6+j0];
        float4 q2=*(const float4*)&Qm[(i0+2)*L6+j0];
        float4 q3=*(const float4*)&Qm[(i0+3)*L6+j0];
        int d0=i0-j0;
        if (d0>=0&&d0<4){ if(d0==0)q0.x+=1e-3f; else if(d0==1)q0.y+=1e-3f; else if(d0==2)q0.z+=1e-3f; else q0.w+=1e-3f; }
        int d1=i0+1-j0;
        if (d1>=0&&d1<4){ if(d1==0)q1.x+=1e-3f; else if(d1==1)q1.y+=1e-3f; else if(d1==2)q1.z+=1e-3f; else q1.w+=1e-3f; }
        int d2=i0+2-j0;
        if (d2>=0&&d2<4){ if(d2==0)q2.x+=1e-3f; else if(d2==1)q2.y+=1e-3f; else if(d2==2)q2.z+=1e-3f; else q2.w+=1e-3f; }
        int d3=i0+3-j0;
        if (d3>=0&&d3<4){ if(d3==0)q3.x+=1e-3f; else if(d3==1)q3.y+=1e-3f; else if(d3==2)q3.z+=1e-3f; else q3.w+=1e-3f; }
        #pragma unroll 4
        for (int q=0;q<8;q++){
          float4 a0=*(const float4*)&T1m[(i0+0)*L6+q*4];
          float4 a1=*(const float4*)&T1m[(i0+1)*L6+q*4];
          float4 a2=*(const float4*)&T1m[(i0+2)*L6+q*4];
          float4 a3=*(const float4*)&T1m[(i0+3)*L6+q*4];
          float4 bv;
          bv=*(const float4*)&AkT2[pl][(q*4+0)*L6+j0];
          FMA4(q0,a0.x,bv); FMA4(q1,a1.x,bv); FMA4(q2,a2.x,bv); FMA4(q3,a3.x,bv);
          bv=*(const float4*)&AkT2[pl][(q*4+1)*L6+j0];
          FMA4(q0,a0.y,bv); FMA4(q1,a1.y,bv); FMA4(q2,a2.y,bv); FMA4(q3,a3.y,bv);
          bv=*(const float4*)&AkT2[pl][(q*4+2)*L6+j0];
          FMA4(q0,a0.z,bv); FMA4(q1,a1.z,bv); FMA4(q2,a2.z,bv); FMA4(q3,a3.z,bv);
          bv=*(const float4*)&AkT2[pl][(q*4+3)*L6+j0];
          FMA4(q0,a0.w,bv); FMA4(q1,a1.w,bv); FMA4(q2,a2.w,bv); FMA4(q3,a3.w,bv);
        }
        *(float4*)&out[off_Pp+btL*1024+(i0+0)*32+j0]=q0;
        *(float4*)&out[off_Pp+btL*1024+(i0+1)*32+j0]=q1;
        *(float4*)&out[off_Pp+btL*1024+(i0+2)*32+j0]=q2;
        *(float4*)&out[off_Pp+btL*1024+(i0+3)*32+j0]=q3;
      }
    }
  }
}

extern "C" void kernel_launch(void* const* d_in, const int* in_sizes, int n_in,
                              void* d_out, int out_size, void* d_ws, size_t ws_size,
                              hipStream_t stream) {
  kf_fwd<<<128, NT, 0, stream>>>(
    (const float*)d_in[0],  // a_seq
    (const float*)d_in[1],  // h_obs
    (const float*)d_in[2],  // A_matrices
    (const float*)d_in[3],  // C_matrices
    (const float*)d_in[4],  // B_matrices
    (const float*)d_in[5],  // u_seq
    (const float*)d_in[6],  // mask
    (const float*)d_in[7],  // P_0
    (const float*)d_in[8],  // mat_Q
    (const float*)d_in[9],  // mat_R
    (const float*)d_in[10], // gru_Wx
    (const float*)d_in[11], // gru_Wh
    (const float*)d_in[12], // gru_b
    (const float*)d_in[13], // out_W
    (const float*)d_in[14], // out_b
    (float*)d_out);
}

// Round 12
// 2400.093 us; speedup vs baseline: 7.0095x; 1.0940x over previous
//
#include <hip/hip_runtime.h>
#include <math.h>

#define NT 256
#define FMA4(acc,u,bv) {acc.x+=(u)*(bv).x; acc.y+=(u)*(bv).y; acc.z+=(u)*(bv).z; acc.w+=(u)*(bv).w;}

__device__ __forceinline__ float sigf(float x){ return 1.0f/(1.0f+expf(-x)); }
__device__ __forceinline__ float rdlane(float v, int l){
  return __int_as_float(__builtin_amdgcn_readlane(__float_as_int(v), l));
}
__device__ __forceinline__ float dot4(float4 a, float4 b){
  return a.x*b.x + a.y*b.y + a.z*b.z + a.w*b.w;
}

__launch_bounds__(NT, 1)
__global__ void kf_fwd(const float* __restrict__ a_seq, const float* __restrict__ h_obs,
  const float* __restrict__ Amat, const float* __restrict__ Cmat, const float* __restrict__ Bmat,
  const float* __restrict__ u_seq, const float* __restrict__ mask, const float* __restrict__ P0,
  const float* __restrict__ matQ, const float* __restrict__ matR,
  const float* __restrict__ Wx, const float* __restrict__ Wh, const float* __restrict__ gbias,
  const float* __restrict__ outW, const float* __restrict__ outb, float* __restrict__ out)
{
  constexpr int T=256, B=128;
  constexpr int L6=36, L0=20;
  constexpr size_t BT=(size_t)B*T;
  const size_t off_zf=0;
  const size_t off_Pf=off_zf+BT*32;
  const size_t off_zl=off_Pf+BT*1024;
  const size_t off_tr=off_zl+BT*32;
  const size_t off_zp=off_tr+BT*1024;
  const size_t off_Pp=off_zp+BT*32;
  const size_t off_af=off_Pp+BT*1024;
  const size_t off_ap=off_af+BT*16;
  const size_t off_S =off_ap+BT*16;
  const size_t off_al=off_S +BT*256;
  const size_t off_ai=off_al+BT*8;
  const size_t off_R =off_ai+BT*8;
  const size_t off_Q =off_R +256;

  __shared__ __align__(16) float sA[8*32*L6];
  __shared__ __align__(16) float sC[8*16*L6];
  __shared__ __align__(16) float W12[48*192];
  __shared__ __align__(16) float gxh[192];
  __shared__ __align__(16) float sBm[1024];
  __shared__ __align__(16) float souWT[512];
  __shared__ __align__(16) float soutb8[8];
  __shared__ __align__(16) float P[32*L6], T1m[32*L6], T3m[32*L6], Qm[32*L6];
  __shared__ __align__(16) float Ak2[2][32*L6], AkT2[2][32*L6];
  __shared__ __align__(16) float Ck2[2][16*L6];
  __shared__ __align__(16) float CPm[16*L6];
  __shared__ __align__(16) float CPT[32*L0], Kg[32*L0];
  __shared__ __align__(16) float Sm[16*L0], Rm[16*L0], Sinv[16*L0];
  __shared__ __align__(16) float Linv[16*17];
  __shared__ __align__(16) float Bk[128];
  __shared__ __align__(16) float zj[256], aj[128];
  __shared__ __align__(16) float gx[192], ghl[192];
  __shared__ __align__(16) float zc[32], znew[32], zloc[32], zpred[32], ghs[64];
  __shared__ __align__(16) float aprevv[16], hob[16];
  __shared__ __align__(16) float ak[16], uk[4], rk[16], alpha8[8];
  __shared__ __align__(16) float ys[16], ws[16];
  __shared__ float mvs2[2];

  const int tid  = threadIdx.x;
  const int wid  = tid>>6;
  const int lane = tid&63;
  const int b = blockIdx.x;

  // ---------- init ----------
  for (int e=tid; e<8192; e+=NT){ int k=e>>10, i=(e>>5)&31, j=e&31; sA[(k*32+i)*L6+j]=Amat[e]; }
  for (int e=tid; e<4096; e+=NT){ int k=e>>9, a=(e>>5)&15, i=e&31; sC[(k*16+a)*L6+i]=Cmat[e]; }
  for (int e=tid; e<1024; e+=NT) sBm[e]=Bmat[e];
  for (int e=tid; e<512; e+=NT){ int r=e>>6, q=e&63; souWT[r*64+q]=outW[q*8+r]; }
  if (tid<8) soutb8[tid]=outb[tid];
  for (int e=tid; e<1024; e+=NT){
    int i=e>>5, j=e&31;
    float s=0.f;
    #pragma unroll 8
    for (int k=0;k<32;k++) s += matQ[i*32+k]*matQ[j*32+k];
    Qm[i*L6+j]=s+(i==j?0.001f:0.f);
    P[i*L6+j]=P0[e];
  }
  for (int e=tid; e<256; e+=NT){
    int i=e>>4, j=e&15;
    float s=0.f;
    #pragma unroll
    for (int k=0;k<16;k++) s += matR[i*16+k]*matR[j*16+k];
    Rm[i*L0+j]=s+(i==j?0.001f:0.f);
  }
  for (int e=tid; e<16*L6; e+=NT){ Ck2[0][e]=0.f; Ck2[1][e]=0.f; }
  if (tid<32) zc[tid]=0.f;
  if (tid<64) ghs[tid]=0.f;
  for (int e=tid; e<192; e+=NT) ghl[e]=0.f;
  if (tid<16) hob[tid]=h_obs[b*16+tid];
  __syncthreads();

  // W1 rows + gxh
  if (tid<48){
    const int c0=tid*4;
    #pragma unroll
    for (int a=0;a<16;a++)
      *(float4*)&W12[(32+a)*192+c0] = *(const float4*)(Wx+(size_t)a*192+c0);
    float4 acc=*(const float4*)(gbias+c0);
    #pragma unroll
    for (int i=0;i<16;i++){
      float4 w=*(const float4*)(Wx+(size_t)(16+i)*192+c0);
      float hv=hob[i];
      FMA4(acc,hv,w);
    }
    *(float4*)&gxh[c0]=acc;
  }
  // W2 = Wx[32:64] + M,  M = sum_k CA_k^T @ Wx[64+16k : 80+16k]
  for (int ic=0; ic<4; ++ic){
    float4 Mi[8];
    if (tid<48){
      const int c0=tid*4;
      #pragma unroll
      for (int ii=0;ii<8;ii++)
        Mi[ii]=*(const float4*)(Wx+(size_t)(32+ic*8+ii)*192+c0);
    }
    for (int k=0;k<8;k++){
      __syncthreads();
      if (tid<128){
        int e=tid; int a=e>>3, ii=e&7; int i=ic*8+ii;
        float s=0.f;
        #pragma unroll 8
        for (int j=0;j<32;j++) s+=sC[(k*16+a)*L6+j]*sA[(k*32+j)*L6+i];
        Kg[a*8+ii]=s;
      }
      __syncthreads();
      if (tid<48){
        const int c0=tid*4;
        #pragma unroll
        for (int a=0;a<16;a++){
          float4 w=*(const float4*)(Wx+(size_t)(64+16*k+a)*192+c0);
          #pragma unroll
          for (int ii=0;ii<8;ii++){
            float ca=Kg[a*8+ii];
            FMA4(Mi[ii],ca,w);
          }
        }
      }
    }
    if (tid<48){
      const int c0=tid*4;
      #pragma unroll
      for (int ii=0;ii<8;ii++)
        *(float4*)&W12[(ic*8+ii)*192+c0]=Mi[ii];
    }
  }
  if (b==0){
    for (int e=tid;e<256;e+=NT) out[off_R+e]=Rm[(e>>4)*L0+(e&15)];
    for (int e=tid;e<1024;e+=NT) out[off_Q+e]=Qm[(e>>5)*L6+(e&31)];
  }
  __syncthreads();

  for (int t=0;t<T;t++){
    const size_t bt=(size_t)b*T+t;
    const int pc=t&1, pp=pc^1;

    // ===== Phase A =====
    if (wid==0){
      // head(t): aprev -> gx -> gates -> logits -> alpha -> Ck(t) blend (in-wave)
      if (lane==0) mvs2[pc]=mask[bt];
      float4 zq[8];
      #pragma unroll
      for (int q=0;q<8;q++) zq[q]=*(const float4*)&zc[q*4];
      if (lane<16){
        float s=0.f;
        #pragma unroll
        for (int q=0;q<8;q++) s+=dot4(*(const float4*)&Ck2[pp][lane*L6+q*4], zq[q]);
        aprevv[lane]=s;
      }
      if (lane<48){
        const int c0=lane*4;
        float4 A0=*(const float4*)&gxh[c0];
        float4 A1=make_float4(0.f,0.f,0.f,0.f), A2=A1, A3=A1;
        #pragma unroll
        for (int q=0;q<8;q++){
          float4 zv=zq[q];
          float4 w0=*(const float4*)&W12[(q*4+0)*192+c0];
          float4 w1=*(const float4*)&W12[(q*4+1)*192+c0];
          float4 w2=*(const float4*)&W12[(q*4+2)*192+c0];
          float4 w3=*(const float4*)&W12[(q*4+3)*192+c0];
          FMA4(A0,zv.x,w0); FMA4(A1,zv.y,w1); FMA4(A2,zv.z,w2); FMA4(A3,zv.w,w3);
        }
        #pragma unroll
        for (int q=0;q<4;q++){
          float4 av=*(const float4*)&aprevv[q*4];
          float4 w0=*(const float4*)&W12[(32+q*4+0)*192+c0];
          float4 w1=*(const float4*)&W12[(32+q*4+1)*192+c0];
          float4 w2=*(const float4*)&W12[(32+q*4+2)*192+c0];
          float4 w3=*(const float4*)&W12[(32+q*4+3)*192+c0];
          FMA4(A0,av.x,w0); FMA4(A1,av.y,w1); FMA4(A2,av.z,w2); FMA4(A3,av.w,w3);
        }
        float4 g=make_float4(A0.x+A1.x+A2.x+A3.x, A0.y+A1.y+A2.y+A3.y,
                             A0.z+A1.z+A2.z+A3.z, A0.w+A1.w+A2.w+A3.w);
        *(float4*)&gx[c0]=g;
      }
      {
        float r =sigf(gx[lane]+ghl[lane]);
        float zg=sigf(gx[64+lane]+ghl[64+lane]);
        float n =tanhf(gx[128+lane]+r*ghl[128+lane]);
        float h=ghs[lane];
        ghs[lane]=(1.f-zg)*n+zg*h;
      }
      if (lane<8){
        float s=soutb8[lane];
        #pragma unroll
        for (int q=0;q<16;q++){
          float4 g=*(const float4*)&ghs[q*4];
          float4 w=*(const float4*)&souWT[lane*64+q*4];
          s+=dot4(g,w);
        }
        float m8=s;
        m8=fmaxf(m8,__shfl_xor(m8,1)); m8=fmaxf(m8,__shfl_xor(m8,2)); m8=fmaxf(m8,__shfl_xor(m8,4));
        float e2=expf(s-m8);
        float ss=e2;
        ss+=__shfl_xor(ss,1); ss+=__shfl_xor(ss,2); ss+=__shfl_xor(ss,4);
        float av=e2/ss;
        alpha8[lane]=av;
        out[off_al+bt*8+lane]=av;
      }
      // Ck(t) blend (reads alpha8 written in-wave above)
      {
        float alr[8];
        float4 a0v=*(const float4*)&alpha8[0], a1v=*(const float4*)&alpha8[4];
        alr[0]=a0v.x; alr[1]=a0v.y; alr[2]=a0v.z; alr[3]=a0v.w;
        alr[4]=a1v.x; alr[5]=a1v.y; alr[6]=a1v.z; alr[7]=a1v.w;
        #pragma unroll
        for (int r=0;r<2;r++){
          int e=lane+64*r; int a=e>>3, qd=e&7;
          float4 acc=make_float4(0.f,0.f,0.f,0.f);
          #pragma unroll
          for (int k=0;k<8;k++){
            float4 cv=*(const float4*)&sC[(k*16+a)*L6+qd*4];
            FMA4(acc,alr[k],cv);
          }
          *(float4*)&Ck2[pc][a*L6+qd*4]=acc;
        }
      }
    } else if (wid==1){
      if (t>0){
        const size_t bt1=bt-1;
        // Sinv = Linv^T Linv
        #pragma unroll
        for (int q=0;q<4;q++){
          int e=lane+64*q; int a2=e>>4, b2=e&15;
          float s=0.f;
          #pragma unroll
          for (int k=0;k<16;k++) s+=Linv[k*17+a2]*Linv[k*17+b2];
          Sinv[a2*L0+b2]=s;
        }
        // Kg = CPT@Sinv * m(t-1)
        {
          int i0=lane>>2, aq=lane&3;
          float4 k0=make_float4(0.f,0.f,0.f,0.f), k1=k0;
          #pragma unroll
          for (int q=0;q<4;q++){
            float4 ca=*(const float4*)&CPT[i0*L0+q*4];
            float4 cb=*(const float4*)&CPT[(i0+16)*L0+q*4];
            float4 v0=*(const float4*)&Sinv[(q*4+0)*L0+aq*4];
            float4 v1=*(const float4*)&Sinv[(q*4+1)*L0+aq*4];
            float4 v2=*(const float4*)&Sinv[(q*4+2)*L0+aq*4];
            float4 v3=*(const float4*)&Sinv[(q*4+3)*L0+aq*4];
            FMA4(k0,ca.x,v0); FMA4(k0,ca.y,v1); FMA4(k0,ca.z,v2); FMA4(k0,ca.w,v3);
            FMA4(k1,cb.x,v0); FMA4(k1,cb.y,v1); FMA4(k1,cb.z,v2); FMA4(k1,cb.w,v3);
          }
          float m=mvs2[pp];
          k0.x*=m;k0.y*=m;k0.z*=m;k0.w*=m;
          k1.x*=m;k1.y*=m;k1.z*=m;k1.w*=m;
          *(float4*)&Kg[i0*L0+aq*4]=k0;
          *(float4*)&Kg[(i0+16)*L0+aq*4]=k1;
        }
        // Pf = P - Kg@CP + 1e-3 I -> T3m + store
        {
          const int i0=(lane>>3)*4, j0=(lane&7)*4;
          float4 q0=*(const float4*)&P[(i0+0)*L6+j0];
          float4 q1=*(const float4*)&P[(i0+1)*L6+j0];
          float4 q2=*(const float4*)&P[(i0+2)*L6+j0];
          float4 q3=*(const float4*)&P[(i0+3)*L6+j0];
          #pragma unroll
          for (int q=0;q<4;q++){
            float4 a0=*(const float4*)&Kg[(i0+0)*L0+q*4];
            float4 a1=*(const float4*)&Kg[(i0+1)*L0+q*4];
            float4 a2=*(const float4*)&Kg[(i0+2)*L0+q*4];
            float4 a3=*(const float4*)&Kg[(i0+3)*L0+q*4];
            float4 bv;
            bv=*(const float4*)&CPm[(q*4+0)*L6+j0];
            FMA4(q0,-a0.x,bv); FMA4(q1,-a1.x,bv); FMA4(q2,-a2.x,bv); FMA4(q3,-a3.x,bv);
            bv=*(const float4*)&CPm[(q*4+1)*L6+j0];
            FMA4(q0,-a0.y,bv); FMA4(q1,-a1.y,bv); FMA4(q2,-a2.y,bv); FMA4(q3,-a3.y,bv);
            bv=*(const float4*)&CPm[(q*4+2)*L6+j0];
            FMA4(q0,-a0.z,bv); FMA4(q1,-a1.z,bv); FMA4(q2,-a2.z,bv); FMA4(q3,-a3.z,bv);
            bv=*(const float4*)&CPm[(q*4+3)*L6+j0];
            FMA4(q0,-a0.w,bv); FMA4(q1,-a1.w,bv); FMA4(q2,-a2.w,bv); FMA4(q3,-a3.w,bv);
          }
          int d0=i0-j0;
          if (d0>=0&&d0<4){ if(d0==0)q0.x+=1e-3f; else if(d0==1)q0.y+=1e-3f; else if(d0==2)q0.z+=1e-3f; else q0.w+=1e-3f; }
          int d1=i0+1-j0;
          if (d1>=0&&d1<4){ if(d1==0)q1.x+=1e-3f; else if(d1==1)q1.y+=1e-3f; else if(d1==2)q1.z+=1e-3f; else q1.w+=1e-3f; }
          int d2=i0+2-j0;
          if (d2>=0&&d2<4){ if(d2==0)q2.x+=1e-3f; else if(d2==1)q2.y+=1e-3f; else if(d2==2)q2.z+=1e-3f; else q2.w+=1e-3f; }
          int d3=i0+3-j0;
          if (d3>=0&&d3<4){ if(d3==0)q3.x+=1e-3f; else if(d3==1)q3.y+=1e-3f; else if(d3==2)q3.z+=1e-3f; else q3.w+=1e-3f; }
          *(float4*)&T3m[(i0+0)*L6+j0]=q0;
          *(float4*)&T3m[(i0+1)*L6+j0]=q1;
          *(float4*)&T3m[(i0+2)*L6+j0]=q2;
          *(float4*)&T3m[(i0+3)*L6+j0]=q3;
          *(float4*)&out[off_Pf+bt1*1024+(i0+0)*32+j0]=q0;
          *(float4*)&out[off_Pf+bt1*1024+(i0+1)*32+j0]=q1;
          *(float4*)&out[off_Pf+bt1*1024+(i0+2)*32+j0]=q2;
          *(float4*)&out[off_Pf+bt1*1024+(i0+3)*32+j0]=q3;
        }
        // M3 = Ak(t-1)@T3m -> T1m  (in-wave: T3m written above by this wave)
        {
          const int i0=(lane>>3)*4, j0=(lane&7)*4;
          float4 q0=make_float4(0.f,0.f,0.f,0.f), q1=q0, q2=q0, q3=q0;
          #pragma unroll 4
          for (int q=0;q<8;q++){
            float4 a0=*(const float4*)&Ak2[pp][(i0+0)*L6+q*4];
            float4 a1=*(const float4*)&Ak2[pp][(i0+1)*L6+q*4];
            float4 a2=*(const float4*)&Ak2[pp][(i0+2)*L6+q*4];
            float4 a3=*(const float4*)&Ak2[pp][(i0+3)*L6+q*4];
            float4 bv;
            bv=*(const float4*)&T3m[(q*4+0)*L6+j0];
            FMA4(q0,a0.x,bv); FMA4(q1,a1.x,bv); FMA4(q2,a2.x,bv); FMA4(q3,a3.x,bv);
            bv=*(const float4*)&T3m[(q*4+1)*L6+j0];
            FMA4(q0,a0.y,bv); FMA4(q1,a1.y,bv); FMA4(q2,a2.y,bv); FMA4(q3,a3.y,bv);
            bv=*(const float4*)&T3m[(q*4+2)*L6+j0];
            FMA4(q0,a0.z,bv); FMA4(q1,a1.z,bv); FMA4(q2,a2.z,bv); FMA4(q3,a3.z,bv);
            bv=*(const float4*)&T3m[(q*4+3)*L6+j0];
            FMA4(q0,a0.w,bv); FMA4(q1,a1.w,bv); FMA4(q2,a2.w,bv); FMA4(q3,a3.w,bv);
          }
          *(float4*)&T1m[(i0+0)*L6+j0]=q0;
          *(float4*)&T1m[(i0+1)*L6+j0]=q1;
          *(float4*)&T1m[(i0+2)*L6+j0]=q2;
          *(float4*)&T1m[(i0+3)*L6+j0]=q3;
        }
        // Pp = T1m@AkT(t-1) + Q + 1e-3I -> P(t) + store
        {
          const int i0=(lane>>3)*4, j0=(lane&7)*4;
          float4 q0=*(const float4*)&Qm[(i0+0)*L6+j0];
          float4 q1=*(const float4*)&Qm[(i0+1)*L6+j0];
          float4 q2=*(const float4*)&Qm[(i0+2)*L6+j0];
          float4 q3=*(const float4*)&Qm[(i0+3)*L6+j0];
          int d0=i0-j0;
          if (d0>=0&&d0<4){ if(d0==0)q0.x+=1e-3f; else if(d0==1)q0.y+=1e-3f; else if(d0==2)q0.z+=1e-3f; else q0.w+=1e-3f; }
          int d1=i0+1-j0;
          if (d1>=0&&d1<4){ if(d1==0)q1.x+=1e-3f; else if(d1==1)q1.y+=1e-3f; else if(d1==2)q1.z+=1e-3f; else q1.w+=1e-3f; }
          int d2=i0+2-j0;
          if (d2>=0&&d2<4){ if(d2==0)q2.x+=1e-3f; else if(d2==1)q2.y+=1e-3f; else if(d2==2)q2.z+=1e-3f; else q2.w+=1e-3f; }
          int d3=i0+3-j0;
          if (d3>=0&&d3<4){ if(d3==0)q3.x+=1e-3f; else if(d3==1)q3.y+=1e-3f; else if(d3==2)q3.z+=1e-3f; else q3.w+=1e-3f; }
          #pragma unroll 4
          for (int q=0;q<8;q++){
            float4 a0=*(const float4*)&T1m[(i0+0)*L6+q*4];
            float4 a1=*(const float4*)&T1m[(i0+1)*L6+q*4];
            float4 a2=*(const float4*)&T1m[(i0+2)*L6+q*4];
            float4 a3=*(const float4*)&T1m[(i0+3)*L6+q*4];
            float4 bv;
            bv=*(const float4*)&AkT2[pp][(q*4+0)*L6+j0];
            FMA4(q0,a0.x,bv); FMA4(q1,a1.x,bv); FMA4(q2,a2.x,bv); FMA4(q3,a3.x,bv);
            bv=*(const float4*)&AkT2[pp][(q*4+1)*L6+j0];
            FMA4(q0,a0.y,bv); FMA4(q1,a1.y,bv); FMA4(q2,a2.y,bv); FMA4(q3,a3.y,bv);
            bv=*(const float4*)&AkT2[pp][(q*4+2)*L6+j0];
            FMA4(q0,a0.z,bv); FMA4(q1,a1.z,bv); FMA4(q2,a2.z,bv); FMA4(q3,a3.z,bv);
            bv=*(const float4*)&AkT2[pp][(q*4+3)*L6+j0];
            FMA4(q0,a0.w,bv); FMA4(q1,a1.w,bv); FMA4(q2,a2.w,bv); FMA4(q3,a3.w,bv);
          }
          *(float4*)&P[(i0+0)*L6+j0]=q0;
          *(float4*)&P[(i0+1)*L6+j0]=q1;
          *(float4*)&P[(i0+2)*L6+j0]=q2;
          *(float4*)&P[(i0+3)*L6+j0]=q3;
          *(float4*)&out[off_Pp+bt1*1024+(i0+0)*32+j0]=q0;
          *(float4*)&out[off_Pp+bt1*1024+(i0+1)*32+j0]=q1;
          *(float4*)&out[off_Pp+bt1*1024+(i0+2)*32+j0]=q2;
          *(float4*)&out[off_Pp+bt1*1024+(i0+3)*32+j0]=q3;
        }
      }
    } else if (wid==2){
      if (t>0){
        const size_t bt1=bt-1;
        float4 zq[8];
        #pragma unroll
        for (int q=0;q<8;q++) zq[q]=*(const float4*)&zc[q*4];
        if (lane<32){
          float s=0.f;
          #pragma unroll
          for (int q=0;q<8;q++) s+=dot4(*(const float4*)&Ak2[pp][lane*L6+q*4], zq[q]);
          float4 bk=*(const float4*)&Bk[lane*4];
          float4 u4=*(const float4*)&uk[0];
          s+=dot4(bk,u4);
          zpred[lane]=s;
          out[off_zp+bt1*32+lane]=s;
        }
        if (lane>=32 && lane<48){
          int a=lane-32;
          float s=0.f;
          #pragma unroll
          for (int q=0;q<8;q++) s+=dot4(*(const float4*)&Ck2[pp][a*L6+q*4], zq[q]);
          out[off_af+bt1*16+a]=s;
        }
        if (lane<16){
          float s=0.f;
          #pragma unroll
          for (int q=0;q<8;q++)
            s+=dot4(*(const float4*)&Ck2[pp][lane*L6+q*4], *(const float4*)&zpred[q*4]);
          out[off_ap+bt1*16+lane]=s;
        }
      }
    } else {
      // wid==3: ak load, zj, aj, ll+alpha_imm
      if (lane<16) ak[lane]=a_seq[bt*16+lane];
      float mv=mask[bt];
      float4 zq[8];
      #pragma unroll
      for (int q=0;q<8;q++) zq[q]=*(const float4*)&zc[q*4];
      #pragma unroll
      for (int r=0;r<4;r++){
        int e=lane+64*r; int k=e>>5, i=e&31;
        float s=0.f;
        #pragma unroll
        for (int q=0;q<8;q++) s+=dot4(*(const float4*)&sA[(k*32+i)*L6+q*4], zq[q]);
        zj[e]=s;
      }
      #pragma unroll
      for (int r=0;r<2;r++){
        int e=lane+64*r; int k=e>>4, a=e&15;
        float s=0.f;
        #pragma unroll
        for (int q=0;q<8;q++) s+=dot4(*(const float4*)&sC[(k*16+a)*L6+q*4], *(const float4*)&zj[k*32+q*4]);
        aj[e]=s;
      }
      if (lane<8){
        float s=0.f;
        #pragma unroll
        for (int q=0;q<4;q++){
          float4 av=*(const float4*)&ak[q*4];
          float4 jv=*(const float4*)&aj[lane*16+q*4];
          float dx=av.x-jv.x, dy=av.y-jv.y, dz=av.z-jv.z, dw=av.w-jv.w;
          s+=dx*dx+dy*dy+dz*dz+dw*dw;
        }
        float llv=-s;
        float m8=llv;
        m8=fmaxf(m8,__shfl_xor(m8,1)); m8=fmaxf(m8,__shfl_xor(m8,2)); m8=fmaxf(m8,__shfl_xor(m8,4));
        float e2=expf(llv-m8);
        float ss=e2;
        ss+=__shfl_xor(ss,1); ss+=__shfl_xor(ss,2); ss+=__shfl_xor(ss,4);
        out[off_ai+bt*8+lane]=e2/ss*mv;
      }
    }
    __syncthreads();

    // ===== Phase B =====
    if (wid==0){
      // znew -> CP -> rk -> S -> chol16 -> solve -> zloc (all in-wave)
      if (lane<32){
        float4 a0v=*(const float4*)&alpha8[0], a1v=*(const float4*)&alpha8[4];
        float s=a0v.x*zj[lane]+a0v.y*zj[32+lane]+a0v.z*zj[64+lane]+a0v.w*zj[96+lane]
               +a1v.x*zj[128+lane]+a1v.y*zj[160+lane]+a1v.z*zj[192+lane]+a1v.w*zj[224+lane];
        znew[lane]=s;
      }
      {
        int qd=lane&7, a0=lane>>3;
        float4 d0=make_float4(0.f,0.f,0.f,0.f), d1=d0;
        #pragma unroll 2
        for (int q=0;q<8;q++){
          float4 c0=*(const float4*)&Ck2[pc][a0*L6+q*4];
          float4 c1=*(const float4*)&Ck2[pc][(a0+8)*L6+q*4];
          float4 p0=*(const float4*)&P[(q*4+0)*L6+qd*4];
          float4 p1=*(const float4*)&P[(q*4+1)*L6+qd*4];
          float4 p2=*(const float4*)&P[(q*4+2)*L6+qd*4];
          float4 p3=*(const float4*)&P[(q*4+3)*L6+qd*4];
          FMA4(d0,c0.x,p0); FMA4(d0,c0.y,p1); FMA4(d0,c0.z,p2); FMA4(d0,c0.w,p3);
          FMA4(d1,c1.x,p0); FMA4(d1,c1.y,p1); FMA4(d1,c1.z,p2); FMA4(d1,c1.w,p3);
        }
        *(float4*)&CPm[a0*L6+qd*4]=d0;
        *(float4*)&CPm[(a0+8)*L6+qd*4]=d1;
        CPT[(qd*4+0)*L0+a0]=d0.x; CPT[(qd*4+1)*L0+a0]=d0.y;
        CPT[(qd*4+2)*L0+a0]=d0.z; CPT[(qd*4+3)*L0+a0]=d0.w;
        CPT[(qd*4+0)*L0+a0+8]=d1.x; CPT[(qd*4+1)*L0+a0+8]=d1.y;
        CPT[(qd*4+2)*L0+a0+8]=d1.z; CPT[(qd*4+3)*L0+a0+8]=d1.w;
      }
      if (lane<16){
        float s=0.f;
        #pragma unroll
        for (int q=0;q<8;q++) s+=dot4(*(const float4*)&Ck2[pc][lane*L6+q*4], *(const float4*)&znew[q*4]);
        rk[lane]=ak[lane]-s;
      }
      {
        int a2=lane>>2, cq=lane&3;
        float s0=0.f,s1=0.f,s2=0.f,s3=0.f;
        #pragma unroll 2
        for (int q=0;q<8;q++){
          float4 cp=*(const float4*)&CPm[a2*L6+q*4];
          s0+=dot4(cp,*(const float4*)&Ck2[pc][(cq*4+0)*L6+q*4]);
          s1+=dot4(cp,*(const float4*)&Ck2[pc][(cq*4+1)*L6+q*4]);
          s2+=dot4(cp,*(const float4*)&Ck2[pc][(cq*4+2)*L6+q*4]);
          s3+=dot4(cp,*(const float4*)&Ck2[pc][(cq*4+3)*L6+q*4]);
        }
        float4 rm=*(const float4*)&Rm[a2*L0+cq*4];
        s0+=rm.x+((a2==cq*4+0)?1e-4f:0.f);
        s1+=rm.y+((a2==cq*4+1)?1e-4f:0.f);
        s2+=rm.z+((a2==cq*4+2)?1e-4f:0.f);
        s3+=rm.w+((a2==cq*4+3)?1e-4f:0.f);
        float4 sv=make_float4(s0,s1,s2,s3);
        *(float4*)&Sm[a2*L0+cq*4]=sv;
        *(float4*)&out[off_S+bt*256+lane*4]=sv;
      }
      {
        int row=lane<16?lane:15;
        float Sr[16], invd[16];
        #pragma unroll
        for (int q=0;q<4;q++){
          float4 v=*(const float4*)&Sm[row*L0+q*4];
          Sr[q*4+0]=v.x; Sr[q*4+1]=v.y; Sr[q*4+2]=v.z; Sr[q*4+3]=v.w;
        }
        #pragma unroll
        for (int c=0;c<16;c++){
          float d=rdlane(Sr[c],c);
          float inv=rsqrtf(d);
          invd[c]=inv;
          float lc=(lane==c)?d*inv:Sr[c]*inv;
          Sr[c]=lc;
          #pragma unroll
          for (int j=c+1;j<16;j++) Sr[j]-=lc*rdlane(lc,j);
        }
        float Li[16], rhs[16];
        #pragma unroll
        for (int r=0;r<16;r++) rhs[r]=(lane==r)?1.f:0.f;
        #pragma unroll
        for (int k=0;k<16;k++){
          float lik=rhs[k]*invd[k];
          Li[k]=lik;
          #pragma unroll
          for (int r=k+1;r<16;r++) rhs[r]-=rdlane(Sr[k],r)*lik;
        }
        if (lane<16){
          #pragma unroll
          for (int r=0;r<16;r++) Linv[r*17+lane]=Li[r];
        }
      }
      if (lane<16){
        float m=mvs2[pc];
        float s=0.f;
        #pragma unroll
        for (int k=0;k<16;k++) s+=Linv[lane*17+k]*(m*rk[k]);
        ys[lane]=s;
      }
      if (lane<16){
        float s=0.f;
        #pragma unroll
        for (int r=0;r<16;r++) s+=Linv[r*17+lane]*ys[r];
        ws[lane]=s;
      }
      if (lane<32){
        float s=znew[lane];
        #pragma unroll
        for (int q=0;q<4;q++)
          s+=dot4(*(const float4*)&CPT[lane*L0+q*4], *(const float4*)&ws[q*4]);
        zloc[lane]=s;
        zc[lane]=s;
        out[off_zf+bt*32+lane]=s;
        out[off_zl+bt*32+lane]=s;
      }
    } else if (wid==1){
      // ghl(t+1) = ghs(t) @ Wh ; uk(t) load
      if (lane<48){
        const int c0=lane*4;
        float4 A0=make_float4(0.f,0.f,0.f,0.f), A1=A0, A2=A0, A3=A0;
        #pragma unroll
        for (int q=0;q<16;q++){
          float4 gv=*(const float4*)&ghs[q*4];
          float4 w0=*(const float4*)(Wh+(size_t)(q*4+0)*192+c0);
          float4 w1=*(const float4*)(Wh+(size_t)(q*4+1)*192+c0);
          float4 w2=*(const float4*)(Wh+(size_t)(q*4+2)*192+c0);
          float4 w3=*(const float4*)(Wh+(size_t)(q*4+3)*192+c0);
          FMA4(A0,gv.x,w0); FMA4(A1,gv.y,w1); FMA4(A2,gv.z,w2); FMA4(A3,gv.w,w3);
        }
        float4 g=make_float4(A0.x+A1.x+A2.x+A3.x, A0.y+A1.y+A2.y+A3.y,
                             A0.z+A1.z+A2.z+A3.z, A0.w+A1.w+A2.w+A3.w);
        *(float4*)&ghl[c0]=g;
      }
      if (lane>=48 && lane<52) uk[lane-48]=u_seq[bt*4+(lane-48)];
    } else if (wid==2){
      if (t>0){
        const size_t bt1=bt-1;
        int row=lane<32?lane:31;
        float trl[32];
        #pragma unroll
        for (int q=0;q<8;q++){
          float4 v=*(const float4*)&T3m[row*L6+q*4];
          trl[q*4+0]=v.x; trl[q*4+1]=v.y; trl[q*4+2]=v.z; trl[q*4+3]=v.w;
        }
        #pragma unroll
        for (int c=0;c<32;c++){
          float d=rdlane(trl[c],c);
          float inv=rsqrtf(d);
          float lc=(lane==c)?d*inv:trl[c]*inv;
          trl[c]=lc;
          #pragma unroll
          for (int j=c+1;j<32;j++) trl[j]-=lc*rdlane(lc,j);
        }
        if (lane<32){
          #pragma unroll
          for (int q=0;q<8;q++){
            float t0=(q*4+0<=lane)?trl[q*4+0]:0.f;
            float t1=(q*4+1<=lane)?trl[q*4+1]:0.f;
            float t2=(q*4+2<=lane)?trl[q*4+2]:0.f;
            float t3=(q*4+3<=lane)?trl[q*4+3]:0.f;
            *(float4*)&out[off_tr+bt1*1024+lane*32+q*4]=make_float4(t0,t1,t2,t3);
          }
        }
      }
    } else {
      // wid==3: blends Ak2[pc]/AkT2[pc] + Bk
      float alr[8];
      float4 a0v=*(const float4*)&alpha8[0], a1v=*(const float4*)&alpha8[4];
      alr[0]=a0v.x; alr[1]=a0v.y; alr[2]=a0v.z; alr[3]=a0v.w;
      alr[4]=a1v.x; alr[5]=a1v.y; alr[6]=a1v.z; alr[7]=a1v.w;
      #pragma unroll
      for (int r=0;r<4;r++){
        int e=lane+64*r; int i=e>>3, qd=e&7;
        float4 acc=make_float4(0.f,0.f,0.f,0.f);
        #pragma unroll
        for (int k=0;k<8;k++){
          float4 av=*(const float4*)&sA[(k*32+i)*L6+qd*4];
          FMA4(acc,alr[k],av);
        }
        *(float4*)&Ak2[pc][i*L6+qd*4]=acc;
        AkT2[pc][(qd*4+0)*L6+i]=acc.x; AkT2[pc][(qd*4+1)*L6+i]=acc.y;
        AkT2[pc][(qd*4+2)*L6+i]=acc.z; AkT2[pc][(qd*4+3)*L6+i]=acc.w;
      }
      #pragma unroll
      for (int r=0;r<2;r++){
        int e=lane+64*r;
        float s=0.f;
        #pragma unroll
        for (int k=0;k<8;k++) s+=alr[k]*sBm[k*128+e];
        Bk[e]=s;
      }
    }
    __syncthreads();
  }

  // ===== Epilogue: tail(T-1) =====
  {
    const size_t btL=(size_t)b*T+(T-1);
    const int pl=(T-1)&1;
    if (wid==1){
      #pragma unroll
      for (int q=0;q<4;q++){
        int e=lane+64*q; int a2=e>>4, b2=e&15;
        float s=0.f;
        #pragma unroll
        for (int k=0;k<16;k++) s+=Linv[k*17+a2]*Linv[k*17+b2];
        Sinv[a2*L0+b2]=s;
      }
      {
        int i0=lane>>2, aq=lane&3;
        float4 k0=make_float4(0.f,0.f,0.f,0.f), k1=k0;
        #pragma unroll
        for (int q=0;q<4;q++){
          float4 ca=*(const float4*)&CPT[i0*L0+q*4];
          float4 cb=*(const float4*)&CPT[(i0+16)*L0+q*4];
          float4 v0=*(const float4*)&Sinv[(q*4+0)*L0+aq*4];
          float4 v1=*(const float4*)&Sinv[(q*4+1)*L0+aq*4];
          float4 v2=*(const float4*)&Sinv[(q*4+2)*L0+aq*4];
          float4 v3=*(const float4*)&Sinv[(q*4+3)*L0+aq*4];
          FMA4(k0,ca.x,v0); FMA4(k0,ca.y,v1); FMA4(k0,ca.z,v2); FMA4(k0,ca.w,v3);
          FMA4(k1,cb.x,v0); FMA4(k1,cb.y,v1); FMA4(k1,cb.z,v2); FMA4(k1,cb.w,v3);
        }
        float m=mvs2[pl];
        k0.x*=m;k0.y*=m;k0.z*=m;k0.w*=m;
        k1.x*=m;k1.y*=m;k1.z*=m;k1.w*=m;
        *(float4*)&Kg[i0*L0+aq*4]=k0;
        *(float4*)&Kg[(i0+16)*L0+aq*4]=k1;
      }
      {
        const int i0=(lane>>3)*4, j0=(lane&7)*4;
        float4 q0=*(const float4*)&P[(i0+0)*L6+j0];
        float4 q1=*(const float4*)&P[(i0+1)*L6+j0];
        float4 q2=*(const float4*)&P[(i0+2)*L6+j0];
        float4 q3=*(const float4*)&P[(i0+3)*L6+j0];
        #pragma unroll
        for (int q=0;q<4;q++){
          float4 a0=*(const float4*)&Kg[(i0+0)*L0+q*4];
          float4 a1=*(const float4*)&Kg[(i0+1)*L0+q*4];
          float4 a2=*(const float4*)&Kg[(i0+2)*L0+q*4];
          float4 a3=*(const float4*)&Kg[(i0+3)*L0+q*4];
          float4 bv;
          bv=*(const float4*)&CPm[(q*4+0)*L6+j0];
          FMA4(q0,-a0.x,bv); FMA4(q1,-a1.x,bv); FMA4(q2,-a2.x,bv); FMA4(q3,-a3.x,bv);
          bv=*(const float4*)&CPm[(q*4+1)*L6+j0];
          FMA4(q0,-a0.y,bv); FMA4(q1,-a1.y,bv); FMA4(q2,-a2.y,bv); FMA4(q3,-a3.y,bv);
          bv=*(const float4*)&CPm[(q*4+2)*L6+j0];
          FMA4(q0,-a0.z,bv); FMA4(q1,-a1.z,bv); FMA4(q2,-a2.z,bv); FMA4(q3,-a3.z,bv);
          bv=*(const float4*)&CPm[(q*4+3)*L6+j0];
          FMA4(q0,-a0.w,bv); FMA4(q1,-a1.w,bv); FMA4(q2,-a2.w,bv); FMA4(q3,-a3.w,bv);
        }
        int d0=i0-j0;
        if (d0>=0&&d0<4){ if(d0==0)q0.x+=1e-3f; else if(d0==1)q0.y+=1e-3f; else if(d0==2)q0.z+=1e-3f; else q0.w+=1e-3f; }
        int d1=i0+1-j0;
        if (d1>=0&&d1<4){ if(d1==0)q1.x+=1e-3f; else if(d1==1)q1.y+=1e-3f; else if(d1==2)q1.z+=1e-3f; else q1.w+=1e-3f; }
        int d2=i0+2-j0;
        if (d2>=0&&d2<4){ if(d2==0)q2.x+=1e-3f; else if(d2==1)q2.y+=1e-3f; else if(d2==2)q2.z+=1e-3f; else q2.w+=1e-3f; }
        int d3=i0+3-j0;
        if (d3>=0&&d3<4){ if(d3==0)q3.x+=1e-3f; else if(d3==1)q3.y+=1e-3f; else if(d3==2)q3.z+=1e-3f; else q3.w+=1e-3f; }
        *(float4*)&T3m[(i0+0)*L6+j0]=q0;
        *(float4*)&T3m[(i0+1)*L6+j0]=q1;
        *(float4*)&T3m[(i0+2)*L6+j0]=q2;
        *(float4*)&T3m[(i0+3)*L6+j0]=q3;
        *(float4*)&out[off_Pf+btL*1024+(i0+0)*32+j0]=q0;
        *(float4*)&out[off_Pf+btL*1024+(i0+1)*32+j0]=q1;
        *(float4*)&out[off_Pf+btL*1024+(i0+2)*32+j0]=q2;
        *(float4*)&out[off_Pf+btL*1024+(i0+3)*32+j0]=q3;
      }
      {
        const int i0=(lane>>3)*4, j0=(lane&7)*4;
        float4 q0=make_float4(0.f,0.f,0.f,0.f), q1=q0, q2=q0, q3=q0;
        #pragma unroll 4
        for (int q=0;q<8;q++){
          float4 a0=*(const float4*)&Ak2[pl][(i0+0)*L6+q*4];
          float4 a1=*(const float4*)&Ak2[pl][(i0+1)*L6+q*4];
          float4 a2=*(const float4*)&Ak2[pl][(i0+2)*L6+q*4];
          float4 a3=*(const float4*)&Ak2[pl][(i0+3)*L6+q*4];
          float4 bv;
          bv=*(const float4*)&T3m[(q*4+0)*L6+j0];
          FMA4(q0,a0.x,bv); FMA4(q1,a1.x,bv); FMA4(q2,a2.x,bv); FMA4(q3,a3.x,bv);
          bv=*(const float4*)&T3m[(q*4+1)*L6+j0];
          FMA4(q0,a0.y,bv); FMA4(q1,a1.y,bv); FMA4(q2,a2.y,bv); FMA4(q3,a3.y,bv);
          bv=*(const float4*)&T3m[(q*4+2)*L6+j0];
          FMA4(q0,a0.z,bv); FMA4(q1,a1.z,bv); FMA4(q2,a2.z,bv); FMA4(q3,a3.z,bv);
          bv=*(const float4*)&T3m[(q*4+3)*L6+j0];
          FMA4(q0,a0.w,bv); FMA4(q1,a1.w,bv); FMA4(q2,a2.w,bv); FMA4(q3,a3.w,bv);
        }
        *(float4*)&T1m[(i0+0)*L6+j0]=q0;
        *(float4*)&T1m[(i0+1)*L6+j0]=q1;
        *(float4*)&T1m[(i0+2)*L6+j0]=q2;
        *(float4*)&T1m[(i0+3)*L6+j0]=q3;
      }
      {
        const int i0=(lane>>3)*4, j0=(lane&7)*4;
        float4 q0=*(const float4*)&Qm[(i0+0)*L6+j0];
        float4 q1=*(const float4*)&Qm[(i0+1)*L6+j0];
        float4 q2=*(const float4*)&Qm[(i0+2)*L6+j0];
        float4 q3=*(const float4*)&Qm[(i0+3)*L6+j0];
        int d0=i0-j0;
        if (d0>=0&&d0<4){ if(d0==0)q0.x+=1e-3f; else if(d0==1)q0.y+=1e-3f; else if(d0==2)q0.z+=1e-3f; else q0.w+=1e-3f; }
        int d1=i0+1-j0;
        if (d1>=0&&d1<4){ if(d1==0)q1.x+=1e-3f; else if(d1==1)q1.y+=1e-3f; else if(d1==2)q1.z+=1e-3f; else q1.w+=1e-3f; }
        int d2=i0+2-j0;
        if (d2>=0&&d2<4){ if(d2==0)q2.x+=1e-3f; else if(d2==1)q2.y+=1e-3f; else if(d2==2)q2.z+=1e-3f; else q2.w+=1e-3f; }
        int d3=i0+3-j0;
        if (d3>=0&&d3<4){ if(d3==0)q3.x+=1e-3f; else if(d3==1)q3.y+=1e-3f; else if(d3==2)q3.z+=1e-3f; else q3.w+=1e-3f; }
        #pragma unroll 4
        for (int q=0;q<8;q++){
          float4 a0=*(const float4*)&T1m[(i0+0)*L6+q*4];
          float4 a1=*(const float4*)&T1m[(i0+1)*L6+q*4];
          float4 a2=*(const float4*)&T1m[(i0+2)*L6+q*4];
          float4 a3=*(const float4*)&T1m[(i0+3)*L6+q*4];
          float4 bv;
          bv=*(const float4*)&AkT2[pl][(q*4+0)*L6+j0];
          FMA4(q0,a0.x,bv); FMA4(q1,a1.x,bv); FMA4(q2,a2.x,bv); FMA4(q3,a3.x,bv);
          bv=*(const float4*)&AkT2[pl][(q*4+1)*L6+j0];
          FMA4(q0,a0.y,bv); FMA4(q1,a1.y,bv); FMA4(q2,a2.y,bv); FMA4(q3,a3.y,bv);
          bv=*(const float4*)&AkT2[pl][(q*4+2)*L6+j0];
          FMA4(q0,a0.z,bv); FMA4(q1,a1.z,bv); FMA4(q2,a2.z,bv); FMA4(q3,a3.z,bv);
          bv=*(const float4*)&AkT2[pl][(q*4+3)*L6+j0];
          FMA4(q0,a0.w,bv); FMA4(q1,a1.w,bv); FMA4(q2,a2.w,bv); FMA4(q3,a3.w,bv);
        }
        *(float4*)&out[off_Pp+btL*1024+(i0+0)*32+j0]=q0;
        *(float4*)&out[off_Pp+btL*1024+(i0+1)*32+j0]=q1;
        *(float4*)&out[off_Pp+btL*1024+(i0+2)*32+j0]=q2;
        *(float4*)&out[off_Pp+btL*1024+(i0+3)*32+j0]=q3;
      }
    } else if (wid==2){
      float4 zq[8];
      #pragma unroll
      for (int q=0;q<8;q++) zq[q]=*(const float4*)&zc[q*4];
      if (lane<32){
        float s=0.f;
        #pragma unroll
        for (int q=0;q<8;q++) s+=dot4(*(const float4*)&Ak2[pl][lane*L6+q*4], zq[q]);
        float4 bk=*(const float4*)&Bk[lane*4];
        float4 u4=*(const float4*)&uk[0];
        s+=dot4(bk,u4);
        zpred[lane]=s;
        out[off_zp+btL*32+lane]=s;
      }
      if (lane>=32 && lane<48){
        int a=lane-32;
        float s=0.f;
        #pragma unroll
        for (int q=0;q<8;q++) s+=dot4(*(const float4*)&Ck2[pl][a*L6+q*4], zq[q]);
        out[off_af+btL*16+a]=s;
      }
      if (lane<16){
        float s=0.f;
        #pragma unroll
        for (int q=0;q<8;q++)
          s+=dot4(*(const float4*)&Ck2[pl][lane*L6+q*4], *(const float4*)&zpred[q*4]);
        out[off_ap+btL*16+lane]=s;
      }
    }
    __syncthreads();
    if (wid==2){
      int row=lane<32?lane:31;
      float trl[32];
      #pragma unroll
      for (int q=0;q<8;q++){
        float4 v=*(const float4*)&T3m[row*L6+q*4];
        trl[q*4+0]=v.x; trl[q*4+1]=v.y; trl[q*4+2]=v.z; trl[q*4+3]=v.w;
      }
      #pragma unroll
      for (int c=0;c<32;c++){
        float d=rdlane(trl[c],c);
        float inv=rsqrtf(d);
        float lc=(lane==c)?d*inv:trl[c]*inv;
        trl[c]=lc;
        #pragma unroll
        for (int j=c+1;j<32;j++) trl[j]-=lc*rdlane(lc,j);
      }
      if (lane<32){
        #pragma unroll
        for (int q=0;q<8;q++){
          float t0=(q*4+0<=lane)?trl[q*4+0]:0.f;
          float t1=(q*4+1<=lane)?trl[q*4+1]:0.f;
          float t2=(q*4+2<=lane)?trl[q*4+2]:0.f;
          float t3=(q*4+3<=lane)?trl[q*4+3]:0.f;
          *(float4*)&out[off_tr+btL*1024+lane*32+q*4]=make_float4(t0,t1,t2,t3);
        }
      }
    }
  }
}

extern "C" void kernel_launch(void* const* d_in, const int* in_sizes, int n_in,
                              void* d_out, int out_size, void* d_ws, size_t ws_size,
                              hipStream_t stream) {
  kf_fwd<<<128, NT, 0, stream>>>(
    (const float*)d_in[0],  // a_seq
    (const float*)d_in[1],  // h_obs
    (const float*)d_in[2],  // A_matrices
    (const float*)d_in[3],  // C_matrices
    (const float*)d_in[4],  // B_matrices
    (const float*)d_in[5],  // u_seq
    (const float*)d_in[6],  // mask
    (const float*)d_in[7],  // P_0
    (const float*)d_in[8],  // mat_Q
    (const float*)d_in[9],  // mat_R
    (const float*)d_in[10], // gru_Wx
    (const float*)d_in[11], // gru_Wh
    (const float*)d_in[12], // gru_b
    (const float*)d_in[13], // out_W
    (const float*)d_in[14], // out_b
    (float*)d_out);
}